// Round 7
// baseline (1304.191 us; speedup 1.0000x reference)
//
#include <hip/hip_runtime.h>

#define B_  2
#define S_  2048
#define NH_ 32
#define HD_ 128
#define H_  4096
#define H3_ 12288

typedef __bf16 bf16x8 __attribute__((ext_vector_type(8)));
typedef float  f32x4  __attribute__((ext_vector_type(4)));
typedef float  f32x16 __attribute__((ext_vector_type(16)));

__device__ __forceinline__ unsigned short f2bf(float f) {
  unsigned int u = __float_as_uint(f);
  u += 0x7fffu + ((u >> 16) & 1u);
  return (unsigned short)(u >> 16);
}
__device__ __forceinline__ void unpack8(uint4 r, float f[8]) {
  f[0] = __uint_as_float(r.x << 16); f[1] = __uint_as_float(r.x & 0xffff0000u);
  f[2] = __uint_as_float(r.y << 16); f[3] = __uint_as_float(r.y & 0xffff0000u);
  f[4] = __uint_as_float(r.z << 16); f[5] = __uint_as_float(r.z & 0xffff0000u);
  f[6] = __uint_as_float(r.w << 16); f[7] = __uint_as_float(r.w & 0xffff0000u);
}
__device__ __forceinline__ void gload_lds16(const void* g, void* l) {
  __builtin_amdgcn_global_load_lds(
      (const __attribute__((address_space(1))) unsigned int*)g,
      (__attribute__((address_space(3))) unsigned int*)l, 16, 0, 0);
}

#define BARSCHED() do { __builtin_amdgcn_s_barrier(); __builtin_amdgcn_sched_barrier(0); } while (0)

// ---------------- f32 -> bf16 convert ----------------
__global__ __launch_bounds__(256) void cvt_bf16(const float* __restrict__ in,
                                                unsigned short* __restrict__ out,
                                                long n) {
  long i = ((long)blockIdx.x * 256 + threadIdx.x) * 4;
  const long stride = (long)gridDim.x * 256 * 4;
  for (; i < n; i += stride) {
    float4 v = *(const float4*)(in + i);
    ushort4 o;
    o.x = f2bf(v.x); o.y = f2bf(v.y); o.z = f2bf(v.z); o.w = f2bf(v.w);
    *(ushort4*)(out + i) = o;
  }
}

// =============================================================================
// 256x256-tile bf16 GEMM with 32x32x16 MFMA, C[m][n] = sum_k A[m][k]*Bt[n][k]
// 8 waves (2Mx4N, wave tile 128x64 = 4x2 32x32 tiles), BK=64, 2-buffer LDS,
// 4 phases/K-tile {ds_read subtile || quarter-prefetch -> barrier -> 8 MFMA ->
// barrier}, counted vmcnt(4) twice per K-tile, chunk-XOR swizzle, setprio.
// Fragments (32x32x16): A/B row|col = l&31, k = (l>>5)*8+j.
// C/D: col = l&31, row = (r&3) + 8*(r>>2) + 4*(l>>5), r in [0,16).
// EPI 0: bf16 out + bias ; EPI 1: f32 out + bias + residual
// =============================================================================
template <int EPI>
__global__ __launch_bounds__(512, 2) void gemm256(
    const unsigned short* __restrict__ A, const unsigned short* __restrict__ Bt,
    void* __restrict__ C, const float* __restrict__ bias, const float* __restrict__ Res,
    int lda, int ldb, int ldc, int K)
{
  __shared__ __align__(16) unsigned short lds[65536];   // 128 KB = 2 x 64 KB buffers

  const int tid = threadIdx.x;
  const int w = tid >> 6, l = tid & 63;

  // XCD-aware block swizzle (nwg % 8 == 0 at both call sites)
  const int gx = gridDim.x;
  const int nwg = gx * gridDim.y;
  const int flat = blockIdx.y * gx + blockIdx.x;
  const int swz = (flat & 7) * (nwg >> 3) + (flat >> 3);
  const int m0 = (swz / gx) * 256;
  const int n0 = (swz % gx) * 256;

  const int wr = w >> 2, wc = w & 3;      // wave tile: rows wr*128.., cols wc*64..

  // --- staging (linear LDS dest; pre-swizzled global source chunk) ---
  const int strow = tid >> 2;
  const int scs = (((tid & 3) ^ ((tid >> 3) & 3)) << 3);   // elems
  const unsigned short* ga = A  + (long)(m0 + strow) * lda + scs;
  const unsigned short* gb = Bt + (long)(n0 + strow) * ldb + scs;
  const int ldsw = w * 512;               // wave-uniform dest offset within region

  // --- 32x32 fragment addressing: row = l&31; k-chunk (8 elems) logical
  // index = ks*2 + (l>>5), physical = logical ^ ((row>>1)&3) = ^ ((l>>1)&3)
  const int l31 = l & 31;
  const int rsw = (l >> 1) & 3;
  const int ca = (((l >> 5) ^ rsw) << 3);          // elems; ks=1 chunk = ca^16
  const int abase2 = (wr * 128 + l31) * 32;        // + mt*1024 + kh*16384 + chunk
  const int bbase2 = 8192 + (wc * 64 + l31) * 32;  // + nt*1024 + kh*16384 + chunk

  const int NT = K >> 6;                  // BK = 64

  f32x16 acc[4][2];
#pragma unroll
  for (int mt = 0; mt < 4; ++mt)
#pragma unroll
    for (int nt = 0; nt < 2; ++nt)
#pragma unroll
      for (int r = 0; r < 16; ++r) acc[mt][nt][r] = 0.f;

  // stage quarter q (0=A-kh0,1=B-kh0,2=A-kh1,3=B-kh1) of K-tile kt into buffer b
  auto stageQ = [&](int kt, int b, int q) {
    const long koff = (long)kt * 64 + (q >> 1) * 32;
    unsigned short* d = lds + b * 32768 + q * 8192 + ldsw;
    if ((q & 1) == 0) {
      gload_lds16(ga + koff,              d);
      gload_lds16(ga + koff + 128L * lda, d + 4096);
    } else {
      gload_lds16(gb + koff,              d);
      gload_lds16(gb + koff + 128L * ldb, d + 4096);
    }
  };

  stageQ(0, 0, 0); stageQ(0, 0, 1); stageQ(0, 0, 2); stageQ(0, 0, 3);
  asm volatile("s_waitcnt vmcnt(0)" ::: "memory");
  BARSCHED();

  bf16x8 av[2][2], bv[2][2];   // av[mt-pair][ks], bv[nt][ks]

#define MFMA32(a, b, c) __builtin_amdgcn_mfma_f32_32x32x16_bf16(a, b, c, 0, 0, 0)
#define PHASE(kh, mh, QIDX)                                                     \
    {                                                                           \
      if ((mh) == 0) {                                                          \
        bv[0][0] = *(const bf16x8*)&rb[(kh)*16384 + bbase2 + ca];               \
        bv[0][1] = *(const bf16x8*)&rb[(kh)*16384 + bbase2 + (ca^16)];          \
        bv[1][0] = *(const bf16x8*)&rb[(kh)*16384 + bbase2 + 1024 + ca];        \
        bv[1][1] = *(const bf16x8*)&rb[(kh)*16384 + bbase2 + 1024 + (ca^16)];   \
      }                                                                         \
      av[0][0] = *(const bf16x8*)&rb[(kh)*16384 + abase2 + (mh)*2048 + ca];     \
      av[0][1] = *(const bf16x8*)&rb[(kh)*16384 + abase2 + (mh)*2048 + (ca^16)];\
      av[1][0] = *(const bf16x8*)&rb[(kh)*16384 + abase2 + (mh)*2048 + 1024 + ca]; \
      av[1][1] = *(const bf16x8*)&rb[(kh)*16384 + abase2 + (mh)*2048 + 1024 + (ca^16)]; \
      if (pf) stageQ(t + 1, nbuf, QIDX);                                        \
      BARSCHED();                                                               \
      __builtin_amdgcn_s_setprio(1);                                            \
      acc[(mh)*2+0][0] = MFMA32(av[0][0], bv[0][0], acc[(mh)*2+0][0]);          \
      acc[(mh)*2+0][1] = MFMA32(av[0][0], bv[1][0], acc[(mh)*2+0][1]);          \
      acc[(mh)*2+1][0] = MFMA32(av[1][0], bv[0][0], acc[(mh)*2+1][0]);          \
      acc[(mh)*2+1][1] = MFMA32(av[1][0], bv[1][0], acc[(mh)*2+1][1]);          \
      acc[(mh)*2+0][0] = MFMA32(av[0][1], bv[0][1], acc[(mh)*2+0][0]);          \
      acc[(mh)*2+0][1] = MFMA32(av[0][1], bv[1][1], acc[(mh)*2+0][1]);          \
      acc[(mh)*2+1][0] = MFMA32(av[1][1], bv[0][1], acc[(mh)*2+1][0]);          \
      acc[(mh)*2+1][1] = MFMA32(av[1][1], bv[1][1], acc[(mh)*2+1][1]);          \
      __builtin_amdgcn_s_setprio(0);                                            \
    }

  for (int t = 0; t < NT; ++t) {
    const unsigned short* rb = lds + (t & 1) * 32768;
    const int nbuf = (t & 1) ^ 1;
    const bool pf = (t + 1 < NT);

    PHASE(0, 0, 0)
    BARSCHED();
    PHASE(0, 1, 1)
    if (pf) asm volatile("s_waitcnt vmcnt(4)" ::: "memory");
    else    asm volatile("s_waitcnt vmcnt(0)" ::: "memory");
    BARSCHED();
    PHASE(1, 0, 2)
    BARSCHED();
    PHASE(1, 1, 3)
    if (pf) {
      asm volatile("s_waitcnt vmcnt(4)" ::: "memory");
      BARSCHED();
    }
  }
#undef PHASE
#undef MFMA32

  // epilogue: C/D col = l&31, row = (r&3) + 8*(r>>2) + 4*(l>>5)
#pragma unroll
  for (int mt = 0; mt < 4; ++mt) {
    const int rowb = m0 + wr * 128 + mt * 32 + 4 * (l >> 5);
#pragma unroll
    for (int nt = 0; nt < 2; ++nt) {
      const int gcol = n0 + wc * 64 + nt * 32 + l31;
      const float bz = bias[gcol];
#pragma unroll
      for (int r = 0; r < 16; ++r) {
        const int grow = rowb + (r & 3) + 8 * (r >> 2);
        const long gi = (long)grow * ldc + gcol;
        float v = acc[mt][nt][r];
        if (EPI == 0) {
          ((unsigned short*)C)[gi] = f2bf(v + bz);
        } else {
          ((float*)C)[gi] = v + bz + Res[gi];
        }
      }
    }
  }
}

// ---------------- 128-tile bf16 GEMM (batched Z-GEMM), swizzled ----------
template <int EPI>
__global__ __launch_bounds__(256) void gemm_bt(
    const unsigned short* __restrict__ Abase, const unsigned short* __restrict__ Bbase,
    void* __restrict__ Cbase, const float* __restrict__ bias, const float* __restrict__ Res,
    int lda, int ldb, int ldc, int K,
    long sAb, long sAn, long sBb, long sBn, long sCb, long sCn)
{
  __shared__ __align__(16) unsigned short As[128][32];
  __shared__ __align__(16) unsigned short Bs[128][32];

  const int zz = blockIdx.z;
  const int zb = zz >> 5, zn = zz & 31;
  const unsigned short* A  = Abase + (long)zb * sAb + (long)zn * sAn;
  const unsigned short* Bm = Bbase + (long)zb * sBb + (long)zn * sBn;
  const long coff = (long)zb * sCb + (long)zn * sCn;

  const int m0 = blockIdx.y * 128;
  const int n0 = blockIdx.x * 128;
  const int tid = threadIdx.x;
  const int wave = tid >> 6;
  const int lane = tid & 63;
  const int wr = wave >> 1, wc = wave & 1;
  const int lr = lane & 15, kq = lane >> 4;
  const int srow = wave * 16 + (lane >> 2);
  const int scol = (((lane & 3) ^ ((lane >> 3) & 3)) << 3);
  const int rch  = ((kq ^ ((lane >> 1) & 3)) << 3);

  const f32x4 zero = {0.0f, 0.0f, 0.0f, 0.0f};
  f32x4 acc[4][4];
#pragma unroll
  for (int m = 0; m < 4; ++m)
#pragma unroll
    for (int n = 0; n < 4; ++n) acc[m][n] = zero;

  for (int k0 = 0; k0 < K; k0 += 32) {
    const unsigned short* ga = A  + (long)(m0 + srow) * lda + k0 + scol;
    const unsigned short* gb = Bm + (long)(n0 + srow) * ldb + k0 + scol;
    gload_lds16(ga,                   &As[wave * 16][0]);
    gload_lds16(ga + (long)64 * lda,  &As[64 + wave * 16][0]);
    gload_lds16(gb,                   &Bs[wave * 16][0]);
    gload_lds16(gb + (long)64 * ldb,  &Bs[64 + wave * 16][0]);
    __syncthreads();

    bf16x8 av[4], bv[4];
#pragma unroll
    for (int m = 0; m < 4; ++m) av[m] = *(const bf16x8*)&As[wr * 64 + m * 16 + lr][rch];
#pragma unroll
    for (int n = 0; n < 4; ++n) bv[n] = *(const bf16x8*)&Bs[wc * 64 + n * 16 + lr][rch];
#pragma unroll
    for (int m = 0; m < 4; ++m)
#pragma unroll
      for (int n = 0; n < 4; ++n)
        acc[m][n] = __builtin_amdgcn_mfma_f32_16x16x32_bf16(av[m], bv[n], acc[m][n], 0, 0, 0);
    __syncthreads();
  }

#pragma unroll
  for (int m = 0; m < 4; ++m) {
    const int grow0 = m0 + wr * 64 + m * 16 + kq * 4;
#pragma unroll
    for (int n = 0; n < 4; ++n) {
      const int gcol = n0 + wc * 64 + n * 16 + lr;
#pragma unroll
      for (int r = 0; r < 4; ++r) {
        const long gi = coff + (long)(grow0 + r) * ldc + gcol;
        float v = acc[m][n][r];
        if (EPI == 0) {
          ((unsigned short*)Cbase)[gi] = f2bf(v + bias[gcol]);
        } else if (EPI == 1) {
          ((float*)Cbase)[gi] = v + bias[gcol] + Res[gi];
        } else {
          ((unsigned short*)Cbase)[gi] = f2bf(v);
        }
      }
    }
  }
}

// ---------------- G = Q^T Q per (b,n), chunked over s, atomic reduce ----------
__global__ __launch_bounds__(256) void compute_g(const unsigned short* __restrict__ fused,
                                                 float* __restrict__ G)
{
  __shared__ float Qs[64][128];
  const int z = blockIdx.x;            // b*32+n
  const int b = z >> 5, n = z & 31;
  const unsigned short* Q = fused + (long)b * S_ * H3_ + n * 384;
  const int t = threadIdx.x;
  const int t1 = t >> 4, t2 = t & 15;
  float acc[8][8];
#pragma unroll
  for (int a = 0; a < 8; ++a)
#pragma unroll
    for (int c = 0; c < 8; ++c) acc[a][c] = 0.f;

  const int sbeg = blockIdx.y * 128;   // 16 y-blocks x 128 s each
  for (int s0 = sbeg; s0 < sbeg + 128; s0 += 64) {
#pragma unroll
    for (int ii = 0; ii < 4; ++ii) {
      const int r = ii * 16 + t1;
      float f[8];
      unpack8(*(const uint4*)(Q + (long)(s0 + r) * H3_ + t2 * 8), f);
#pragma unroll
      for (int j = 0; j < 8; ++j) Qs[r][t2 * 8 + j] = f[j];
    }
    __syncthreads();
    for (int ss = 0; ss < 64; ++ss) {
      float qa[8], qb[8];
#pragma unroll
      for (int j = 0; j < 8; ++j) { qa[j] = Qs[ss][t1 * 8 + j]; qb[j] = Qs[ss][t2 * 8 + j]; }
#pragma unroll
      for (int a = 0; a < 8; ++a)
#pragma unroll
        for (int c = 0; c < 8; ++c) acc[a][c] += qa[a] * qb[c];
    }
    __syncthreads();
  }
  float* Gz = G + (long)z * 16384;
#pragma unroll
  for (int a = 0; a < 8; ++a)
#pragma unroll
    for (int c = 0; c < 8; ++c)
      atomicAdd(&Gz[(t1 * 8 + a) * 128 + t2 * 8 + c], acc[a][c]);
}

// ---------------- register-resident Gauss-Jordan inverse of SPD 128x128 ------
__global__ __launch_bounds__(1024) void invert_g(const float* __restrict__ G,
                                                 unsigned short* __restrict__ Ginv)
{
  __shared__ __align__(16) float prow[2][128];
  __shared__ __align__(16) float pcol[2][128];
  const int z = blockIdx.x;
  const int t = threadIdx.x;
  const int c  = t & 127;
  const int rg = t >> 7;                 // 0..7 -> rows rg*16 .. rg*16+15
  const float* Gz = G + (long)z * 16384;

  float a[16];
#pragma unroll
  for (int i = 0; i < 16; ++i) a[i] = Gz[(rg * 16 + i) * 128 + c];

  for (int p = 0; p < 128; ++p) {
    const int buf = p & 1;
    const int prg = p >> 4, pi = p & 15;
    if (rg == prg) {
      float v = a[0];
#pragma unroll
      for (int i = 1; i < 16; ++i) v = (pi == i) ? a[i] : v;
      prow[buf][c] = v;
    }
    if (c == p) {
#pragma unroll
      for (int q = 0; q < 4; ++q) {
        float4 w4 = make_float4(a[q * 4], a[q * 4 + 1], a[q * 4 + 2], a[q * 4 + 3]);
        *(float4*)&pcol[buf][rg * 16 + q * 4] = w4;
      }
    }
    __syncthreads();
    const float invp = 1.0f / prow[buf][p];
    const float rowv = (c == p) ? invp : prow[buf][c] * invp;
#pragma unroll
    for (int q = 0; q < 4; ++q) {
      const float4 pc4 = *(const float4*)&pcol[buf][rg * 16 + q * 4];
      const float pcv[4] = {pc4.x, pc4.y, pc4.z, pc4.w};
#pragma unroll
      for (int j = 0; j < 4; ++j) {
        const int i = q * 4 + j;
        const int r = rg * 16 + i;
        const float cur = (c == p) ? 0.f : a[i];
        a[i] = (r == p) ? rowv : cur - pcv[j] * rowv;
      }
    }
  }
  unsigned short* Oz = Ginv + (long)z * 16384;
#pragma unroll
  for (int i = 0; i < 16; ++i) Oz[(rg * 16 + i) * 128 + c] = f2bf(a[i]);
}

// ---------------- per-position 32x32 head attention ----------------
__global__ __launch_bounds__(256) void attn_pos(
    const unsigned short* __restrict__ fused, const unsigned short* __restrict__ Zb,
    const float* __restrict__ alibi, unsigned short* __restrict__ ctx)
{
  __shared__ __align__(16) unsigned short qkv[H3_];
  __shared__ __align__(16) unsigned short zsh[H_];
  __shared__ float wsh[NH_][NH_ + 1];
  __shared__ float pden[NH_];
  __shared__ float alib[NH_];

  const int s = blockIdx.x, b = blockIdx.y;
  const int t = threadIdx.x;
  const unsigned short* src = fused + ((long)b * S_ + s) * H3_;
  for (int i = t * 8; i < H3_; i += 2048) *(uint4*)&qkv[i] = *(const uint4*)&src[i];
  const unsigned short* zsrc = Zb + ((long)b * S_ + s) * H_;
  for (int i = t * 8; i < H_; i += 2048) *(uint4*)&zsh[i] = *(const uint4*)&zsrc[i];
  if (t < NH_) alib[t] = 0.08838834764831845f * alibi[((long)(b * NH_ + t)) * S_ + s];
  __syncthreads();

  const int i = t >> 3;
  const int j0 = (t & 7) * 4;
  const int rot = (i ^ (t & 7)) & 15;
  float aqk[4] = {0.f, 0.f, 0.f, 0.f};
  float aqz[4] = {0.f, 0.f, 0.f, 0.f};
  for (int dbi = 0; dbi < 16; ++dbi) {
    const int d0b = ((dbi + rot) & 15) * 8;
    float qf[8];
    unpack8(*(const uint4*)&qkv[i * 384 + d0b], qf);
#pragma unroll
    for (int jj = 0; jj < 4; ++jj) {
      const int j = j0 + jj;
      float kf[8], zf[8];
      unpack8(*(const uint4*)&qkv[j * 384 + 128 + d0b], kf);
      unpack8(*(const uint4*)&zsh[j * 128 + d0b], zf);
#pragma unroll
      for (int d = 0; d < 8; ++d) { aqk[jj] += qf[d] * kf[d]; aqz[jj] += qf[d] * zf[d]; }
    }
  }
  // wave-parallel softmax: 8-lane group owns row i (4 w-values per lane, in regs)
  float wv[4];
#pragma unroll
  for (int jj = 0; jj < 4; ++jj)
    wv[jj] = 0.0078125f * aqk[jj] + alib[j0 + jj] * aqz[jj];
  float vmax = fmaxf(fmaxf(wv[0], wv[1]), fmaxf(wv[2], wv[3]));
  vmax = fmaxf(vmax, __shfl_xor(vmax, 1));
  vmax = fmaxf(vmax, __shfl_xor(vmax, 2));
  vmax = fmaxf(vmax, __shfl_xor(vmax, 4));
  float ssum = 0.f;
#pragma unroll
  for (int jj = 0; jj < 4; ++jj) { wv[jj] = __expf(wv[jj] - vmax); ssum += wv[jj]; }
#pragma unroll
  for (int jj = 0; jj < 4; ++jj) wsh[i][j0 + jj] = wv[jj];
  ssum += __shfl_xor(ssum, 1);
  ssum += __shfl_xor(ssum, 2);
  ssum += __shfl_xor(ssum, 4);
  if ((t & 7) == 0) pden[i] = 1.0f / (ssum + 1e-8f);
  __syncthreads();

  const int d0 = (t & 7) * 16;
  float acc[16];
#pragma unroll
  for (int d = 0; d < 16; ++d) acc[d] = 0.f;
  for (int j = 0; j < NH_; ++j) {
    const float p = wsh[i][j];
    float vf[16];
    unpack8(*(const uint4*)&qkv[j * 384 + 256 + d0], vf);
    unpack8(*(const uint4*)&qkv[j * 384 + 256 + d0 + 8], vf + 8);
#pragma unroll
    for (int d = 0; d < 16; ++d) acc[d] += p * vf[d];
  }
  const float inv = pden[i];
  union { uint4 u[2]; unsigned short us[16]; } ov;
#pragma unroll
  for (int d = 0; d < 16; ++d) ov.us[d] = f2bf(acc[d] * inv);
  unsigned short* cp = ctx + ((long)b * S_ + s) * H_ + i * HD_ + d0;
  *(uint4*)&cp[0] = ov.u[0];
  *(uint4*)&cp[8] = ov.u[1];
}

// -----------------------------------------------------------------------------
extern "C" void kernel_launch(void* const* d_in, const int* in_sizes, int n_in,
                              void* d_out, int out_size, void* d_ws, size_t ws_size,
                              hipStream_t stream)
{
  (void)in_sizes; (void)n_in; (void)out_size; (void)ws_size;
  const float* hidden   = (const float*)d_in[0];
  const float* residual = (const float*)d_in[1];
  const float* alibi    = (const float*)d_in[2];
  const float* Wqkv     = (const float*)d_in[4];
  const float* bqkv     = (const float*)d_in[5];
  const float* Wd       = (const float*)d_in[6];
  const float* bd       = (const float*)d_in[7];
  float* out = (float*)d_out;

  char* ws = (char*)d_ws;
  size_t off = 0;
  auto carve = [&](size_t bytes) -> void* {
    void* p = ws + off;
    off += (bytes + 255) & ~(size_t)255;
    return p;
  };
  const long nHid = (long)B_ * S_ * H_;
  const long nWq  = (long)H3_ * H_;
  unsigned short* hid_bf   = (unsigned short*)carve((size_t)nHid * 2);
  unsigned short* wqkv_bf  = (unsigned short*)carve((size_t)nWq * 2);
  unsigned short* wd_bf    = (unsigned short*)carve((size_t)H_ * H_ * 2);
  unsigned short* fused_bf = (unsigned short*)carve((size_t)B_ * S_ * H3_ * 2);
  unsigned short* z_bf     = (unsigned short*)carve((size_t)nHid * 2);
  unsigned short* ctx_bf   = (unsigned short*)carve((size_t)nHid * 2);
  float*          Gbuf     = (float*)carve((size_t)64 * 16384 * 4);
  unsigned short* ginv_bf  = (unsigned short*)carve((size_t)64 * 16384 * 2);

  // 1) bf16 casts
  cvt_bf16<<<2048, 256, 0, stream>>>(hidden, hid_bf, nHid);
  cvt_bf16<<<2048, 256, 0, stream>>>(Wqkv, wqkv_bf, nWq);
  cvt_bf16<<<2048, 256, 0, stream>>>(Wd, wd_bf, (long)H_ * H_);

  // 2) fused = hidden @ Wqkv^T + b_qkv  (bf16 out) — 32x32-MFMA 256² GEMM
  gemm256<0><<<dim3(H3_ / 256, (B_ * S_) / 256, 1), 512, 0, stream>>>(
      hid_bf, wqkv_bf, fused_bf, bqkv, nullptr, H_, H_, H3_, H_);

  // 3) G = Q^T Q per (b,n); then Ginv via register-resident Gauss-Jordan
  hipMemsetAsync(Gbuf, 0, (size_t)64 * 16384 * 4, stream);
  compute_g<<<dim3(64, 16), 256, 0, stream>>>(fused_bf, Gbuf);
  invert_g<<<64, 1024, 0, stream>>>(Gbuf, ginv_bf);

  // 4) Z[b,s,n,:] = Ginv_{b,n} q_{b,n}(s)   (small batched GEMM, 128² kernel)
  gemm_bt<2><<<dim3(1, S_ / 128, 64), 256, 0, stream>>>(
      fused_bf, ginv_bf, z_bf, nullptr, nullptr, H3_, HD_, H_, HD_,
      (long)S_ * H3_, 384, (long)32 * 16384, 16384, (long)S_ * H_, HD_);

  // 5) per-position 32x32 head attention -> ctx (bf16)
  attn_pos<<<dim3(S_, B_), 256, 0, stream>>>(fused_bf, z_bf, alibi, ctx_bf);

  // 6) out = ctx @ Wd^T + b_dense + residual  (f32 out) — 32x32-MFMA 256² GEMM
  gemm256<1><<<dim3(H_ / 256, (B_ * S_) / 256, 1), 512, 0, stream>>>(
      ctx_bf, wd_bf, out, bd, residual, H_, H_, H_, H_);
}

// Round 8
// 913.600 us; speedup vs baseline: 1.4275x; 1.4275x over previous
//
#include <hip/hip_runtime.h>

#define B_  2
#define S_  2048
#define NH_ 32
#define HD_ 128
#define H_  4096
#define H3_ 12288
#define GP_ 8   // compute_g partial chunks

typedef __bf16 bf16x8 __attribute__((ext_vector_type(8)));
typedef float  f32x4  __attribute__((ext_vector_type(4)));
typedef float  f32x16 __attribute__((ext_vector_type(16)));

__device__ __forceinline__ unsigned short f2bf(float f) {
  unsigned int u = __float_as_uint(f);
  u += 0x7fffu + ((u >> 16) & 1u);
  return (unsigned short)(u >> 16);
}
__device__ __forceinline__ void unpack8(uint4 r, float f[8]) {
  f[0] = __uint_as_float(r.x << 16); f[1] = __uint_as_float(r.x & 0xffff0000u);
  f[2] = __uint_as_float(r.y << 16); f[3] = __uint_as_float(r.y & 0xffff0000u);
  f[4] = __uint_as_float(r.z << 16); f[5] = __uint_as_float(r.z & 0xffff0000u);
  f[6] = __uint_as_float(r.w << 16); f[7] = __uint_as_float(r.w & 0xffff0000u);
}
__device__ __forceinline__ void gload_lds16(const void* g, void* l) {
  __builtin_amdgcn_global_load_lds(
      (const __attribute__((address_space(1))) unsigned int*)g,
      (__attribute__((address_space(3))) unsigned int*)l, 16, 0, 0);
}

// ---------------- f32 -> bf16 convert ----------------
__global__ __launch_bounds__(256) void cvt_bf16(const float* __restrict__ in,
                                                unsigned short* __restrict__ out,
                                                long n) {
  long i = ((long)blockIdx.x * 256 + threadIdx.x) * 4;
  const long stride = (long)gridDim.x * 256 * 4;
  for (; i < n; i += stride) {
    float4 v = *(const float4*)(in + i);
    ushort4 o;
    o.x = f2bf(v.x); o.y = f2bf(v.y); o.z = f2bf(v.z); o.w = f2bf(v.w);
    *(ushort4*)(out + i) = o;
  }
}

// =============================================================================
// 256x256-tile bf16 GEMM, 32x32x16 MFMA, C[m][n] = sum_k A[m][k]*Bt[n][k]
// BK=64, FULL-TILE double buffer (128 KB). No intra-tile barriers: all reads
// of tile t hit buf[cur] (staged last tile); tile t+1 stages into buf[nbuf].
// One {vmcnt(0); barrier} per tile boundary; prefetch issued at tile top so
// the drain is covered by ~1 tile of compute. Compiler free-schedules
// ds_read <-> MFMA within the tile (kills the phase-lockstep serialization).
// EPI 0: bf16 out + bias ; EPI 1: f32 out + bias + residual
// =============================================================================
template <int EPI>
__global__ __launch_bounds__(512, 2) void gemm256(
    const unsigned short* __restrict__ A, const unsigned short* __restrict__ Bt,
    void* __restrict__ C, const float* __restrict__ bias, const float* __restrict__ Res,
    int lda, int ldb, int ldc, int K)
{
  __shared__ __align__(16) unsigned short lds[65536];   // 2 x 64 KB buffers

  const int tid = threadIdx.x;
  const int w = tid >> 6, l = tid & 63;

  // XCD-aware block swizzle (nwg % 8 == 0 at both call sites)
  const int gx = gridDim.x;
  const int nwg = gx * gridDim.y;
  const int flat = blockIdx.y * gx + blockIdx.x;
  const int swz = (flat & 7) * (nwg >> 3) + (flat >> 3);
  const int m0 = (swz / gx) * 256;
  const int n0 = (swz % gx) * 256;

  const int wr = w >> 2, wc = w & 3;      // wave tile: rows wr*128.., cols wc*64..

  // staging (linear LDS dest; pre-swizzled global source chunk)
  const int strow = tid >> 2;
  const int scs = (((tid & 3) ^ ((tid >> 3) & 3)) << 3);   // elems
  const unsigned short* ga = A  + (long)(m0 + strow) * lda + scs;
  const unsigned short* gb = Bt + (long)(n0 + strow) * ldb + scs;
  const int ldsw = w * 512;               // wave-uniform dest offset within region

  // 32x32 fragment addressing: row = l&31; logical k-chunk ks*2+(l>>5),
  // physical = logical ^ ((row>>1)&3) = ^ ((l>>1)&3)
  const int l31 = l & 31;
  const int rsw = (l >> 1) & 3;
  const int ca = (((l >> 5) ^ rsw) << 3);          // elems; ks=1 chunk = ca^16
  const int abase2 = (wr * 128 + l31) * 32;        // + mt*1024 + kh*16384 + chunk
  const int bbase2 = 8192 + (wc * 64 + l31) * 32;  // + nt*1024 + kh*16384 + chunk

  const int NT = K >> 6;                  // BK = 64

  f32x16 acc[4][2];
#pragma unroll
  for (int mt = 0; mt < 4; ++mt)
#pragma unroll
    for (int nt = 0; nt < 2; ++nt)
#pragma unroll
      for (int r = 0; r < 16; ++r) acc[mt][nt][r] = 0.f;

  // stage quarter q (0=A-kh0,1=B-kh0,2=A-kh1,3=B-kh1) of K-tile kt into buffer b
  auto stageQ = [&](int kt, int b, int q) {
    const long koff = (long)kt * 64 + (q >> 1) * 32;
    unsigned short* d = lds + b * 32768 + q * 8192 + ldsw;
    if ((q & 1) == 0) {
      gload_lds16(ga + koff,              d);
      gload_lds16(ga + koff + 128L * lda, d + 4096);
    } else {
      gload_lds16(gb + koff,              d);
      gload_lds16(gb + koff + 128L * ldb, d + 4096);
    }
  };

  stageQ(0, 0, 0); stageQ(0, 0, 1); stageQ(0, 0, 2); stageQ(0, 0, 3);
  asm volatile("s_waitcnt vmcnt(0)" ::: "memory");
  __builtin_amdgcn_s_barrier();
  __builtin_amdgcn_sched_barrier(0);

  bf16x8 av[2][2], bv[2][2];

#define MFMA32(a, b, c) __builtin_amdgcn_mfma_f32_32x32x16_bf16(a, b, c, 0, 0, 0)
#define PHASE(kh, mh)                                                           \
    {                                                                           \
      if ((mh) == 0) {                                                          \
        bv[0][0] = *(const bf16x8*)&rb[(kh)*16384 + bbase2 + ca];               \
        bv[0][1] = *(const bf16x8*)&rb[(kh)*16384 + bbase2 + (ca^16)];          \
        bv[1][0] = *(const bf16x8*)&rb[(kh)*16384 + bbase2 + 1024 + ca];        \
        bv[1][1] = *(const bf16x8*)&rb[(kh)*16384 + bbase2 + 1024 + (ca^16)];   \
      }                                                                         \
      av[0][0] = *(const bf16x8*)&rb[(kh)*16384 + abase2 + (mh)*2048 + ca];     \
      av[0][1] = *(const bf16x8*)&rb[(kh)*16384 + abase2 + (mh)*2048 + (ca^16)];\
      av[1][0] = *(const bf16x8*)&rb[(kh)*16384 + abase2 + (mh)*2048 + 1024 + ca]; \
      av[1][1] = *(const bf16x8*)&rb[(kh)*16384 + abase2 + (mh)*2048 + 1024 + (ca^16)]; \
      acc[(mh)*2+0][0] = MFMA32(av[0][0], bv[0][0], acc[(mh)*2+0][0]);          \
      acc[(mh)*2+0][1] = MFMA32(av[0][0], bv[1][0], acc[(mh)*2+0][1]);          \
      acc[(mh)*2+1][0] = MFMA32(av[1][0], bv[0][0], acc[(mh)*2+1][0]);          \
      acc[(mh)*2+1][1] = MFMA32(av[1][0], bv[1][0], acc[(mh)*2+1][1]);          \
      acc[(mh)*2+0][0] = MFMA32(av[0][1], bv[0][1], acc[(mh)*2+0][0]);          \
      acc[(mh)*2+0][1] = MFMA32(av[0][1], bv[1][1], acc[(mh)*2+0][1]);          \
      acc[(mh)*2+1][0] = MFMA32(av[1][1], bv[0][1], acc[(mh)*2+1][0]);          \
      acc[(mh)*2+1][1] = MFMA32(av[1][1], bv[1][1], acc[(mh)*2+1][1]);          \
    }

  for (int t = 0; t < NT; ++t) {
    const unsigned short* rb = lds + (t & 1) * 32768;
    const int nbuf = (t & 1) ^ 1;
    const bool pf = (t + 1 < NT);

    // prefetch next tile entirely at tile top -> full tile of latency cover
    if (pf) { stageQ(t + 1, nbuf, 0); stageQ(t + 1, nbuf, 1);
              stageQ(t + 1, nbuf, 2); stageQ(t + 1, nbuf, 3); }

    // no intra-tile barriers: compiler interleaves ds_read with MFMA
    PHASE(0, 0)
    PHASE(0, 1)
    PHASE(1, 0)
    PHASE(1, 1)

    if (pf) {
      asm volatile("s_waitcnt vmcnt(0)" ::: "memory");   // next tile resident
      __builtin_amdgcn_s_barrier();                      // all waves done w/ rb
      __builtin_amdgcn_sched_barrier(0);                 // pin the boundary
    }
  }
#undef PHASE
#undef MFMA32

  // epilogue: C/D col = l&31, row = (r&3) + 8*(r>>2) + 4*(l>>5)
#pragma unroll
  for (int mt = 0; mt < 4; ++mt) {
    const int rowb = m0 + wr * 128 + mt * 32 + 4 * (l >> 5);
#pragma unroll
    for (int nt = 0; nt < 2; ++nt) {
      const int gcol = n0 + wc * 64 + nt * 32 + l31;
      const float bz = bias[gcol];
#pragma unroll
      for (int r = 0; r < 16; ++r) {
        const int grow = rowb + (r & 3) + 8 * (r >> 2);
        const long gi = (long)grow * ldc + gcol;
        float v = acc[mt][nt][r];
        if (EPI == 0) {
          ((unsigned short*)C)[gi] = f2bf(v + bz);
        } else {
          ((float*)C)[gi] = v + bz + Res[gi];
        }
      }
    }
  }
}

// ---------------- 128-tile bf16 GEMM (batched Z-GEMM), swizzled ----------
template <int EPI>
__global__ __launch_bounds__(256) void gemm_bt(
    const unsigned short* __restrict__ Abase, const unsigned short* __restrict__ Bbase,
    void* __restrict__ Cbase, const float* __restrict__ bias, const float* __restrict__ Res,
    int lda, int ldb, int ldc, int K,
    long sAb, long sAn, long sBb, long sBn, long sCb, long sCn)
{
  __shared__ __align__(16) unsigned short As[128][32];
  __shared__ __align__(16) unsigned short Bs[128][32];

  const int zz = blockIdx.z;
  const int zb = zz >> 5, zn = zz & 31;
  const unsigned short* A  = Abase + (long)zb * sAb + (long)zn * sAn;
  const unsigned short* Bm = Bbase + (long)zb * sBb + (long)zn * sBn;
  const long coff = (long)zb * sCb + (long)zn * sCn;

  const int m0 = blockIdx.y * 128;
  const int n0 = blockIdx.x * 128;
  const int tid = threadIdx.x;
  const int wave = tid >> 6;
  const int lane = tid & 63;
  const int wr = wave >> 1, wc = wave & 1;
  const int lr = lane & 15, kq = lane >> 4;
  const int srow = wave * 16 + (lane >> 2);
  const int scol = (((lane & 3) ^ ((lane >> 3) & 3)) << 3);
  const int rch  = ((kq ^ ((lane >> 1) & 3)) << 3);

  const f32x4 zero = {0.0f, 0.0f, 0.0f, 0.0f};
  f32x4 acc[4][4];
#pragma unroll
  for (int m = 0; m < 4; ++m)
#pragma unroll
    for (int n = 0; n < 4; ++n) acc[m][n] = zero;

  for (int k0 = 0; k0 < K; k0 += 32) {
    const unsigned short* ga = A  + (long)(m0 + srow) * lda + k0 + scol;
    const unsigned short* gb = Bm + (long)(n0 + srow) * ldb + k0 + scol;
    gload_lds16(ga,                   &As[wave * 16][0]);
    gload_lds16(ga + (long)64 * lda,  &As[64 + wave * 16][0]);
    gload_lds16(gb,                   &Bs[wave * 16][0]);
    gload_lds16(gb + (long)64 * ldb,  &Bs[64 + wave * 16][0]);
    __syncthreads();

    bf16x8 av[4], bv[4];
#pragma unroll
    for (int m = 0; m < 4; ++m) av[m] = *(const bf16x8*)&As[wr * 64 + m * 16 + lr][rch];
#pragma unroll
    for (int n = 0; n < 4; ++n) bv[n] = *(const bf16x8*)&Bs[wc * 64 + n * 16 + lr][rch];
#pragma unroll
    for (int m = 0; m < 4; ++m)
#pragma unroll
      for (int n = 0; n < 4; ++n)
        acc[m][n] = __builtin_amdgcn_mfma_f32_16x16x32_bf16(av[m], bv[n], acc[m][n], 0, 0, 0);
    __syncthreads();
  }

#pragma unroll
  for (int m = 0; m < 4; ++m) {
    const int grow0 = m0 + wr * 64 + m * 16 + kq * 4;
#pragma unroll
    for (int n = 0; n < 4; ++n) {
      const int gcol = n0 + wc * 64 + n * 16 + lr;
#pragma unroll
      for (int r = 0; r < 4; ++r) {
        const long gi = coff + (long)(grow0 + r) * ldc + gcol;
        float v = acc[m][n][r];
        if (EPI == 0) {
          ((unsigned short*)Cbase)[gi] = f2bf(v + bias[gcol]);
        } else if (EPI == 1) {
          ((float*)Cbase)[gi] = v + bias[gcol] + Res[gi];
        } else {
          ((unsigned short*)Cbase)[gi] = f2bf(v);
        }
      }
    }
  }
}

// ---------------- G partials: Gpart[z][p] = Q_chunk^T Q_chunk (NO atomics) ----
__global__ __launch_bounds__(256) void compute_g(const unsigned short* __restrict__ fused,
                                                 float* __restrict__ Gpart)
{
  __shared__ float Qs[64][128];
  const int z = blockIdx.x;            // b*32+n
  const int b = z >> 5, n = z & 31;
  const unsigned short* Q = fused + (long)b * S_ * H3_ + n * 384;
  const int t = threadIdx.x;
  const int t1 = t >> 4, t2 = t & 15;
  float acc[8][8];
#pragma unroll
  for (int a = 0; a < 8; ++a)
#pragma unroll
    for (int c = 0; c < 8; ++c) acc[a][c] = 0.f;

  const int sbeg = blockIdx.y * (S_ / GP_);   // 256 rows per chunk
  for (int s0 = sbeg; s0 < sbeg + S_ / GP_; s0 += 64) {
#pragma unroll
    for (int ii = 0; ii < 4; ++ii) {
      const int r = ii * 16 + t1;
      float f[8];
      unpack8(*(const uint4*)(Q + (long)(s0 + r) * H3_ + t2 * 8), f);
#pragma unroll
      for (int j = 0; j < 8; ++j) Qs[r][t2 * 8 + j] = f[j];
    }
    __syncthreads();
    for (int ss = 0; ss < 64; ++ss) {
      float qa[8], qb[8];
#pragma unroll
      for (int j = 0; j < 8; ++j) { qa[j] = Qs[ss][t1 * 8 + j]; qb[j] = Qs[ss][t2 * 8 + j]; }
#pragma unroll
      for (int a = 0; a < 8; ++a)
#pragma unroll
        for (int c = 0; c < 8; ++c) acc[a][c] += qa[a] * qb[c];
    }
    __syncthreads();
  }
  float* Gp = Gpart + ((long)z * GP_ + blockIdx.y) * 16384;
#pragma unroll
  for (int a = 0; a < 8; ++a)
#pragma unroll
    for (int cc = 0; cc < 2; ++cc) {
      float4 v = make_float4(acc[a][cc * 4], acc[a][cc * 4 + 1],
                             acc[a][cc * 4 + 2], acc[a][cc * 4 + 3]);
      *(float4*)&Gp[(t1 * 8 + a) * 128 + t2 * 8 + cc * 4] = v;
    }
}

// ---------------- register-resident Gauss-Jordan inverse of SPD 128x128 ------
// Loads sum the GP_ partials (replaces the old atomic reduce + memset).
__global__ __launch_bounds__(1024) void invert_g(const float* __restrict__ Gpart,
                                                 unsigned short* __restrict__ Ginv)
{
  __shared__ __align__(16) float prow[2][128];
  __shared__ __align__(16) float pcol[2][128];
  const int z = blockIdx.x;
  const int t = threadIdx.x;
  const int c  = t & 127;
  const int rg = t >> 7;                 // 0..7 -> rows rg*16 .. rg*16+15
  const float* Gz = Gpart + (long)z * GP_ * 16384;

  float a[16];
#pragma unroll
  for (int i = 0; i < 16; ++i) {
    const int idx = (rg * 16 + i) * 128 + c;
    float s = 0.f;
#pragma unroll
    for (int p = 0; p < GP_; ++p) s += Gz[p * 16384 + idx];
    a[i] = s;
  }

  for (int p = 0; p < 128; ++p) {
    const int buf = p & 1;
    const int prg = p >> 4, pi = p & 15;
    if (rg == prg) {
      float v = a[0];
#pragma unroll
      for (int i = 1; i < 16; ++i) v = (pi == i) ? a[i] : v;
      prow[buf][c] = v;
    }
    if (c == p) {
#pragma unroll
      for (int q = 0; q < 4; ++q) {
        float4 w4 = make_float4(a[q * 4], a[q * 4 + 1], a[q * 4 + 2], a[q * 4 + 3]);
        *(float4*)&pcol[buf][rg * 16 + q * 4] = w4;
      }
    }
    __syncthreads();
    const float invp = 1.0f / prow[buf][p];
    const float rowv = (c == p) ? invp : prow[buf][c] * invp;
#pragma unroll
    for (int q = 0; q < 4; ++q) {
      const float4 pc4 = *(const float4*)&pcol[buf][rg * 16 + q * 4];
      const float pcv[4] = {pc4.x, pc4.y, pc4.z, pc4.w};
#pragma unroll
      for (int j = 0; j < 4; ++j) {
        const int i = q * 4 + j;
        const int r = rg * 16 + i;
        const float cur = (c == p) ? 0.f : a[i];
        a[i] = (r == p) ? rowv : cur - pcv[j] * rowv;
      }
    }
  }
  unsigned short* Oz = Ginv + (long)z * 16384;
#pragma unroll
  for (int i = 0; i < 16; ++i) Oz[(rg * 16 + i) * 128 + c] = f2bf(a[i]);
}

// ---------------- per-position 32x32 head attention ----------------
__global__ __launch_bounds__(256) void attn_pos(
    const unsigned short* __restrict__ fused, const unsigned short* __restrict__ Zb,
    const float* __restrict__ alibi, unsigned short* __restrict__ ctx)
{
  __shared__ __align__(16) unsigned short qkv[H3_];
  __shared__ __align__(16) unsigned short zsh[H_];
  __shared__ float wsh[NH_][NH_ + 1];
  __shared__ float pden[NH_];
  __shared__ float alib[NH_];

  const int s = blockIdx.x, b = blockIdx.y;
  const int t = threadIdx.x;
  const unsigned short* src = fused + ((long)b * S_ + s) * H3_;
  for (int i = t * 8; i < H3_; i += 2048) *(uint4*)&qkv[i] = *(const uint4*)&src[i];
  const unsigned short* zsrc = Zb + ((long)b * S_ + s) * H_;
  for (int i = t * 8; i < H_; i += 2048) *(uint4*)&zsh[i] = *(const uint4*)&zsrc[i];
  if (t < NH_) alib[t] = 0.08838834764831845f * alibi[((long)(b * NH_ + t)) * S_ + s];
  __syncthreads();

  const int i = t >> 3;
  const int j0 = (t & 7) * 4;
  const int rot = (i ^ (t & 7)) & 15;
  float aqk[4] = {0.f, 0.f, 0.f, 0.f};
  float aqz[4] = {0.f, 0.f, 0.f, 0.f};
  for (int dbi = 0; dbi < 16; ++dbi) {
    const int d0b = ((dbi + rot) & 15) * 8;
    float qf[8];
    unpack8(*(const uint4*)&qkv[i * 384 + d0b], qf);
#pragma unroll
    for (int jj = 0; jj < 4; ++jj) {
      const int j = j0 + jj;
      float kf[8], zf[8];
      unpack8(*(const uint4*)&qkv[j * 384 + 128 + d0b], kf);
      unpack8(*(const uint4*)&zsh[j * 128 + d0b], zf);
#pragma unroll
      for (int d = 0; d < 8; ++d) { aqk[jj] += qf[d] * kf[d]; aqz[jj] += qf[d] * zf[d]; }
    }
  }
  float wv[4];
#pragma unroll
  for (int jj = 0; jj < 4; ++jj)
    wv[jj] = 0.0078125f * aqk[jj] + alib[j0 + jj] * aqz[jj];
  float vmax = fmaxf(fmaxf(wv[0], wv[1]), fmaxf(wv[2], wv[3]));
  vmax = fmaxf(vmax, __shfl_xor(vmax, 1));
  vmax = fmaxf(vmax, __shfl_xor(vmax, 2));
  vmax = fmaxf(vmax, __shfl_xor(vmax, 4));
  float ssum = 0.f;
#pragma unroll
  for (int jj = 0; jj < 4; ++jj) { wv[jj] = __expf(wv[jj] - vmax); ssum += wv[jj]; }
#pragma unroll
  for (int jj = 0; jj < 4; ++jj) wsh[i][j0 + jj] = wv[jj];
  ssum += __shfl_xor(ssum, 1);
  ssum += __shfl_xor(ssum, 2);
  ssum += __shfl_xor(ssum, 4);
  if ((t & 7) == 0) pden[i] = 1.0f / (ssum + 1e-8f);
  __syncthreads();

  const int d0 = (t & 7) * 16;
  float acc[16];
#pragma unroll
  for (int d = 0; d < 16; ++d) acc[d] = 0.f;
  for (int j = 0; j < NH_; ++j) {
    const float p = wsh[i][j];
    float vf[16];
    unpack8(*(const uint4*)&qkv[j * 384 + 256 + d0], vf);
    unpack8(*(const uint4*)&qkv[j * 384 + 256 + d0 + 8], vf + 8);
#pragma unroll
    for (int d = 0; d < 16; ++d) acc[d] += p * vf[d];
  }
  const float inv = pden[i];
  union { uint4 u[2]; unsigned short us[16]; } ov;
#pragma unroll
  for (int d = 0; d < 16; ++d) ov.us[d] = f2bf(acc[d] * inv);
  unsigned short* cp = ctx + ((long)b * S_ + s) * H_ + i * HD_ + d0;
  *(uint4*)&cp[0] = ov.u[0];
  *(uint4*)&cp[8] = ov.u[1];
}

// -----------------------------------------------------------------------------
extern "C" void kernel_launch(void* const* d_in, const int* in_sizes, int n_in,
                              void* d_out, int out_size, void* d_ws, size_t ws_size,
                              hipStream_t stream)
{
  (void)in_sizes; (void)n_in; (void)out_size; (void)ws_size;
  const float* hidden   = (const float*)d_in[0];
  const float* residual = (const float*)d_in[1];
  const float* alibi    = (const float*)d_in[2];
  const float* Wqkv     = (const float*)d_in[4];
  const float* bqkv     = (const float*)d_in[5];
  const float* Wd       = (const float*)d_in[6];
  const float* bd       = (const float*)d_in[7];
  float* out = (float*)d_out;

  char* ws = (char*)d_ws;
  size_t off = 0;
  auto carve = [&](size_t bytes) -> void* {
    void* p = ws + off;
    off += (bytes + 255) & ~(size_t)255;
    return p;
  };
  const long nHid = (long)B_ * S_ * H_;
  const long nWq  = (long)H3_ * H_;
  unsigned short* hid_bf   = (unsigned short*)carve((size_t)nHid * 2);
  unsigned short* wqkv_bf  = (unsigned short*)carve((size_t)nWq * 2);
  unsigned short* wd_bf    = (unsigned short*)carve((size_t)H_ * H_ * 2);
  unsigned short* fused_bf = (unsigned short*)carve((size_t)B_ * S_ * H3_ * 2);
  unsigned short* z_bf     = (unsigned short*)carve((size_t)nHid * 2);
  unsigned short* ctx_bf   = (unsigned short*)carve((size_t)nHid * 2);
  float*          Gpart    = (float*)carve((size_t)64 * GP_ * 16384 * 4);
  unsigned short* ginv_bf  = (unsigned short*)carve((size_t)64 * 16384 * 2);

  // 1) bf16 casts
  cvt_bf16<<<2048, 256, 0, stream>>>(hidden, hid_bf, nHid);
  cvt_bf16<<<2048, 256, 0, stream>>>(Wqkv, wqkv_bf, nWq);
  cvt_bf16<<<2048, 256, 0, stream>>>(Wd, wd_bf, (long)H_ * H_);

  // 2) fused = hidden @ Wqkv^T + b_qkv  (bf16 out)
  gemm256<0><<<dim3(H3_ / 256, (B_ * S_) / 256, 1), 512, 0, stream>>>(
      hid_bf, wqkv_bf, fused_bf, bqkv, nullptr, H_, H_, H3_, H_);

  // 3) G partials (no atomics) -> Ginv via register Gauss-Jordan (sums partials)
  compute_g<<<dim3(64, GP_), 256, 0, stream>>>(fused_bf, Gpart);
  invert_g<<<64, 1024, 0, stream>>>(Gpart, ginv_bf);

  // 4) Z[b,s,n,:] = Ginv_{b,n} q_{b,n}(s)   (small batched GEMM, 128² kernel)
  gemm_bt<2><<<dim3(1, S_ / 128, 64), 256, 0, stream>>>(
      fused_bf, ginv_bf, z_bf, nullptr, nullptr, H3_, HD_, H_, HD_,
      (long)S_ * H3_, 384, (long)32 * 16384, 16384, (long)S_ * H_, HD_);

  // 5) per-position 32x32 head attention -> ctx (bf16)
  attn_pos<<<dim3(S_, B_), 256, 0, stream>>>(fused_bf, z_bf, alibi, ctx_bf);

  // 6) out = ctx @ Wd^T + b_dense + residual  (f32 out)
  gemm256<1><<<dim3(H_ / 256, (B_ * S_) / 256, 1), 512, 0, stream>>>(
      ctx_bf, wd_bf, out, bd, residual, H_, H_, H_, H_);
}

// Round 9
// 864.187 us; speedup vs baseline: 1.5092x; 1.0572x over previous
//
#include <hip/hip_runtime.h>

#define B_  2
#define S_  2048
#define NH_ 32
#define HD_ 128
#define H_  4096
#define H3_ 12288
#define GP_ 8   // compute_g partial chunks

typedef __bf16 bf16x8 __attribute__((ext_vector_type(8)));
typedef float  f32x4  __attribute__((ext_vector_type(4)));

__device__ __forceinline__ unsigned short f2bf(float f) {
  unsigned int u = __float_as_uint(f);
  u += 0x7fffu + ((u >> 16) & 1u);
  return (unsigned short)(u >> 16);
}
__device__ __forceinline__ void unpack8(uint4 r, float f[8]) {
  f[0] = __uint_as_float(r.x << 16); f[1] = __uint_as_float(r.x & 0xffff0000u);
  f[2] = __uint_as_float(r.y << 16); f[3] = __uint_as_float(r.y & 0xffff0000u);
  f[4] = __uint_as_float(r.z << 16); f[5] = __uint_as_float(r.z & 0xffff0000u);
  f[6] = __uint_as_float(r.w << 16); f[7] = __uint_as_float(r.w & 0xffff0000u);
}
__device__ __forceinline__ void gload_lds16(const void* g, void* l) {
  __builtin_amdgcn_global_load_lds(
      (const __attribute__((address_space(1))) unsigned int*)g,
      (__attribute__((address_space(3))) unsigned int*)l, 16, 0, 0);
}

// ---------------- f32 -> bf16 convert ----------------
__global__ __launch_bounds__(256) void cvt_bf16(const float* __restrict__ in,
                                                unsigned short* __restrict__ out,
                                                long n) {
  long i = ((long)blockIdx.x * 256 + threadIdx.x) * 4;
  const long stride = (long)gridDim.x * 256 * 4;
  for (; i < n; i += stride) {
    float4 v = *(const float4*)(in + i);
    ushort4 o;
    o.x = f2bf(v.x); o.y = f2bf(v.y); o.z = f2bf(v.z); o.w = f2bf(v.w);
    *(ushort4*)(out + i) = o;
  }
}

// =============================================================================
// 256x256-tile bf16 GEMM (round-5 best-measured structure, sched_barriers
// removed so the compiler may sink tail MFMAs past the boundary barrier and
// overlap them with next-tile ds_reads).
// 8 waves (2x4), BK=32, 3-stage LDS pipeline (96 KB) with counted vmcnt(4),
// chunk-XOR swizzle (row bits 1..2), setprio around the MFMA cluster.
// EPI 0: bf16 out + bias ; EPI 1: f32 out + bias + residual
// =============================================================================
template <int EPI>
__global__ __launch_bounds__(512, 2) void gemm256(
    const unsigned short* __restrict__ A, const unsigned short* __restrict__ Bt,
    void* __restrict__ C, const float* __restrict__ bias, const float* __restrict__ Res,
    int lda, int ldb, int ldc, int K)
{
  // 3 stages x (A: 256x32 + B: 256x32) bf16 = 96 KB
  __shared__ __align__(16) unsigned short lds[3 * 16384];

  const int tid = threadIdx.x;
  const int w = tid >> 6, l = tid & 63;

  // XCD-aware block swizzle (nwg % 8 == 0 at both call sites)
  const int gx = gridDim.x;
  const int nwg = gx * gridDim.y;
  const int flat = blockIdx.y * gx + blockIdx.x;
  const int swz = (flat & 7) * (nwg >> 3) + (flat >> 3);
  const int m0 = (swz / gx) * 256;
  const int n0 = (swz % gx) * 256;

  const int wr = w >> 2, wc = w & 3;      // wave output: rows wr*128.., cols wc*64..
  const int lr16 = l & 15, kq = l >> 4;

  // staging: lane l stages row (l>>2) of its 16-row group, physical chunk (l&3);
  // pre-swizzled source chunk = (l&3) ^ ((l>>3)&3)  [row bits 1..2]
  const int srow = w * 16 + (l >> 2);
  const int scs  = (((l & 3) ^ ((l >> 3) & 3)) << 3);   // elems
  const unsigned short* ga = A  + (long)(m0 + srow) * lda + scs;
  const unsigned short* gb = Bt + (long)(n0 + srow) * ldb + scs;
  unsigned short* sb_w = lds + w * 512;                  // wave-uniform LDS base

  // ds_read: logical chunk kq of frag-row rr at physical chunk kq^((rr>>1)&3);
  // frag rows rr = base16 + (l&15) so (rr>>1)&3 = (l>>1)&3
  const int rchunk = ((kq ^ ((l >> 1) & 3)) << 3);       // elems

  const int NT = K >> 5;

  const f32x4 zero = {0.f, 0.f, 0.f, 0.f};
  f32x4 acc[8][4];
#pragma unroll
  for (int m = 0; m < 8; ++m)
#pragma unroll
    for (int n = 0; n < 4; ++n) acc[m][n] = zero;

  auto stage = [&](int kt, int s) {
    const unsigned short* a = ga + (long)kt * 32;
    const unsigned short* b = gb + (long)kt * 32;
    unsigned short* d = sb_w + s * 16384;
    gload_lds16(a,                  d);
    gload_lds16(a + 128L * lda,     d + 4096);
    gload_lds16(b,                  d + 8192);
    gload_lds16(b + 128L * ldb,     d + 12288);
  };

  // prologue: tiles 0 and 1 in flight; wait for tile 0 only
  stage(0, 0);
  stage(1, 1);
  asm volatile("s_waitcnt vmcnt(4)" ::: "memory");
  __builtin_amdgcn_s_barrier();

  for (int t = 0; t < NT; ++t) {
    const int cur = t % 3;
    if (t + 2 < NT) stage(t + 2, (t + 2) % 3);

    const unsigned short* sa = lds + cur * 16384;
    const unsigned short* sbB = sa + 8192;
    bf16x8 av[8], bv[4];
#pragma unroll
    for (int n = 0; n < 4; ++n)
      bv[n] = *(const bf16x8*)&sbB[(wc * 64 + n * 16 + lr16) * 32 + rchunk];
#pragma unroll
    for (int m = 0; m < 8; ++m)
      av[m] = *(const bf16x8*)&sa[(wr * 128 + m * 16 + lr16) * 32 + rchunk];

    __builtin_amdgcn_s_setprio(1);
#pragma unroll
    for (int m = 0; m < 8; ++m)
#pragma unroll
      for (int n = 0; n < 4; ++n)
        acc[m][n] = __builtin_amdgcn_mfma_f32_16x16x32_bf16(av[m], bv[n], acc[m][n], 0, 0, 0);
    __builtin_amdgcn_s_setprio(0);

    if (t + 1 < NT) {
      if (t + 2 < NT) asm volatile("s_waitcnt vmcnt(4)" ::: "memory");
      else            asm volatile("s_waitcnt vmcnt(0)" ::: "memory");
      __builtin_amdgcn_s_barrier();
    }
  }

  // epilogue: C/D layout col=lane&15, row=(lane>>4)*4+i
#pragma unroll
  for (int m = 0; m < 8; ++m) {
    const int grow0 = m0 + wr * 128 + m * 16 + kq * 4;
#pragma unroll
    for (int n = 0; n < 4; ++n) {
      const int gcol = n0 + wc * 64 + n * 16 + lr16;
#pragma unroll
      for (int i = 0; i < 4; ++i) {
        const long gi = (long)(grow0 + i) * ldc + gcol;
        float v = acc[m][n][i];
        if (EPI == 0) {
          ((unsigned short*)C)[gi] = f2bf(v + bias[gcol]);
        } else {
          ((float*)C)[gi] = v + bias[gcol] + Res[gi];
        }
      }
    }
  }
}

// ---------------- 128-tile bf16 GEMM (batched Z-GEMM), swizzled ----------
template <int EPI>
__global__ __launch_bounds__(256) void gemm_bt(
    const unsigned short* __restrict__ Abase, const unsigned short* __restrict__ Bbase,
    void* __restrict__ Cbase, const float* __restrict__ bias, const float* __restrict__ Res,
    int lda, int ldb, int ldc, int K,
    long sAb, long sAn, long sBb, long sBn, long sCb, long sCn)
{
  __shared__ __align__(16) unsigned short As[128][32];
  __shared__ __align__(16) unsigned short Bs[128][32];

  const int zz = blockIdx.z;
  const int zb = zz >> 5, zn = zz & 31;
  const unsigned short* A  = Abase + (long)zb * sAb + (long)zn * sAn;
  const unsigned short* Bm = Bbase + (long)zb * sBb + (long)zn * sBn;
  const long coff = (long)zb * sCb + (long)zn * sCn;

  const int m0 = blockIdx.y * 128;
  const int n0 = blockIdx.x * 128;
  const int tid = threadIdx.x;
  const int wave = tid >> 6;
  const int lane = tid & 63;
  const int wr = wave >> 1, wc = wave & 1;
  const int lr = lane & 15, kq = lane >> 4;
  const int srow = wave * 16 + (lane >> 2);
  const int scol = (((lane & 3) ^ ((lane >> 3) & 3)) << 3);
  const int rch  = ((kq ^ ((lane >> 1) & 3)) << 3);

  const f32x4 zero = {0.0f, 0.0f, 0.0f, 0.0f};
  f32x4 acc[4][4];
#pragma unroll
  for (int m = 0; m < 4; ++m)
#pragma unroll
    for (int n = 0; n < 4; ++n) acc[m][n] = zero;

  for (int k0 = 0; k0 < K; k0 += 32) {
    const unsigned short* ga = A  + (long)(m0 + srow) * lda + k0 + scol;
    const unsigned short* gb = Bm + (long)(n0 + srow) * ldb + k0 + scol;
    gload_lds16(ga,                   &As[wave * 16][0]);
    gload_lds16(ga + (long)64 * lda,  &As[64 + wave * 16][0]);
    gload_lds16(gb,                   &Bs[wave * 16][0]);
    gload_lds16(gb + (long)64 * ldb,  &Bs[64 + wave * 16][0]);
    __syncthreads();

    bf16x8 av[4], bv[4];
#pragma unroll
    for (int m = 0; m < 4; ++m) av[m] = *(const bf16x8*)&As[wr * 64 + m * 16 + lr][rch];
#pragma unroll
    for (int n = 0; n < 4; ++n) bv[n] = *(const bf16x8*)&Bs[wc * 64 + n * 16 + lr][rch];
#pragma unroll
    for (int m = 0; m < 4; ++m)
#pragma unroll
      for (int n = 0; n < 4; ++n)
        acc[m][n] = __builtin_amdgcn_mfma_f32_16x16x32_bf16(av[m], bv[n], acc[m][n], 0, 0, 0);
    __syncthreads();
  }

#pragma unroll
  for (int m = 0; m < 4; ++m) {
    const int grow0 = m0 + wr * 64 + m * 16 + kq * 4;
#pragma unroll
    for (int n = 0; n < 4; ++n) {
      const int gcol = n0 + wc * 64 + n * 16 + lr;
#pragma unroll
      for (int r = 0; r < 4; ++r) {
        const long gi = coff + (long)(grow0 + r) * ldc + gcol;
        float v = acc[m][n][r];
        if (EPI == 0) {
          ((unsigned short*)Cbase)[gi] = f2bf(v + bias[gcol]);
        } else if (EPI == 1) {
          ((float*)Cbase)[gi] = v + bias[gcol] + Res[gi];
        } else {
          ((unsigned short*)Cbase)[gi] = f2bf(v);
        }
      }
    }
  }
}

// ---------------- G partials: Gpart[z][p] = Q_chunk^T Q_chunk (NO atomics) ----
__global__ __launch_bounds__(256) void compute_g(const unsigned short* __restrict__ fused,
                                                 float* __restrict__ Gpart)
{
  __shared__ float Qs[64][128];
  const int z = blockIdx.x;            // b*32+n
  const int b = z >> 5, n = z & 31;
  const unsigned short* Q = fused + (long)b * S_ * H3_ + n * 384;
  const int t = threadIdx.x;
  const int t1 = t >> 4, t2 = t & 15;
  float acc[8][8];
#pragma unroll
  for (int a = 0; a < 8; ++a)
#pragma unroll
    for (int c = 0; c < 8; ++c) acc[a][c] = 0.f;

  const int sbeg = blockIdx.y * (S_ / GP_);   // 256 rows per chunk
  for (int s0 = sbeg; s0 < sbeg + S_ / GP_; s0 += 64) {
#pragma unroll
    for (int ii = 0; ii < 4; ++ii) {
      const int r = ii * 16 + t1;
      float f[8];
      unpack8(*(const uint4*)(Q + (long)(s0 + r) * H3_ + t2 * 8), f);
#pragma unroll
      for (int j = 0; j < 8; ++j) Qs[r][t2 * 8 + j] = f[j];
    }
    __syncthreads();
    for (int ss = 0; ss < 64; ++ss) {
      float qa[8], qb[8];
#pragma unroll
      for (int j = 0; j < 8; ++j) { qa[j] = Qs[ss][t1 * 8 + j]; qb[j] = Qs[ss][t2 * 8 + j]; }
#pragma unroll
      for (int a = 0; a < 8; ++a)
#pragma unroll
        for (int c = 0; c < 8; ++c) acc[a][c] += qa[a] * qb[c];
    }
    __syncthreads();
  }
  float* Gp = Gpart + ((long)z * GP_ + blockIdx.y) * 16384;
#pragma unroll
  for (int a = 0; a < 8; ++a)
#pragma unroll
    for (int cc = 0; cc < 2; ++cc) {
      float4 v = make_float4(acc[a][cc * 4], acc[a][cc * 4 + 1],
                             acc[a][cc * 4 + 2], acc[a][cc * 4 + 3]);
      *(float4*)&Gp[(t1 * 8 + a) * 128 + t2 * 8 + cc * 4] = v;
    }
}

// ---------------- register-resident Gauss-Jordan inverse of SPD 128x128 ------
__global__ __launch_bounds__(1024) void invert_g(const float* __restrict__ Gpart,
                                                 unsigned short* __restrict__ Ginv)
{
  __shared__ __align__(16) float prow[2][128];
  __shared__ __align__(16) float pcol[2][128];
  const int z = blockIdx.x;
  const int t = threadIdx.x;
  const int c  = t & 127;
  const int rg = t >> 7;                 // 0..7 -> rows rg*16 .. rg*16+15
  const float* Gz = Gpart + (long)z * GP_ * 16384;

  float a[16];
#pragma unroll
  for (int i = 0; i < 16; ++i) {
    const int idx = (rg * 16 + i) * 128 + c;
    float s = 0.f;
#pragma unroll
    for (int p = 0; p < GP_; ++p) s += Gz[p * 16384 + idx];
    a[i] = s;
  }

  for (int p = 0; p < 128; ++p) {
    const int buf = p & 1;
    const int prg = p >> 4, pi = p & 15;
    if (rg == prg) {
      float v = a[0];
#pragma unroll
      for (int i = 1; i < 16; ++i) v = (pi == i) ? a[i] : v;
      prow[buf][c] = v;
    }
    if (c == p) {
#pragma unroll
      for (int q = 0; q < 4; ++q) {
        float4 w4 = make_float4(a[q * 4], a[q * 4 + 1], a[q * 4 + 2], a[q * 4 + 3]);
        *(float4*)&pcol[buf][rg * 16 + q * 4] = w4;
      }
    }
    __syncthreads();
    const float invp = 1.0f / prow[buf][p];
    const float rowv = (c == p) ? invp : prow[buf][c] * invp;
#pragma unroll
    for (int q = 0; q < 4; ++q) {
      const float4 pc4 = *(const float4*)&pcol[buf][rg * 16 + q * 4];
      const float pcv[4] = {pc4.x, pc4.y, pc4.z, pc4.w};
#pragma unroll
      for (int j = 0; j < 4; ++j) {
        const int i = q * 4 + j;
        const int r = rg * 16 + i;
        const float cur = (c == p) ? 0.f : a[i];
        a[i] = (r == p) ? rowv : cur - pcv[j] * rowv;
      }
    }
  }
  unsigned short* Oz = Ginv + (long)z * 16384;
#pragma unroll
  for (int i = 0; i < 16; ++i) Oz[(rg * 16 + i) * 128 + c] = f2bf(a[i]);
}

// ---------------- per-position 32x32 head attention ----------------
__global__ __launch_bounds__(256) void attn_pos(
    const unsigned short* __restrict__ fused, const unsigned short* __restrict__ Zb,
    const float* __restrict__ alibi, unsigned short* __restrict__ ctx)
{
  __shared__ __align__(16) unsigned short qkv[H3_];
  __shared__ __align__(16) unsigned short zsh[H_];
  __shared__ float wsh[NH_][NH_ + 1];
  __shared__ float pden[NH_];
  __shared__ float alib[NH_];

  const int s = blockIdx.x, b = blockIdx.y;
  const int t = threadIdx.x;
  const unsigned short* src = fused + ((long)b * S_ + s) * H3_;
  for (int i = t * 8; i < H3_; i += 2048) *(uint4*)&qkv[i] = *(const uint4*)&src[i];
  const unsigned short* zsrc = Zb + ((long)b * S_ + s) * H_;
  for (int i = t * 8; i < H_; i += 2048) *(uint4*)&zsh[i] = *(const uint4*)&zsrc[i];
  if (t < NH_) alib[t] = 0.08838834764831845f * alibi[((long)(b * NH_ + t)) * S_ + s];
  __syncthreads();

  const int i = t >> 3;
  const int j0 = (t & 7) * 4;
  const int rot = (i ^ (t & 7)) & 15;
  float aqk[4] = {0.f, 0.f, 0.f, 0.f};
  float aqz[4] = {0.f, 0.f, 0.f, 0.f};
  for (int dbi = 0; dbi < 16; ++dbi) {
    const int d0b = ((dbi + rot) & 15) * 8;
    float qf[8];
    unpack8(*(const uint4*)&qkv[i * 384 + d0b], qf);
#pragma unroll
    for (int jj = 0; jj < 4; ++jj) {
      const int j = j0 + jj;
      float kf[8], zf[8];
      unpack8(*(const uint4*)&qkv[j * 384 + 128 + d0b], kf);
      unpack8(*(const uint4*)&zsh[j * 128 + d0b], zf);
#pragma unroll
      for (int d = 0; d < 8; ++d) { aqk[jj] += qf[d] * kf[d]; aqz[jj] += qf[d] * zf[d]; }
    }
  }
  float wv[4];
#pragma unroll
  for (int jj = 0; jj < 4; ++jj)
    wv[jj] = 0.0078125f * aqk[jj] + alib[j0 + jj] * aqz[jj];
  float vmax = fmaxf(fmaxf(wv[0], wv[1]), fmaxf(wv[2], wv[3]));
  vmax = fmaxf(vmax, __shfl_xor(vmax, 1));
  vmax = fmaxf(vmax, __shfl_xor(vmax, 2));
  vmax = fmaxf(vmax, __shfl_xor(vmax, 4));
  float ssum = 0.f;
#pragma unroll
  for (int jj = 0; jj < 4; ++jj) { wv[jj] = __expf(wv[jj] - vmax); ssum += wv[jj]; }
#pragma unroll
  for (int jj = 0; jj < 4; ++jj) wsh[i][j0 + jj] = wv[jj];
  ssum += __shfl_xor(ssum, 1);
  ssum += __shfl_xor(ssum, 2);
  ssum += __shfl_xor(ssum, 4);
  if ((t & 7) == 0) pden[i] = 1.0f / (ssum + 1e-8f);
  __syncthreads();

  const int d0 = (t & 7) * 16;
  float acc[16];
#pragma unroll
  for (int d = 0; d < 16; ++d) acc[d] = 0.f;
  for (int j = 0; j < NH_; ++j) {
    const float p = wsh[i][j];
    float vf[16];
    unpack8(*(const uint4*)&qkv[j * 384 + 256 + d0], vf);
    unpack8(*(const uint4*)&qkv[j * 384 + 256 + d0 + 8], vf + 8);
#pragma unroll
    for (int d = 0; d < 16; ++d) acc[d] += p * vf[d];
  }
  const float inv = pden[i];
  union { uint4 u[2]; unsigned short us[16]; } ov;
#pragma unroll
  for (int d = 0; d < 16; ++d) ov.us[d] = f2bf(acc[d] * inv);
  unsigned short* cp = ctx + ((long)b * S_ + s) * H_ + i * HD_ + d0;
  *(uint4*)&cp[0] = ov.u[0];
  *(uint4*)&cp[8] = ov.u[1];
}

// -----------------------------------------------------------------------------
extern "C" void kernel_launch(void* const* d_in, const int* in_sizes, int n_in,
                              void* d_out, int out_size, void* d_ws, size_t ws_size,
                              hipStream_t stream)
{
  (void)in_sizes; (void)n_in; (void)out_size; (void)ws_size;
  const float* hidden   = (const float*)d_in[0];
  const float* residual = (const float*)d_in[1];
  const float* alibi    = (const float*)d_in[2];
  const float* Wqkv     = (const float*)d_in[4];
  const float* bqkv     = (const float*)d_in[5];
  const float* Wd       = (const float*)d_in[6];
  const float* bd       = (const float*)d_in[7];
  float* out = (float*)d_out;

  char* ws = (char*)d_ws;
  size_t off = 0;
  auto carve = [&](size_t bytes) -> void* {
    void* p = ws + off;
    off += (bytes + 255) & ~(size_t)255;
    return p;
  };
  const long nHid = (long)B_ * S_ * H_;
  const long nWq  = (long)H3_ * H_;
  unsigned short* hid_bf   = (unsigned short*)carve((size_t)nHid * 2);
  unsigned short* wqkv_bf  = (unsigned short*)carve((size_t)nWq * 2);
  unsigned short* wd_bf    = (unsigned short*)carve((size_t)H_ * H_ * 2);
  unsigned short* fused_bf = (unsigned short*)carve((size_t)B_ * S_ * H3_ * 2);
  unsigned short* z_bf     = (unsigned short*)carve((size_t)nHid * 2);
  unsigned short* ctx_bf   = (unsigned short*)carve((size_t)nHid * 2);
  float*          Gpart    = (float*)carve((size_t)64 * GP_ * 16384 * 4);
  unsigned short* ginv_bf  = (unsigned short*)carve((size_t)64 * 16384 * 2);

  // 1) bf16 casts
  cvt_bf16<<<2048, 256, 0, stream>>>(hidden, hid_bf, nHid);
  cvt_bf16<<<2048, 256, 0, stream>>>(Wqkv, wqkv_bf, nWq);
  cvt_bf16<<<2048, 256, 0, stream>>>(Wd, wd_bf, (long)H_ * H_);

  // 2) fused = hidden @ Wqkv^T + b_qkv  (bf16 out)
  gemm256<0><<<dim3(H3_ / 256, (B_ * S_) / 256, 1), 512, 0, stream>>>(
      hid_bf, wqkv_bf, fused_bf, bqkv, nullptr, H_, H_, H3_, H_);

  // 3) G partials (no atomics) -> Ginv via register Gauss-Jordan (sums partials)
  compute_g<<<dim3(64, GP_), 256, 0, stream>>>(fused_bf, Gpart);
  invert_g<<<64, 1024, 0, stream>>>(Gpart, ginv_bf);

  // 4) Z[b,s,n,:] = Ginv_{b,n} q_{b,n}(s)   (small batched GEMM, 128² kernel)
  gemm_bt<2><<<dim3(1, S_ / 128, 64), 256, 0, stream>>>(
      fused_bf, ginv_bf, z_bf, nullptr, nullptr, H3_, HD_, H_, HD_,
      (long)S_ * H3_, 384, (long)32 * 16384, 16384, (long)S_ * H_, HD_);

  // 5) per-position 32x32 head attention -> ctx (bf16)
  attn_pos<<<dim3(S_, B_), 256, 0, stream>>>(fused_bf, z_bf, alibi, ctx_bf);

  // 6) out = ctx @ Wd^T + b_dense + residual  (f32 out)
  gemm256<1><<<dim3(H_ / 256, (B_ * S_) / 256, 1), 512, 0, stream>>>(
      ctx_bf, wd_bf, out, bd, residual, H_, H_, H_, H_);
}

// Round 10
// 822.890 us; speedup vs baseline: 1.5849x; 1.0502x over previous
//
#include <hip/hip_runtime.h>

#define B_  2
#define S_  2048
#define NH_ 32
#define HD_ 128
#define H_  4096
#define H3_ 12288
#define GP_ 8   // compute_g partial chunks

typedef __bf16 bf16x8 __attribute__((ext_vector_type(8)));
typedef float  f32x4  __attribute__((ext_vector_type(4)));
typedef float  f32x16 __attribute__((ext_vector_type(16)));

__device__ __forceinline__ unsigned short f2bf(float f) {
  unsigned int u = __float_as_uint(f);
  u += 0x7fffu + ((u >> 16) & 1u);
  return (unsigned short)(u >> 16);
}
__device__ __forceinline__ void unpack8(uint4 r, float f[8]) {
  f[0] = __uint_as_float(r.x << 16); f[1] = __uint_as_float(r.x & 0xffff0000u);
  f[2] = __uint_as_float(r.y << 16); f[3] = __uint_as_float(r.y & 0xffff0000u);
  f[4] = __uint_as_float(r.z << 16); f[5] = __uint_as_float(r.z & 0xffff0000u);
  f[6] = __uint_as_float(r.w << 16); f[7] = __uint_as_float(r.w & 0xffff0000u);
}
__device__ __forceinline__ void gload_lds16(const void* g, void* l) {
  __builtin_amdgcn_global_load_lds(
      (const __attribute__((address_space(1))) unsigned int*)g,
      (__attribute__((address_space(3))) unsigned int*)l, 16, 0, 0);
}

// ---------------- fused f32 -> bf16 converts (one launch, 3 segments) --------
__device__ __forceinline__ void cvt_seg(const float* __restrict__ in,
                                        unsigned short* __restrict__ out,
                                        long n, long base, long stride) {
  for (long i = base; i < n; i += stride) {
    float4 v = *(const float4*)(in + i);
    ushort4 o;
    o.x = f2bf(v.x); o.y = f2bf(v.y); o.z = f2bf(v.z); o.w = f2bf(v.w);
    *(ushort4*)(out + i) = o;
  }
}
__global__ __launch_bounds__(256) void cvt3(
    const float* __restrict__ a, unsigned short* __restrict__ oa, long na,
    const float* __restrict__ b, unsigned short* __restrict__ ob, long nb,
    const float* __restrict__ c, unsigned short* __restrict__ oc, long nc) {
  const long base = ((long)blockIdx.x * 256 + threadIdx.x) * 4;
  const long stride = (long)gridDim.x * 256 * 4;
  cvt_seg(a, oa, na, base, stride);
  cvt_seg(b, ob, nb, base, stride);
  cvt_seg(c, oc, nc, base, stride);
}

// =============================================================================
// 256x256-tile bf16 GEMM (measured-best structure: 8 waves (2x4), BK=32,
// 3-stage LDS pipeline (96 KB), counted vmcnt(4), chunk-XOR swizzle
// (row bits 1..2), setprio around the MFMA cluster).
// EPI 0: bf16 out + bias ; EPI 1: f32 out + bias + residual
// =============================================================================
template <int EPI>
__global__ __launch_bounds__(512, 2) void gemm256(
    const unsigned short* __restrict__ A, const unsigned short* __restrict__ Bt,
    void* __restrict__ C, const float* __restrict__ bias, const float* __restrict__ Res,
    int lda, int ldb, int ldc, int K)
{
  __shared__ __align__(16) unsigned short lds[3 * 16384];

  const int tid = threadIdx.x;
  const int w = tid >> 6, l = tid & 63;

  const int gx = gridDim.x;
  const int nwg = gx * gridDim.y;
  const int flat = blockIdx.y * gx + blockIdx.x;
  const int swz = (flat & 7) * (nwg >> 3) + (flat >> 3);
  const int m0 = (swz / gx) * 256;
  const int n0 = (swz % gx) * 256;

  const int wr = w >> 2, wc = w & 3;
  const int lr16 = l & 15, kq = l >> 4;

  const int srow = w * 16 + (l >> 2);
  const int scs  = (((l & 3) ^ ((l >> 3) & 3)) << 3);
  const unsigned short* ga = A  + (long)(m0 + srow) * lda + scs;
  const unsigned short* gb = Bt + (long)(n0 + srow) * ldb + scs;
  unsigned short* sb_w = lds + w * 512;

  const int rchunk = ((kq ^ ((l >> 1) & 3)) << 3);

  const int NT = K >> 5;

  const f32x4 zero = {0.f, 0.f, 0.f, 0.f};
  f32x4 acc[8][4];
#pragma unroll
  for (int m = 0; m < 8; ++m)
#pragma unroll
    for (int n = 0; n < 4; ++n) acc[m][n] = zero;

  auto stage = [&](int kt, int s) {
    const unsigned short* a = ga + (long)kt * 32;
    const unsigned short* b = gb + (long)kt * 32;
    unsigned short* d = sb_w + s * 16384;
    gload_lds16(a,                  d);
    gload_lds16(a + 128L * lda,     d + 4096);
    gload_lds16(b,                  d + 8192);
    gload_lds16(b + 128L * ldb,     d + 12288);
  };

  stage(0, 0);
  stage(1, 1);
  asm volatile("s_waitcnt vmcnt(4)" ::: "memory");
  __builtin_amdgcn_s_barrier();

  for (int t = 0; t < NT; ++t) {
    const int cur = t % 3;
    if (t + 2 < NT) stage(t + 2, (t + 2) % 3);

    const unsigned short* sa = lds + cur * 16384;
    const unsigned short* sbB = sa + 8192;
    bf16x8 av[8], bv[4];
#pragma unroll
    for (int n = 0; n < 4; ++n)
      bv[n] = *(const bf16x8*)&sbB[(wc * 64 + n * 16 + lr16) * 32 + rchunk];
#pragma unroll
    for (int m = 0; m < 8; ++m)
      av[m] = *(const bf16x8*)&sa[(wr * 128 + m * 16 + lr16) * 32 + rchunk];

    __builtin_amdgcn_s_setprio(1);
#pragma unroll
    for (int m = 0; m < 8; ++m)
#pragma unroll
      for (int n = 0; n < 4; ++n)
        acc[m][n] = __builtin_amdgcn_mfma_f32_16x16x32_bf16(av[m], bv[n], acc[m][n], 0, 0, 0);
    __builtin_amdgcn_s_setprio(0);

    if (t + 1 < NT) {
      if (t + 2 < NT) asm volatile("s_waitcnt vmcnt(4)" ::: "memory");
      else            asm volatile("s_waitcnt vmcnt(0)" ::: "memory");
      __builtin_amdgcn_s_barrier();
    }
  }

#pragma unroll
  for (int m = 0; m < 8; ++m) {
    const int grow0 = m0 + wr * 128 + m * 16 + kq * 4;
#pragma unroll
    for (int n = 0; n < 4; ++n) {
      const int gcol = n0 + wc * 64 + n * 16 + lr16;
#pragma unroll
      for (int i = 0; i < 4; ++i) {
        const long gi = (long)(grow0 + i) * ldc + gcol;
        float v = acc[m][n][i];
        if (EPI == 0) {
          ((unsigned short*)C)[gi] = f2bf(v + bias[gcol]);
        } else {
          ((float*)C)[gi] = v + bias[gcol] + Res[gi];
        }
      }
    }
  }
}

// ---------------- 128-tile bf16 GEMM (batched Z-GEMM), swizzled ----------
template <int EPI>
__global__ __launch_bounds__(256) void gemm_bt(
    const unsigned short* __restrict__ Abase, const unsigned short* __restrict__ Bbase,
    void* __restrict__ Cbase, const float* __restrict__ bias, const float* __restrict__ Res,
    int lda, int ldb, int ldc, int K,
    long sAb, long sAn, long sBb, long sBn, long sCb, long sCn)
{
  __shared__ __align__(16) unsigned short As[128][32];
  __shared__ __align__(16) unsigned short Bs[128][32];

  const int zz = blockIdx.z;
  const int zb = zz >> 5, zn = zz & 31;
  const unsigned short* A  = Abase + (long)zb * sAb + (long)zn * sAn;
  const unsigned short* Bm = Bbase + (long)zb * sBb + (long)zn * sBn;
  const long coff = (long)zb * sCb + (long)zn * sCn;

  const int m0 = blockIdx.y * 128;
  const int n0 = blockIdx.x * 128;
  const int tid = threadIdx.x;
  const int wave = tid >> 6;
  const int lane = tid & 63;
  const int wr = wave >> 1, wc = wave & 1;
  const int lr = lane & 15, kq = lane >> 4;
  const int srow = wave * 16 + (lane >> 2);
  const int scol = (((lane & 3) ^ ((lane >> 3) & 3)) << 3);
  const int rch  = ((kq ^ ((lane >> 1) & 3)) << 3);

  const f32x4 zero = {0.0f, 0.0f, 0.0f, 0.0f};
  f32x4 acc[4][4];
#pragma unroll
  for (int m = 0; m < 4; ++m)
#pragma unroll
    for (int n = 0; n < 4; ++n) acc[m][n] = zero;

  for (int k0 = 0; k0 < K; k0 += 32) {
    const unsigned short* ga = A  + (long)(m0 + srow) * lda + k0 + scol;
    const unsigned short* gb = Bm + (long)(n0 + srow) * ldb + k0 + scol;
    gload_lds16(ga,                   &As[wave * 16][0]);
    gload_lds16(ga + (long)64 * lda,  &As[64 + wave * 16][0]);
    gload_lds16(gb,                   &Bs[wave * 16][0]);
    gload_lds16(gb + (long)64 * ldb,  &Bs[64 + wave * 16][0]);
    __syncthreads();

    bf16x8 av[4], bv[4];
#pragma unroll
    for (int m = 0; m < 4; ++m) av[m] = *(const bf16x8*)&As[wr * 64 + m * 16 + lr][rch];
#pragma unroll
    for (int n = 0; n < 4; ++n) bv[n] = *(const bf16x8*)&Bs[wc * 64 + n * 16 + lr][rch];
#pragma unroll
    for (int m = 0; m < 4; ++m)
#pragma unroll
      for (int n = 0; n < 4; ++n)
        acc[m][n] = __builtin_amdgcn_mfma_f32_16x16x32_bf16(av[m], bv[n], acc[m][n], 0, 0, 0);
    __syncthreads();
  }

#pragma unroll
  for (int m = 0; m < 4; ++m) {
    const int grow0 = m0 + wr * 64 + m * 16 + kq * 4;
#pragma unroll
    for (int n = 0; n < 4; ++n) {
      const int gcol = n0 + wc * 64 + n * 16 + lr;
#pragma unroll
      for (int r = 0; r < 4; ++r) {
        const long gi = coff + (long)(grow0 + r) * ldc + gcol;
        float v = acc[m][n][r];
        if (EPI == 0) {
          ((unsigned short*)Cbase)[gi] = f2bf(v + bias[gcol]);
        } else if (EPI == 1) {
          ((float*)Cbase)[gi] = v + bias[gcol] + Res[gi];
        } else {
          ((unsigned short*)Cbase)[gi] = f2bf(v);
        }
      }
    }
  }
}

// ---------------- G partials via MFMA: Gpart[z][p] = Q_chunk^T Q_chunk -------
// G[a][c] = sum_s Q[s][a] Q[s][c]  == MFMA with A[a][s]=Q[s][a], B[s][c]=Q[s][c].
// Q chunk staged row-major bf16 in LDS (pad to 136 elems); both fragments are
// COLUMN gathers (8x u16, stride 136 -> <=2-way banks). 4 waves x 4 tiles
// cover the 4x4 grid of 32x32 output tiles. C/D map: col=l&31,
// row=(r&3)+8*(r>>2)+4*(l>>5)  [in-situ verified rounds 6-7].
__global__ __launch_bounds__(256) void compute_g(const unsigned short* __restrict__ fused,
                                                 float* __restrict__ Gpart)
{
  __shared__ __align__(16) unsigned short Qs[64 * 136];
  const int z = blockIdx.x;            // b*32+n
  const int b = z >> 5, n = z & 31;
  const unsigned short* Q = fused + (long)b * S_ * H3_ + n * 384;
  const int t = threadIdx.x;
  const int w = t >> 6, l = t & 63;
  const int l31 = l & 31, hi = l >> 5;
  const int ar0 = (w & 1) * 2, ac0 = (w >> 1) * 2;   // wave's 2x2 tile block

  f32x16 acc[2][2];
#pragma unroll
  for (int i = 0; i < 2; ++i)
#pragma unroll
    for (int j = 0; j < 2; ++j)
#pragma unroll
      for (int r = 0; r < 16; ++r) acc[i][j][r] = 0.f;

  const int sbeg = blockIdx.y * (S_ / GP_);   // 256 rows per chunk

  for (int ss0 = 0; ss0 < S_ / GP_; ss0 += 64) {
    __syncthreads();            // previous sub-chunk's readers done
#pragma unroll
    for (int pass = 0; pass < 4; ++pass) {
      const int sL = pass * 16 + (t >> 4);
      const int c = t & 15;
      uint4 v = *(const uint4*)(Q + (long)(sbeg + ss0 + sL) * H3_ + c * 8);
      *(uint4*)&Qs[sL * 136 + c * 8] = v;
    }
    __syncthreads();

#pragma unroll
    for (int ks = 0; ks < 4; ++ks) {
      const int sb = ks * 16 + hi * 8;    // this lane-half's 8 k-slots
      bf16x8 fa[2], fb[2];
#pragma unroll
      for (int i = 0; i < 2; ++i) {
        const int colA = (ar0 + i) * 32 + l31;
        const int colB = (ac0 + i) * 32 + l31;
        bf16x8 ra, rbv;
#pragma unroll
        for (int j = 0; j < 8; ++j) {
          unsigned short ua = Qs[(sb + j) * 136 + colA];
          unsigned short ub = Qs[(sb + j) * 136 + colB];
          ra[j]  = *reinterpret_cast<__bf16*>(&ua);
          rbv[j] = *reinterpret_cast<__bf16*>(&ub);
        }
        fa[i] = ra; fb[i] = rbv;
      }
#pragma unroll
      for (int i = 0; i < 2; ++i)
#pragma unroll
        for (int j = 0; j < 2; ++j)
          acc[i][j] = __builtin_amdgcn_mfma_f32_32x32x16_bf16(fa[i], fb[j], acc[i][j], 0, 0, 0);
    }
  }

  float* Gp = Gpart + ((long)z * GP_ + blockIdx.y) * 16384;
#pragma unroll
  for (int i = 0; i < 2; ++i) {
    const int rowb = (ar0 + i) * 32 + 4 * hi;
#pragma unroll
    for (int j = 0; j < 2; ++j) {
      const int col = (ac0 + j) * 32 + l31;
#pragma unroll
      for (int r = 0; r < 16; ++r) {
        const int row = rowb + (r & 3) + 8 * (r >> 2);
        Gp[row * 128 + col] = acc[i][j][r];
      }
    }
  }
}

// ---------------- register-resident Gauss-Jordan inverse of SPD 128x128 ------
__global__ __launch_bounds__(1024) void invert_g(const float* __restrict__ Gpart,
                                                 unsigned short* __restrict__ Ginv)
{
  __shared__ __align__(16) float prow[2][128];
  __shared__ __align__(16) float pcol[2][128];
  const int z = blockIdx.x;
  const int t = threadIdx.x;
  const int c  = t & 127;
  const int rg = t >> 7;
  const float* Gz = Gpart + (long)z * GP_ * 16384;

  float a[16];
#pragma unroll
  for (int i = 0; i < 16; ++i) {
    const int idx = (rg * 16 + i) * 128 + c;
    float s = 0.f;
#pragma unroll
    for (int p = 0; p < GP_; ++p) s += Gz[p * 16384 + idx];
    a[i] = s;
  }

  for (int p = 0; p < 128; ++p) {
    const int buf = p & 1;
    const int prg = p >> 4, pi = p & 15;
    if (rg == prg) {
      float v = a[0];
#pragma unroll
      for (int i = 1; i < 16; ++i) v = (pi == i) ? a[i] : v;
      prow[buf][c] = v;
    }
    if (c == p) {
#pragma unroll
      for (int q = 0; q < 4; ++q) {
        float4 w4 = make_float4(a[q * 4], a[q * 4 + 1], a[q * 4 + 2], a[q * 4 + 3]);
        *(float4*)&pcol[buf][rg * 16 + q * 4] = w4;
      }
    }
    __syncthreads();
    const float invp = 1.0f / prow[buf][p];
    const float rowv = (c == p) ? invp : prow[buf][c] * invp;
#pragma unroll
    for (int q = 0; q < 4; ++q) {
      const float4 pc4 = *(const float4*)&pcol[buf][rg * 16 + q * 4];
      const float pcv[4] = {pc4.x, pc4.y, pc4.z, pc4.w};
#pragma unroll
      for (int j = 0; j < 4; ++j) {
        const int i = q * 4 + j;
        const int r = rg * 16 + i;
        const float cur = (c == p) ? 0.f : a[i];
        a[i] = (r == p) ? rowv : cur - pcv[j] * rowv;
      }
    }
  }
  unsigned short* Oz = Ginv + (long)z * 16384;
#pragma unroll
  for (int i = 0; i < 16; ++i) Oz[(rg * 16 + i) * 128 + c] = f2bf(a[i]);
}

// ---------------- per-position 32x32 head attention ----------------
__global__ __launch_bounds__(256) void attn_pos(
    const unsigned short* __restrict__ fused, const unsigned short* __restrict__ Zb,
    const float* __restrict__ alibi, unsigned short* __restrict__ ctx)
{
  __shared__ __align__(16) unsigned short qkv[H3_];
  __shared__ __align__(16) unsigned short zsh[H_];
  __shared__ float wsh[NH_][NH_ + 1];
  __shared__ float pden[NH_];
  __shared__ float alib[NH_];

  const int s = blockIdx.x, b = blockIdx.y;
  const int t = threadIdx.x;
  const unsigned short* src = fused + ((long)b * S_ + s) * H3_;
  for (int i = t * 8; i < H3_; i += 2048) *(uint4*)&qkv[i] = *(const uint4*)&src[i];
  const unsigned short* zsrc = Zb + ((long)b * S_ + s) * H_;
  for (int i = t * 8; i < H_; i += 2048) *(uint4*)&zsh[i] = *(const uint4*)&zsrc[i];
  if (t < NH_) alib[t] = 0.08838834764831845f * alibi[((long)(b * NH_ + t)) * S_ + s];
  __syncthreads();

  const int i = t >> 3;
  const int j0 = (t & 7) * 4;
  const int rot = (i ^ (t & 7)) & 15;
  float aqk[4] = {0.f, 0.f, 0.f, 0.f};
  float aqz[4] = {0.f, 0.f, 0.f, 0.f};
  for (int dbi = 0; dbi < 16; ++dbi) {
    const int d0b = ((dbi + rot) & 15) * 8;
    float qf[8];
    unpack8(*(const uint4*)&qkv[i * 384 + d0b], qf);
#pragma unroll
    for (int jj = 0; jj < 4; ++jj) {
      const int j = j0 + jj;
      float kf[8], zf[8];
      unpack8(*(const uint4*)&qkv[j * 384 + 128 + d0b], kf);
      unpack8(*(const uint4*)&zsh[j * 128 + d0b], zf);
#pragma unroll
      for (int d = 0; d < 8; ++d) { aqk[jj] += qf[d] * kf[d]; aqz[jj] += qf[d] * zf[d]; }
    }
  }
  float wv[4];
#pragma unroll
  for (int jj = 0; jj < 4; ++jj)
    wv[jj] = 0.0078125f * aqk[jj] + alib[j0 + jj] * aqz[jj];
  float vmax = fmaxf(fmaxf(wv[0], wv[1]), fmaxf(wv[2], wv[3]));
  vmax = fmaxf(vmax, __shfl_xor(vmax, 1));
  vmax = fmaxf(vmax, __shfl_xor(vmax, 2));
  vmax = fmaxf(vmax, __shfl_xor(vmax, 4));
  float ssum = 0.f;
#pragma unroll
  for (int jj = 0; jj < 4; ++jj) { wv[jj] = __expf(wv[jj] - vmax); ssum += wv[jj]; }
#pragma unroll
  for (int jj = 0; jj < 4; ++jj) wsh[i][j0 + jj] = wv[jj];
  ssum += __shfl_xor(ssum, 1);
  ssum += __shfl_xor(ssum, 2);
  ssum += __shfl_xor(ssum, 4);
  if ((t & 7) == 0) pden[i] = 1.0f / (ssum + 1e-8f);
  __syncthreads();

  const int d0 = (t & 7) * 16;
  float acc[16];
#pragma unroll
  for (int d = 0; d < 16; ++d) acc[d] = 0.f;
  for (int j = 0; j < NH_; ++j) {
    const float p = wsh[i][j];
    float vf[16];
    unpack8(*(const uint4*)&qkv[j * 384 + 256 + d0], vf);
    unpack8(*(const uint4*)&qkv[j * 384 + 256 + d0 + 8], vf + 8);
#pragma unroll
    for (int d = 0; d < 16; ++d) acc[d] += p * vf[d];
  }
  const float inv = pden[i];
  union { uint4 u[2]; unsigned short us[16]; } ov;
#pragma unroll
  for (int d = 0; d < 16; ++d) ov.us[d] = f2bf(acc[d] * inv);
  unsigned short* cp = ctx + ((long)b * S_ + s) * H_ + i * HD_ + d0;
  *(uint4*)&cp[0] = ov.u[0];
  *(uint4*)&cp[8] = ov.u[1];
}

// -----------------------------------------------------------------------------
extern "C" void kernel_launch(void* const* d_in, const int* in_sizes, int n_in,
                              void* d_out, int out_size, void* d_ws, size_t ws_size,
                              hipStream_t stream)
{
  (void)in_sizes; (void)n_in; (void)out_size; (void)ws_size;
  const float* hidden   = (const float*)d_in[0];
  const float* residual = (const float*)d_in[1];
  const float* alibi    = (const float*)d_in[2];
  const float* Wqkv     = (const float*)d_in[4];
  const float* bqkv     = (const float*)d_in[5];
  const float* Wd       = (const float*)d_in[6];
  const float* bd       = (const float*)d_in[7];
  float* out = (float*)d_out;

  char* ws = (char*)d_ws;
  size_t off = 0;
  auto carve = [&](size_t bytes) -> void* {
    void* p = ws + off;
    off += (bytes + 255) & ~(size_t)255;
    return p;
  };
  const long nHid = (long)B_ * S_ * H_;
  const long nWq  = (long)H3_ * H_;
  unsigned short* hid_bf   = (unsigned short*)carve((size_t)nHid * 2);
  unsigned short* wqkv_bf  = (unsigned short*)carve((size_t)nWq * 2);
  unsigned short* wd_bf    = (unsigned short*)carve((size_t)H_ * H_ * 2);
  unsigned short* fused_bf = (unsigned short*)carve((size_t)B_ * S_ * H3_ * 2);
  unsigned short* z_bf     = (unsigned short*)carve((size_t)nHid * 2);
  unsigned short* ctx_bf   = (unsigned short*)carve((size_t)nHid * 2);
  float*          Gpart    = (float*)carve((size_t)64 * GP_ * 16384 * 4);
  unsigned short* ginv_bf  = (unsigned short*)carve((size_t)64 * 16384 * 2);

  // 1) bf16 casts (single launch, 3 segments)
  cvt3<<<2048, 256, 0, stream>>>(hidden, hid_bf, nHid,
                                 Wqkv, wqkv_bf, nWq,
                                 Wd, wd_bf, (long)H_ * H_);

  // 2) fused = hidden @ Wqkv^T + b_qkv  (bf16 out)
  gemm256<0><<<dim3(H3_ / 256, (B_ * S_) / 256, 1), 512, 0, stream>>>(
      hid_bf, wqkv_bf, fused_bf, bqkv, nullptr, H_, H_, H3_, H_);

  // 3) G partials via MFMA -> Ginv via register Gauss-Jordan (sums partials)
  compute_g<<<dim3(64, GP_), 256, 0, stream>>>(fused_bf, Gpart);
  invert_g<<<64, 1024, 0, stream>>>(Gpart, ginv_bf);

  // 4) Z[b,s,n,:] = Ginv_{b,n} q_{b,n}(s)   (small batched GEMM, 128² kernel)
  gemm_bt<2><<<dim3(1, S_ / 128, 64), 256, 0, stream>>>(
      fused_bf, ginv_bf, z_bf, nullptr, nullptr, H3_, HD_, H_, HD_,
      (long)S_ * H3_, 384, (long)32 * 16384, 16384, (long)S_ * H_, HD_);

  // 5) per-position 32x32 head attention -> ctx (bf16)
  attn_pos<<<dim3(S_, B_), 256, 0, stream>>>(fused_bf, z_bf, alibi, ctx_bf);

  // 6) out = ctx @ Wd^T + b_dense + residual  (f32 out)
  gemm256<1><<<dim3(H_ / 256, (B_ * S_) / 256, 1), 512, 0, stream>>>(
      ctx_bf, wd_bf, out, bd, residual, H_, H_, H_, H_);
}

// Round 11
// 792.706 us; speedup vs baseline: 1.6452x; 1.0381x over previous
//
#include <hip/hip_runtime.h>

#define B_  2
#define S_  2048
#define NH_ 32
#define HD_ 128
#define H_  4096
#define H3_ 12288
#define GP_ 8   // compute_g partial chunks

typedef __bf16 bf16x8 __attribute__((ext_vector_type(8)));
typedef float  f32x4  __attribute__((ext_vector_type(4)));
typedef float  f32x16 __attribute__((ext_vector_type(16)));

__device__ __forceinline__ unsigned short f2bf(float f) {
  unsigned int u = __float_as_uint(f);
  u += 0x7fffu + ((u >> 16) & 1u);
  return (unsigned short)(u >> 16);
}
__device__ __forceinline__ void unpack8(uint4 r, float f[8]) {
  f[0] = __uint_as_float(r.x << 16); f[1] = __uint_as_float(r.x & 0xffff0000u);
  f[2] = __uint_as_float(r.y << 16); f[3] = __uint_as_float(r.y & 0xffff0000u);
  f[4] = __uint_as_float(r.z << 16); f[5] = __uint_as_float(r.z & 0xffff0000u);
  f[6] = __uint_as_float(r.w << 16); f[7] = __uint_as_float(r.w & 0xffff0000u);
}
__device__ __forceinline__ void gload_lds16(const void* g, void* l) {
  __builtin_amdgcn_global_load_lds(
      (const __attribute__((address_space(1))) unsigned int*)g,
      (__attribute__((address_space(3))) unsigned int*)l, 16, 0, 0);
}

// ---------------- fused f32 -> bf16 converts (one launch, 3 segments) --------
__device__ __forceinline__ void cvt_seg(const float* __restrict__ in,
                                        unsigned short* __restrict__ out,
                                        long n, long base, long stride) {
  for (long i = base; i < n; i += stride) {
    float4 v = *(const float4*)(in + i);
    ushort4 o;
    o.x = f2bf(v.x); o.y = f2bf(v.y); o.z = f2bf(v.z); o.w = f2bf(v.w);
    *(ushort4*)(out + i) = o;
  }
}
__global__ __launch_bounds__(256) void cvt3(
    const float* __restrict__ a, unsigned short* __restrict__ oa, long na,
    const float* __restrict__ b, unsigned short* __restrict__ ob, long nb,
    const float* __restrict__ c, unsigned short* __restrict__ oc, long nc) {
  const long base = ((long)blockIdx.x * 256 + threadIdx.x) * 4;
  const long stride = (long)gridDim.x * 256 * 4;
  cvt_seg(a, oa, na, base, stride);
  cvt_seg(b, ob, nb, base, stride);
  cvt_seg(c, oc, nc, base, stride);
}

// =============================================================================
// 256x256-tile bf16 GEMM (measured-best structure: 8 waves (2x4), BK=32,
// 3-stage LDS pipeline (96 KB), counted vmcnt(4), chunk-XOR swizzle
// (row bits 1..2), setprio around the MFMA cluster).
// EPI 0: bf16 out + bias ; EPI 1: f32 out + bias + residual
// =============================================================================
template <int EPI>
__global__ __launch_bounds__(512, 2) void gemm256(
    const unsigned short* __restrict__ A, const unsigned short* __restrict__ Bt,
    void* __restrict__ C, const float* __restrict__ bias, const float* __restrict__ Res,
    int lda, int ldb, int ldc, int K)
{
  __shared__ __align__(16) unsigned short lds[3 * 16384];

  const int tid = threadIdx.x;
  const int w = tid >> 6, l = tid & 63;

  const int gx = gridDim.x;
  const int nwg = gx * gridDim.y;
  const int flat = blockIdx.y * gx + blockIdx.x;
  const int swz = (flat & 7) * (nwg >> 3) + (flat >> 3);
  const int m0 = (swz / gx) * 256;
  const int n0 = (swz % gx) * 256;

  const int wr = w >> 2, wc = w & 3;
  const int lr16 = l & 15, kq = l >> 4;

  const int srow = w * 16 + (l >> 2);
  const int scs  = (((l & 3) ^ ((l >> 3) & 3)) << 3);
  const unsigned short* ga = A  + (long)(m0 + srow) * lda + scs;
  const unsigned short* gb = Bt + (long)(n0 + srow) * ldb + scs;
  unsigned short* sb_w = lds + w * 512;

  const int rchunk = ((kq ^ ((l >> 1) & 3)) << 3);

  const int NT = K >> 5;

  const f32x4 zero = {0.f, 0.f, 0.f, 0.f};
  f32x4 acc[8][4];
#pragma unroll
  for (int m = 0; m < 8; ++m)
#pragma unroll
    for (int n = 0; n < 4; ++n) acc[m][n] = zero;

  auto stage = [&](int kt, int s) {
    const unsigned short* a = ga + (long)kt * 32;
    const unsigned short* b = gb + (long)kt * 32;
    unsigned short* d = sb_w + s * 16384;
    gload_lds16(a,                  d);
    gload_lds16(a + 128L * lda,     d + 4096);
    gload_lds16(b,                  d + 8192);
    gload_lds16(b + 128L * ldb,     d + 12288);
  };

  stage(0, 0);
  stage(1, 1);
  asm volatile("s_waitcnt vmcnt(4)" ::: "memory");
  __builtin_amdgcn_s_barrier();

  for (int t = 0; t < NT; ++t) {
    const int cur = t % 3;
    if (t + 2 < NT) stage(t + 2, (t + 2) % 3);

    const unsigned short* sa = lds + cur * 16384;
    const unsigned short* sbB = sa + 8192;
    bf16x8 av[8], bv[4];
#pragma unroll
    for (int n = 0; n < 4; ++n)
      bv[n] = *(const bf16x8*)&sbB[(wc * 64 + n * 16 + lr16) * 32 + rchunk];
#pragma unroll
    for (int m = 0; m < 8; ++m)
      av[m] = *(const bf16x8*)&sa[(wr * 128 + m * 16 + lr16) * 32 + rchunk];

    __builtin_amdgcn_s_setprio(1);
#pragma unroll
    for (int m = 0; m < 8; ++m)
#pragma unroll
      for (int n = 0; n < 4; ++n)
        acc[m][n] = __builtin_amdgcn_mfma_f32_16x16x32_bf16(av[m], bv[n], acc[m][n], 0, 0, 0);
    __builtin_amdgcn_s_setprio(0);

    if (t + 1 < NT) {
      if (t + 2 < NT) asm volatile("s_waitcnt vmcnt(4)" ::: "memory");
      else            asm volatile("s_waitcnt vmcnt(0)" ::: "memory");
      __builtin_amdgcn_s_barrier();
    }
  }

#pragma unroll
  for (int m = 0; m < 8; ++m) {
    const int grow0 = m0 + wr * 128 + m * 16 + kq * 4;
#pragma unroll
    for (int n = 0; n < 4; ++n) {
      const int gcol = n0 + wc * 64 + n * 16 + lr16;
#pragma unroll
      for (int i = 0; i < 4; ++i) {
        const long gi = (long)(grow0 + i) * ldc + gcol;
        float v = acc[m][n][i];
        if (EPI == 0) {
          ((unsigned short*)C)[gi] = f2bf(v + bias[gcol]);
        } else {
          ((float*)C)[gi] = v + bias[gcol] + Res[gi];
        }
      }
    }
  }
}

// ---------------- 128-tile bf16 GEMM (batched Z-GEMM), swizzled ----------
template <int EPI>
__global__ __launch_bounds__(256) void gemm_bt(
    const unsigned short* __restrict__ Abase, const unsigned short* __restrict__ Bbase,
    void* __restrict__ Cbase, const float* __restrict__ bias, const float* __restrict__ Res,
    int lda, int ldb, int ldc, int K,
    long sAb, long sAn, long sBb, long sBn, long sCb, long sCn)
{
  __shared__ __align__(16) unsigned short As[128][32];
  __shared__ __align__(16) unsigned short Bs[128][32];

  const int zz = blockIdx.z;
  const int zb = zz >> 5, zn = zz & 31;
  const unsigned short* A  = Abase + (long)zb * sAb + (long)zn * sAn;
  const unsigned short* Bm = Bbase + (long)zb * sBb + (long)zn * sBn;
  const long coff = (long)zb * sCb + (long)zn * sCn;

  const int m0 = blockIdx.y * 128;
  const int n0 = blockIdx.x * 128;
  const int tid = threadIdx.x;
  const int wave = tid >> 6;
  const int lane = tid & 63;
  const int wr = wave >> 1, wc = wave & 1;
  const int lr = lane & 15, kq = lane >> 4;
  const int srow = wave * 16 + (lane >> 2);
  const int scol = (((lane & 3) ^ ((lane >> 3) & 3)) << 3);
  const int rch  = ((kq ^ ((lane >> 1) & 3)) << 3);

  const f32x4 zero = {0.0f, 0.0f, 0.0f, 0.0f};
  f32x4 acc[4][4];
#pragma unroll
  for (int m = 0; m < 4; ++m)
#pragma unroll
    for (int n = 0; n < 4; ++n) acc[m][n] = zero;

  for (int k0 = 0; k0 < K; k0 += 32) {
    const unsigned short* ga = A  + (long)(m0 + srow) * lda + k0 + scol;
    const unsigned short* gb = Bm + (long)(n0 + srow) * ldb + k0 + scol;
    gload_lds16(ga,                   &As[wave * 16][0]);
    gload_lds16(ga + (long)64 * lda,  &As[64 + wave * 16][0]);
    gload_lds16(gb,                   &Bs[wave * 16][0]);
    gload_lds16(gb + (long)64 * ldb,  &Bs[64 + wave * 16][0]);
    __syncthreads();

    bf16x8 av[4], bv[4];
#pragma unroll
    for (int m = 0; m < 4; ++m) av[m] = *(const bf16x8*)&As[wr * 64 + m * 16 + lr][rch];
#pragma unroll
    for (int n = 0; n < 4; ++n) bv[n] = *(const bf16x8*)&Bs[wc * 64 + n * 16 + lr][rch];
#pragma unroll
    for (int m = 0; m < 4; ++m)
#pragma unroll
      for (int n = 0; n < 4; ++n)
        acc[m][n] = __builtin_amdgcn_mfma_f32_16x16x32_bf16(av[m], bv[n], acc[m][n], 0, 0, 0);
    __syncthreads();
  }

#pragma unroll
  for (int m = 0; m < 4; ++m) {
    const int grow0 = m0 + wr * 64 + m * 16 + kq * 4;
#pragma unroll
    for (int n = 0; n < 4; ++n) {
      const int gcol = n0 + wc * 64 + n * 16 + lr;
#pragma unroll
      for (int r = 0; r < 4; ++r) {
        const long gi = coff + (long)(grow0 + r) * ldc + gcol;
        float v = acc[m][n][r];
        if (EPI == 0) {
          ((unsigned short*)Cbase)[gi] = f2bf(v + bias[gcol]);
        } else if (EPI == 1) {
          ((float*)Cbase)[gi] = v + bias[gcol] + Res[gi];
        } else {
          ((unsigned short*)Cbase)[gi] = f2bf(v);
        }
      }
    }
  }
}

// ---------------- G partials via MFMA: Gpart[z][p] = Q_chunk^T Q_chunk -------
__global__ __launch_bounds__(256) void compute_g(const unsigned short* __restrict__ fused,
                                                 float* __restrict__ Gpart)
{
  __shared__ __align__(16) unsigned short Qs[64 * 136];
  const int z = blockIdx.x;            // b*32+n
  const int b = z >> 5, n = z & 31;
  const unsigned short* Q = fused + (long)b * S_ * H3_ + n * 384;
  const int t = threadIdx.x;
  const int w = t >> 6, l = t & 63;
  const int l31 = l & 31, hi = l >> 5;
  const int ar0 = (w & 1) * 2, ac0 = (w >> 1) * 2;

  f32x16 acc[2][2];
#pragma unroll
  for (int i = 0; i < 2; ++i)
#pragma unroll
    for (int j = 0; j < 2; ++j)
#pragma unroll
      for (int r = 0; r < 16; ++r) acc[i][j][r] = 0.f;

  const int sbeg = blockIdx.y * (S_ / GP_);

  for (int ss0 = 0; ss0 < S_ / GP_; ss0 += 64) {
    __syncthreads();
#pragma unroll
    for (int pass = 0; pass < 4; ++pass) {
      const int sL = pass * 16 + (t >> 4);
      const int c = t & 15;
      uint4 v = *(const uint4*)(Q + (long)(sbeg + ss0 + sL) * H3_ + c * 8);
      *(uint4*)&Qs[sL * 136 + c * 8] = v;
    }
    __syncthreads();

#pragma unroll
    for (int ks = 0; ks < 4; ++ks) {
      const int sb = ks * 16 + hi * 8;
      bf16x8 fa[2], fb[2];
#pragma unroll
      for (int i = 0; i < 2; ++i) {
        const int colA = (ar0 + i) * 32 + l31;
        const int colB = (ac0 + i) * 32 + l31;
        bf16x8 ra, rbv;
#pragma unroll
        for (int j = 0; j < 8; ++j) {
          unsigned short ua = Qs[(sb + j) * 136 + colA];
          unsigned short ub = Qs[(sb + j) * 136 + colB];
          ra[j]  = *reinterpret_cast<__bf16*>(&ua);
          rbv[j] = *reinterpret_cast<__bf16*>(&ub);
        }
        fa[i] = ra; fb[i] = rbv;
      }
#pragma unroll
      for (int i = 0; i < 2; ++i)
#pragma unroll
        for (int j = 0; j < 2; ++j)
          acc[i][j] = __builtin_amdgcn_mfma_f32_32x32x16_bf16(fa[i], fb[j], acc[i][j], 0, 0, 0);
    }
  }

  float* Gp = Gpart + ((long)z * GP_ + blockIdx.y) * 16384;
#pragma unroll
  for (int i = 0; i < 2; ++i) {
    const int rowb = (ar0 + i) * 32 + 4 * hi;
#pragma unroll
    for (int j = 0; j < 2; ++j) {
      const int col = (ac0 + j) * 32 + l31;
#pragma unroll
      for (int r = 0; r < 16; ++r) {
        const int row = rowb + (r & 3) + 8 * (r >> 2);
        Gp[row * 128 + col] = acc[i][j][r];
      }
    }
  }
}

// ---------------- register-resident Gauss-Jordan inverse of SPD 128x128 ------
__global__ __launch_bounds__(1024) void invert_g(const float* __restrict__ Gpart,
                                                 unsigned short* __restrict__ Ginv)
{
  __shared__ __align__(16) float prow[2][128];
  __shared__ __align__(16) float pcol[2][128];
  const int z = blockIdx.x;
  const int t = threadIdx.x;
  const int c  = t & 127;
  const int rg = t >> 7;
  const float* Gz = Gpart + (long)z * GP_ * 16384;

  float a[16];
#pragma unroll
  for (int i = 0; i < 16; ++i) {
    const int idx = (rg * 16 + i) * 128 + c;
    float s = 0.f;
#pragma unroll
    for (int p = 0; p < GP_; ++p) s += Gz[p * 16384 + idx];
    a[i] = s;
  }

  for (int p = 0; p < 128; ++p) {
    const int buf = p & 1;
    const int prg = p >> 4, pi = p & 15;
    if (rg == prg) {
      float v = a[0];
#pragma unroll
      for (int i = 1; i < 16; ++i) v = (pi == i) ? a[i] : v;
      prow[buf][c] = v;
    }
    if (c == p) {
#pragma unroll
      for (int q = 0; q < 4; ++q) {
        float4 w4 = make_float4(a[q * 4], a[q * 4 + 1], a[q * 4 + 2], a[q * 4 + 3]);
        *(float4*)&pcol[buf][rg * 16 + q * 4] = w4;
      }
    }
    __syncthreads();
    const float invp = 1.0f / prow[buf][p];
    const float rowv = (c == p) ? invp : prow[buf][c] * invp;
#pragma unroll
    for (int q = 0; q < 4; ++q) {
      const float4 pc4 = *(const float4*)&pcol[buf][rg * 16 + q * 4];
      const float pcv[4] = {pc4.x, pc4.y, pc4.z, pc4.w};
#pragma unroll
      for (int j = 0; j < 4; ++j) {
        const int i = q * 4 + j;
        const int r = rg * 16 + i;
        const float cur = (c == p) ? 0.f : a[i];
        a[i] = (r == p) ? rowv : cur - pcv[j] * rowv;
      }
    }
  }
  unsigned short* Oz = Ginv + (long)z * 16384;
#pragma unroll
  for (int i = 0; i < 16; ++i) Oz[(rg * 16 + i) * 128 + c] = f2bf(a[i]);
}

// ---------------- per-position 32x32 head attention (K' precompute) ----------
// K'[j][d] = k_j[d]/128 + (scale*alibi_j)*z_j[d] built ONCE per position into
// bf16 LDS; w[i][j] = q_i . K'_j. q/v staged via per-lane-source gload_lds
// into linear [32][128] LDS. Halves both LDS reads and FMA vs the naive form.
__global__ __launch_bounds__(256) void attn_pos(
    const unsigned short* __restrict__ fused, const unsigned short* __restrict__ Zb,
    const float* __restrict__ alibi, unsigned short* __restrict__ ctx)
{
  __shared__ __align__(16) unsigned short q_s[32 * 128];   // 8 KB
  __shared__ __align__(16) unsigned short v_s[32 * 128];   // 8 KB
  __shared__ __align__(16) unsigned short kp[32 * 136];    // 8.5 KB (pad 8)
  __shared__ float wsh[NH_][NH_ + 1];
  __shared__ float pden[NH_];
  __shared__ float alib[NH_];

  const int s = blockIdx.x, b = blockIdx.y;
  const int t = threadIdx.x;
  const int w = t >> 6;
  const unsigned short* src = fused + ((long)b * S_ + s) * H3_;

  if (t < NH_) alib[t] = 0.08838834764831845f * alibi[((long)(b * NH_ + t)) * S_ + s];

  // async stage q and v into linear [head][d] LDS: thread t covers
  // (head = t>>4, chunk = t&15) and (head+16, chunk). LDS elem offset = t*8.
  {
    const int i0 = t >> 4, c = t & 15;
    gload_lds16(src + i0 * 384 + c * 8,              (char*)q_s + w * 1024);
    gload_lds16(src + (i0 + 16) * 384 + c * 8,       (char*)q_s + 4096 + w * 1024);
    gload_lds16(src + i0 * 384 + 256 + c * 8,        (char*)v_s + w * 1024);
    gload_lds16(src + (i0 + 16) * 384 + 256 + c * 8, (char*)v_s + 4096 + w * 1024);
  }

  // K' inputs from global (each element read once)
  const int kj = t >> 3, kd = (t & 7) * 16;
  const unsigned short* kg = src + kj * 384 + 128 + kd;
  const unsigned short* zg = Zb + ((long)b * S_ + s) * H_ + kj * 128 + kd;
  uint4 kr0 = *(const uint4*)(kg);
  uint4 kr1 = *(const uint4*)(kg + 8);
  uint4 zr0 = *(const uint4*)(zg);
  uint4 zr1 = *(const uint4*)(zg + 8);
  __syncthreads();                        // alib visible; q_s/v_s staged (vm drain)

  {
    const float aj = alib[kj];
    float kf[16], zf[16];
    unpack8(kr0, kf); unpack8(kr1, kf + 8);
    unpack8(zr0, zf); unpack8(zr1, zf + 8);
    union { uint4 u[2]; unsigned short us[16]; } kk;
#pragma unroll
    for (int d = 0; d < 16; ++d) kk.us[d] = f2bf(0.0078125f * kf[d] + aj * zf[d]);
    *(uint4*)&kp[kj * 136 + kd]     = kk.u[0];
    *(uint4*)&kp[kj * 136 + kd + 8] = kk.u[1];
  }
  __syncthreads();                        // kp ready

  // w[i][j] = q_i . K'_j ; thread: i = t>>3, j in j0..j0+3
  const int i = t >> 3;
  const int j0 = (t & 7) * 4;
  const int rot = (i ^ (t & 7)) & 15;
  float wv[4] = {0.f, 0.f, 0.f, 0.f};
  for (int dbi = 0; dbi < 16; ++dbi) {
    const int d0b = ((dbi + rot) & 15) * 8;
    float qf[8];
    unpack8(*(const uint4*)&q_s[i * 128 + d0b], qf);
#pragma unroll
    for (int jj = 0; jj < 4; ++jj) {
      float kf2[8];
      unpack8(*(const uint4*)&kp[(j0 + jj) * 136 + d0b], kf2);
#pragma unroll
      for (int d = 0; d < 8; ++d) wv[jj] += qf[d] * kf2[d];
    }
  }
  // wave-parallel softmax over the 8-lane group that owns row i
  float vmax = fmaxf(fmaxf(wv[0], wv[1]), fmaxf(wv[2], wv[3]));
  vmax = fmaxf(vmax, __shfl_xor(vmax, 1));
  vmax = fmaxf(vmax, __shfl_xor(vmax, 2));
  vmax = fmaxf(vmax, __shfl_xor(vmax, 4));
  float ssum = 0.f;
#pragma unroll
  for (int jj = 0; jj < 4; ++jj) { wv[jj] = __expf(wv[jj] - vmax); ssum += wv[jj]; }
#pragma unroll
  for (int jj = 0; jj < 4; ++jj) wsh[i][j0 + jj] = wv[jj];
  ssum += __shfl_xor(ssum, 1);
  ssum += __shfl_xor(ssum, 2);
  ssum += __shfl_xor(ssum, 4);
  if ((t & 7) == 0) pden[i] = 1.0f / (ssum + 1e-8f);
  __syncthreads();

  // ctx_i[d] = sum_j p_ij v_j[d] ; thread: i = t>>3, 16 d's at d0
  const int d0 = (t & 7) * 16;
  float acc[16];
#pragma unroll
  for (int d = 0; d < 16; ++d) acc[d] = 0.f;
  for (int j = 0; j < NH_; ++j) {
    const float p = wsh[i][j];
    float vf[16];
    unpack8(*(const uint4*)&v_s[j * 128 + d0], vf);
    unpack8(*(const uint4*)&v_s[j * 128 + d0 + 8], vf + 8);
#pragma unroll
    for (int d = 0; d < 16; ++d) acc[d] += p * vf[d];
  }
  const float inv = pden[i];
  union { uint4 u[2]; unsigned short us[16]; } ov;
#pragma unroll
  for (int d = 0; d < 16; ++d) ov.us[d] = f2bf(acc[d] * inv);
  unsigned short* cp = ctx + ((long)b * S_ + s) * H_ + i * HD_ + d0;
  *(uint4*)&cp[0] = ov.u[0];
  *(uint4*)&cp[8] = ov.u[1];
}

// -----------------------------------------------------------------------------
extern "C" void kernel_launch(void* const* d_in, const int* in_sizes, int n_in,
                              void* d_out, int out_size, void* d_ws, size_t ws_size,
                              hipStream_t stream)
{
  (void)in_sizes; (void)n_in; (void)out_size; (void)ws_size;
  const float* hidden   = (const float*)d_in[0];
  const float* residual = (const float*)d_in[1];
  const float* alibi    = (const float*)d_in[2];
  const float* Wqkv     = (const float*)d_in[4];
  const float* bqkv     = (const float*)d_in[5];
  const float* Wd       = (const float*)d_in[6];
  const float* bd       = (const float*)d_in[7];
  float* out = (float*)d_out;

  char* ws = (char*)d_ws;
  size_t off = 0;
  auto carve = [&](size_t bytes) -> void* {
    void* p = ws + off;
    off += (bytes + 255) & ~(size_t)255;
    return p;
  };
  const long nHid = (long)B_ * S_ * H_;
  const long nWq  = (long)H3_ * H_;
  unsigned short* hid_bf   = (unsigned short*)carve((size_t)nHid * 2);
  unsigned short* wqkv_bf  = (unsigned short*)carve((size_t)nWq * 2);
  unsigned short* wd_bf    = (unsigned short*)carve((size_t)H_ * H_ * 2);
  unsigned short* fused_bf = (unsigned short*)carve((size_t)B_ * S_ * H3_ * 2);
  unsigned short* z_bf     = (unsigned short*)carve((size_t)nHid * 2);
  unsigned short* ctx_bf   = (unsigned short*)carve((size_t)nHid * 2);
  float*          Gpart    = (float*)carve((size_t)64 * GP_ * 16384 * 4);
  unsigned short* ginv_bf  = (unsigned short*)carve((size_t)64 * 16384 * 2);

  // 1) bf16 casts (single launch, 3 segments)
  cvt3<<<2048, 256, 0, stream>>>(hidden, hid_bf, nHid,
                                 Wqkv, wqkv_bf, nWq,
                                 Wd, wd_bf, (long)H_ * H_);

  // 2) fused = hidden @ Wqkv^T + b_qkv  (bf16 out)
  gemm256<0><<<dim3(H3_ / 256, (B_ * S_) / 256, 1), 512, 0, stream>>>(
      hid_bf, wqkv_bf, fused_bf, bqkv, nullptr, H_, H_, H3_, H_);

  // 3) G partials via MFMA -> Ginv via register Gauss-Jordan (sums partials)
  compute_g<<<dim3(64, GP_), 256, 0, stream>>>(fused_bf, Gpart);
  invert_g<<<64, 1024, 0, stream>>>(Gpart, ginv_bf);

  // 4) Z[b,s,n,:] = Ginv_{b,n} q_{b,n}(s)   (small batched GEMM, 128² kernel)
  gemm_bt<2><<<dim3(1, S_ / 128, 64), 256, 0, stream>>>(
      fused_bf, ginv_bf, z_bf, nullptr, nullptr, H3_, HD_, H_, HD_,
      (long)S_ * H3_, 384, (long)32 * 16384, 16384, (long)S_ * H_, HD_);

  // 5) per-position 32x32 head attention -> ctx (bf16)
  attn_pos<<<dim3(S_, B_), 256, 0, stream>>>(fused_bf, z_bf, alibi, ctx_bf);

  // 6) out = ctx @ Wd^T + b_dense + residual  (f32 out)
  gemm256<1><<<dim3(H_ / 256, (B_ * S_) / 256, 1), 512, 0, stream>>>(
      ctx_bf, wd_bf, out, bd, residual, H_, H_, H_, H_);
}

// Round 12
// 775.056 us; speedup vs baseline: 1.6827x; 1.0228x over previous
//
#include <hip/hip_runtime.h>

#define B_  2
#define S_  2048
#define NH_ 32
#define HD_ 128
#define H_  4096
#define H3_ 12288
#define GP_ 8   // compute_g partial chunks

typedef __bf16 bf16x8 __attribute__((ext_vector_type(8)));
typedef float  f32x4  __attribute__((ext_vector_type(4)));
typedef float  f32x16 __attribute__((ext_vector_type(16)));

__device__ __forceinline__ unsigned short f2bf(float f) {
  unsigned int u = __float_as_uint(f);
  u += 0x7fffu + ((u >> 16) & 1u);
  return (unsigned short)(u >> 16);
}
__device__ __forceinline__ void unpack8(uint4 r, float f[8]) {
  f[0] = __uint_as_float(r.x << 16); f[1] = __uint_as_float(r.x & 0xffff0000u);
  f[2] = __uint_as_float(r.y << 16); f[3] = __uint_as_float(r.y & 0xffff0000u);
  f[4] = __uint_as_float(r.z << 16); f[5] = __uint_as_float(r.z & 0xffff0000u);
  f[6] = __uint_as_float(r.w << 16); f[7] = __uint_as_float(r.w & 0xffff0000u);
}
__device__ __forceinline__ void gload_lds16(const void* g, void* l) {
  __builtin_amdgcn_global_load_lds(
      (const __attribute__((address_space(1))) unsigned int*)g,
      (__attribute__((address_space(3))) unsigned int*)l, 16, 0, 0);
}

// ---------------- fused f32 -> bf16 converts (one launch, 3 segments) --------
__device__ __forceinline__ void cvt_seg(const float* __restrict__ in,
                                        unsigned short* __restrict__ out,
                                        long n, long base, long stride) {
  for (long i = base; i < n; i += stride) {
    float4 v = *(const float4*)(in + i);
    ushort4 o;
    o.x = f2bf(v.x); o.y = f2bf(v.y); o.z = f2bf(v.z); o.w = f2bf(v.w);
    *(ushort4*)(out + i) = o;
  }
}
__global__ __launch_bounds__(256) void cvt3(
    const float* __restrict__ a, unsigned short* __restrict__ oa, long na,
    const float* __restrict__ b, unsigned short* __restrict__ ob, long nb,
    const float* __restrict__ c, unsigned short* __restrict__ oc, long nc) {
  const long base = ((long)blockIdx.x * 256 + threadIdx.x) * 4;
  const long stride = (long)gridDim.x * 256 * 4;
  cvt_seg(a, oa, na, base, stride);
  cvt_seg(b, ob, nb, base, stride);
  cvt_seg(c, oc, nc, base, stride);
}

// =============================================================================
// 256x256-tile bf16 GEMM (measured-best structure: 8 waves (2x4), BK=32,
// 3-stage LDS pipeline (96 KB), counted vmcnt(4), chunk-XOR swizzle
// (row bits 1..2), setprio around the MFMA cluster).
// EPI 0: bf16 out + bias ; EPI 1: f32 out + bias + residual
// =============================================================================
template <int EPI>
__global__ __launch_bounds__(512, 2) void gemm256(
    const unsigned short* __restrict__ A, const unsigned short* __restrict__ Bt,
    void* __restrict__ C, const float* __restrict__ bias, const float* __restrict__ Res,
    int lda, int ldb, int ldc, int K)
{
  __shared__ __align__(16) unsigned short lds[3 * 16384];

  const int tid = threadIdx.x;
  const int w = tid >> 6, l = tid & 63;

  const int gx = gridDim.x;
  const int nwg = gx * gridDim.y;
  const int flat = blockIdx.y * gx + blockIdx.x;
  const int swz = (flat & 7) * (nwg >> 3) + (flat >> 3);
  const int m0 = (swz / gx) * 256;
  const int n0 = (swz % gx) * 256;

  const int wr = w >> 2, wc = w & 3;
  const int lr16 = l & 15, kq = l >> 4;

  const int srow = w * 16 + (l >> 2);
  const int scs  = (((l & 3) ^ ((l >> 3) & 3)) << 3);
  const unsigned short* ga = A  + (long)(m0 + srow) * lda + scs;
  const unsigned short* gb = Bt + (long)(n0 + srow) * ldb + scs;
  unsigned short* sb_w = lds + w * 512;

  const int rchunk = ((kq ^ ((l >> 1) & 3)) << 3);

  const int NT = K >> 5;

  const f32x4 zero = {0.f, 0.f, 0.f, 0.f};
  f32x4 acc[8][4];
#pragma unroll
  for (int m = 0; m < 8; ++m)
#pragma unroll
    for (int n = 0; n < 4; ++n) acc[m][n] = zero;

  auto stage = [&](int kt, int s) {
    const unsigned short* a = ga + (long)kt * 32;
    const unsigned short* b = gb + (long)kt * 32;
    unsigned short* d = sb_w + s * 16384;
    gload_lds16(a,                  d);
    gload_lds16(a + 128L * lda,     d + 4096);
    gload_lds16(b,                  d + 8192);
    gload_lds16(b + 128L * ldb,     d + 12288);
  };

  stage(0, 0);
  stage(1, 1);
  asm volatile("s_waitcnt vmcnt(4)" ::: "memory");
  __builtin_amdgcn_s_barrier();

  for (int t = 0; t < NT; ++t) {
    const int cur = t % 3;
    if (t + 2 < NT) stage(t + 2, (t + 2) % 3);

    const unsigned short* sa = lds + cur * 16384;
    const unsigned short* sbB = sa + 8192;
    bf16x8 av[8], bv[4];
#pragma unroll
    for (int n = 0; n < 4; ++n)
      bv[n] = *(const bf16x8*)&sbB[(wc * 64 + n * 16 + lr16) * 32 + rchunk];
#pragma unroll
    for (int m = 0; m < 8; ++m)
      av[m] = *(const bf16x8*)&sa[(wr * 128 + m * 16 + lr16) * 32 + rchunk];

    __builtin_amdgcn_s_setprio(1);
#pragma unroll
    for (int m = 0; m < 8; ++m)
#pragma unroll
      for (int n = 0; n < 4; ++n)
        acc[m][n] = __builtin_amdgcn_mfma_f32_16x16x32_bf16(av[m], bv[n], acc[m][n], 0, 0, 0);
    __builtin_amdgcn_s_setprio(0);

    if (t + 1 < NT) {
      if (t + 2 < NT) asm volatile("s_waitcnt vmcnt(4)" ::: "memory");
      else            asm volatile("s_waitcnt vmcnt(0)" ::: "memory");
      __builtin_amdgcn_s_barrier();
    }
  }

#pragma unroll
  for (int m = 0; m < 8; ++m) {
    const int grow0 = m0 + wr * 128 + m * 16 + kq * 4;
#pragma unroll
    for (int n = 0; n < 4; ++n) {
      const int gcol = n0 + wc * 64 + n * 16 + lr16;
#pragma unroll
      for (int i = 0; i < 4; ++i) {
        const long gi = (long)(grow0 + i) * ldc + gcol;
        float v = acc[m][n][i];
        if (EPI == 0) {
          ((unsigned short*)C)[gi] = f2bf(v + bias[gcol]);
        } else {
          ((float*)C)[gi] = v + bias[gcol] + Res[gi];
        }
      }
    }
  }
}

// ---------------- 128-tile bf16 GEMM (batched Z-GEMM), swizzled ----------
template <int EPI>
__global__ __launch_bounds__(256) void gemm_bt(
    const unsigned short* __restrict__ Abase, const unsigned short* __restrict__ Bbase,
    void* __restrict__ Cbase, const float* __restrict__ bias, const float* __restrict__ Res,
    int lda, int ldb, int ldc, int K,
    long sAb, long sAn, long sBb, long sBn, long sCb, long sCn)
{
  __shared__ __align__(16) unsigned short As[128][32];
  __shared__ __align__(16) unsigned short Bs[128][32];

  const int zz = blockIdx.z;
  const int zb = zz >> 5, zn = zz & 31;
  const unsigned short* A  = Abase + (long)zb * sAb + (long)zn * sAn;
  const unsigned short* Bm = Bbase + (long)zb * sBb + (long)zn * sBn;
  const long coff = (long)zb * sCb + (long)zn * sCn;

  const int m0 = blockIdx.y * 128;
  const int n0 = blockIdx.x * 128;
  const int tid = threadIdx.x;
  const int wave = tid >> 6;
  const int lane = tid & 63;
  const int wr = wave >> 1, wc = wave & 1;
  const int lr = lane & 15, kq = lane >> 4;
  const int srow = wave * 16 + (lane >> 2);
  const int scol = (((lane & 3) ^ ((lane >> 3) & 3)) << 3);
  const int rch  = ((kq ^ ((lane >> 1) & 3)) << 3);

  const f32x4 zero = {0.0f, 0.0f, 0.0f, 0.0f};
  f32x4 acc[4][4];
#pragma unroll
  for (int m = 0; m < 4; ++m)
#pragma unroll
    for (int n = 0; n < 4; ++n) acc[m][n] = zero;

  for (int k0 = 0; k0 < K; k0 += 32) {
    const unsigned short* ga = A  + (long)(m0 + srow) * lda + k0 + scol;
    const unsigned short* gb = Bm + (long)(n0 + srow) * ldb + k0 + scol;
    gload_lds16(ga,                   &As[wave * 16][0]);
    gload_lds16(ga + (long)64 * lda,  &As[64 + wave * 16][0]);
    gload_lds16(gb,                   &Bs[wave * 16][0]);
    gload_lds16(gb + (long)64 * ldb,  &Bs[64 + wave * 16][0]);
    __syncthreads();

    bf16x8 av[4], bv[4];
#pragma unroll
    for (int m = 0; m < 4; ++m) av[m] = *(const bf16x8*)&As[wr * 64 + m * 16 + lr][rch];
#pragma unroll
    for (int n = 0; n < 4; ++n) bv[n] = *(const bf16x8*)&Bs[wc * 64 + n * 16 + lr][rch];
#pragma unroll
    for (int m = 0; m < 4; ++m)
#pragma unroll
      for (int n = 0; n < 4; ++n)
        acc[m][n] = __builtin_amdgcn_mfma_f32_16x16x32_bf16(av[m], bv[n], acc[m][n], 0, 0, 0);
    __syncthreads();
  }

#pragma unroll
  for (int m = 0; m < 4; ++m) {
    const int grow0 = m0 + wr * 64 + m * 16 + kq * 4;
#pragma unroll
    for (int n = 0; n < 4; ++n) {
      const int gcol = n0 + wc * 64 + n * 16 + lr;
#pragma unroll
      for (int r = 0; r < 4; ++r) {
        const long gi = coff + (long)(grow0 + r) * ldc + gcol;
        float v = acc[m][n][r];
        if (EPI == 0) {
          ((unsigned short*)Cbase)[gi] = f2bf(v + bias[gcol]);
        } else if (EPI == 1) {
          ((float*)Cbase)[gi] = v + bias[gcol] + Res[gi];
        } else {
          ((unsigned short*)Cbase)[gi] = f2bf(v);
        }
      }
    }
  }
}

// ---------------- G partials via MFMA: Gpart[z][p] = Q_chunk^T Q_chunk -------
__global__ __launch_bounds__(256) void compute_g(const unsigned short* __restrict__ fused,
                                                 float* __restrict__ Gpart)
{
  __shared__ __align__(16) unsigned short Qs[64 * 136];
  const int z = blockIdx.x;            // b*32+n
  const int b = z >> 5, n = z & 31;
  const unsigned short* Q = fused + (long)b * S_ * H3_ + n * 384;
  const int t = threadIdx.x;
  const int w = t >> 6, l = t & 63;
  const int l31 = l & 31, hi = l >> 5;
  const int ar0 = (w & 1) * 2, ac0 = (w >> 1) * 2;

  f32x16 acc[2][2];
#pragma unroll
  for (int i = 0; i < 2; ++i)
#pragma unroll
    for (int j = 0; j < 2; ++j)
#pragma unroll
      for (int r = 0; r < 16; ++r) acc[i][j][r] = 0.f;

  const int sbeg = blockIdx.y * (S_ / GP_);

  for (int ss0 = 0; ss0 < S_ / GP_; ss0 += 64) {
    __syncthreads();
#pragma unroll
    for (int pass = 0; pass < 4; ++pass) {
      const int sL = pass * 16 + (t >> 4);
      const int c = t & 15;
      uint4 v = *(const uint4*)(Q + (long)(sbeg + ss0 + sL) * H3_ + c * 8);
      *(uint4*)&Qs[sL * 136 + c * 8] = v;
    }
    __syncthreads();

#pragma unroll
    for (int ks = 0; ks < 4; ++ks) {
      const int sb = ks * 16 + hi * 8;
      bf16x8 fa[2], fb[2];
#pragma unroll
      for (int i = 0; i < 2; ++i) {
        const int colA = (ar0 + i) * 32 + l31;
        const int colB = (ac0 + i) * 32 + l31;
        bf16x8 ra, rbv;
#pragma unroll
        for (int j = 0; j < 8; ++j) {
          unsigned short ua = Qs[(sb + j) * 136 + colA];
          unsigned short ub = Qs[(sb + j) * 136 + colB];
          ra[j]  = *reinterpret_cast<__bf16*>(&ua);
          rbv[j] = *reinterpret_cast<__bf16*>(&ub);
        }
        fa[i] = ra; fb[i] = rbv;
      }
#pragma unroll
      for (int i = 0; i < 2; ++i)
#pragma unroll
        for (int j = 0; j < 2; ++j)
          acc[i][j] = __builtin_amdgcn_mfma_f32_32x32x16_bf16(fa[i], fb[j], acc[i][j], 0, 0, 0);
    }
  }

  float* Gp = Gpart + ((long)z * GP_ + blockIdx.y) * 16384;
#pragma unroll
  for (int i = 0; i < 2; ++i) {
    const int rowb = (ar0 + i) * 32 + 4 * hi;
#pragma unroll
    for (int j = 0; j < 2; ++j) {
      const int col = (ac0 + j) * 32 + l31;
#pragma unroll
      for (int r = 0; r < 16; ++r) {
        const int row = rowb + (r & 3) + 8 * (r >> 2);
        Gp[row * 128 + col] = acc[i][j][r];
      }
    }
  }
}

// ---------------- register-resident Gauss-Jordan inverse of SPD 128x128 ------
__global__ __launch_bounds__(1024) void invert_g(const float* __restrict__ Gpart,
                                                 unsigned short* __restrict__ Ginv)
{
  __shared__ __align__(16) float prow[2][128];
  __shared__ __align__(16) float pcol[2][128];
  const int z = blockIdx.x;
  const int t = threadIdx.x;
  const int c  = t & 127;
  const int rg = t >> 7;
  const float* Gz = Gpart + (long)z * GP_ * 16384;

  float a[16];
#pragma unroll
  for (int i = 0; i < 16; ++i) {
    const int idx = (rg * 16 + i) * 128 + c;
    float s = 0.f;
#pragma unroll
    for (int p = 0; p < GP_; ++p) s += Gz[p * 16384 + idx];
    a[i] = s;
  }

  for (int p = 0; p < 128; ++p) {
    const int buf = p & 1;
    const int prg = p >> 4, pi = p & 15;
    if (rg == prg) {
      float v = a[0];
#pragma unroll
      for (int i = 1; i < 16; ++i) v = (pi == i) ? a[i] : v;
      prow[buf][c] = v;
    }
    if (c == p) {
#pragma unroll
      for (int q = 0; q < 4; ++q) {
        float4 w4 = make_float4(a[q * 4], a[q * 4 + 1], a[q * 4 + 2], a[q * 4 + 3]);
        *(float4*)&pcol[buf][rg * 16 + q * 4] = w4;
      }
    }
    __syncthreads();
    const float invp = 1.0f / prow[buf][p];
    const float rowv = (c == p) ? invp : prow[buf][c] * invp;
#pragma unroll
    for (int q = 0; q < 4; ++q) {
      const float4 pc4 = *(const float4*)&pcol[buf][rg * 16 + q * 4];
      const float pcv[4] = {pc4.x, pc4.y, pc4.z, pc4.w};
#pragma unroll
      for (int j = 0; j < 4; ++j) {
        const int i = q * 4 + j;
        const int r = rg * 16 + i;
        const float cur = (c == p) ? 0.f : a[i];
        a[i] = (r == p) ? rowv : cur - pcv[j] * rowv;
      }
    }
  }
  unsigned short* Oz = Ginv + (long)z * 16384;
#pragma unroll
  for (int i = 0; i < 16; ++i) Oz[(rg * 16 + i) * 128 + c] = f2bf(a[i]);
}

// ---------------- per-position 32x32 head attention (MFMA grams) -------------
// w[i][j] = g1[i][j]/128 + alib_j * g2[i][j] with g1 = q k^T, g2 = q z^T.
// Each of 4 waves computes a d-slice (32) partial of BOTH grams via
// mfma_f32_32x32x16_bf16 (fragment pattern verified in gemm256-32x32, r7):
// A: row=l&31, k=(l>>5)*8+j ; C/D: col=l&31, row=(r&3)+8*(r>>2)+4*(l>>5).
// alibi is column-indexed (= lane-local l&31) so K' is never materialized.
// q/k/z reg-staged into padded [32][136] bf16 LDS (pad kills D=128 conflicts).
__global__ __launch_bounds__(256) void attn_pos(
    const unsigned short* __restrict__ fused, const unsigned short* __restrict__ Zb,
    const float* __restrict__ alibi, unsigned short* __restrict__ ctx)
{
  __shared__ __align__(16) unsigned short q_s[32 * 136];   // 8.5 KB
  __shared__ __align__(16) unsigned short k_s[32 * 136];
  __shared__ __align__(16) unsigned short z_s[32 * 136];
  __shared__ __align__(16) unsigned short v_s[32 * 128];   // 8 KB (gload linear)
  __shared__ float part[4][32][33];                        // 16.5 KB
  __shared__ float wsh[NH_][NH_ + 1];
  __shared__ float pden[NH_];
  __shared__ float alib[NH_];

  const int s = blockIdx.x, b = blockIdx.y;
  const int t = threadIdx.x;
  const int w = t >> 6, l = t & 63;
  const int l31 = l & 31, hi = l >> 5;
  const unsigned short* src = fused + ((long)b * S_ + s) * H3_;
  const unsigned short* zg = Zb + ((long)b * S_ + s) * H_;

  if (t < NH_) alib[t] = 0.08838834764831845f * alibi[((long)(b * NH_ + t)) * S_ + s];

  // v via gload_lds, linear [head][d]
  {
    const int i0 = t >> 4, c = t & 15;
    gload_lds16(src + i0 * 384 + 256 + c * 8,        (char*)v_s + w * 1024);
    gload_lds16(src + (i0 + 16) * 384 + 256 + c * 8, (char*)v_s + 4096 + w * 1024);
  }
  // q,k,z reg-staged into padded [32][136]
  {
    const int row = t >> 3, c = (t & 7) * 16;
    uint4 a0 = *(const uint4*)(src + row * 384 + c);
    uint4 a1 = *(const uint4*)(src + row * 384 + c + 8);
    uint4 b0 = *(const uint4*)(src + row * 384 + 128 + c);
    uint4 b1 = *(const uint4*)(src + row * 384 + 128 + c + 8);
    uint4 c0 = *(const uint4*)(zg + row * 128 + c);
    uint4 c1 = *(const uint4*)(zg + row * 128 + c + 8);
    *(uint4*)&q_s[row * 136 + c] = a0; *(uint4*)&q_s[row * 136 + c + 8] = a1;
    *(uint4*)&k_s[row * 136 + c] = b0; *(uint4*)&k_s[row * 136 + c + 8] = b1;
    *(uint4*)&z_s[row * 136 + c] = c0; *(uint4*)&z_s[row * 136 + c + 8] = c1;
  }
  __syncthreads();

  // per-wave d-slice grams
  {
    f32x16 g1, g2;
#pragma unroll
    for (int r = 0; r < 16; ++r) { g1[r] = 0.f; g2[r] = 0.f; }
#pragma unroll
    for (int ks = 0; ks < 2; ++ks) {
      const int off = w * 32 + ks * 16 + hi * 8;
      bf16x8 aq = *(const bf16x8*)&q_s[l31 * 136 + off];
      bf16x8 bk = *(const bf16x8*)&k_s[l31 * 136 + off];
      bf16x8 bz = *(const bf16x8*)&z_s[l31 * 136 + off];
      g1 = __builtin_amdgcn_mfma_f32_32x32x16_bf16(aq, bk, g1, 0, 0, 0);
      g2 = __builtin_amdgcn_mfma_f32_32x32x16_bf16(aq, bz, g2, 0, 0, 0);
    }
    const float aj = alib[l31];
#pragma unroll
    for (int r = 0; r < 16; ++r) {
      const int row = (r & 3) + 8 * (r >> 2) + 4 * hi;
      part[w][row][l31] = 0.0078125f * g1[r] + aj * g2[r];
    }
  }
  __syncthreads();

  // reduce 4 wave-partials into wsh
#pragma unroll
  for (int e = 0; e < 4; ++e) {
    const int idx = t * 4 + e;
    const int ii = idx >> 5, jj = idx & 31;
    wsh[ii][jj] = part[0][ii][jj] + part[1][ii][jj] + part[2][ii][jj] + part[3][ii][jj];
  }
  __syncthreads();

  // wave-parallel softmax: 8-lane group owns row i
  const int i = t >> 3;
  const int j0 = (t & 7) * 4;
  float wv[4];
#pragma unroll
  for (int jj = 0; jj < 4; ++jj) wv[jj] = wsh[i][j0 + jj];
  float vmax = fmaxf(fmaxf(wv[0], wv[1]), fmaxf(wv[2], wv[3]));
  vmax = fmaxf(vmax, __shfl_xor(vmax, 1));
  vmax = fmaxf(vmax, __shfl_xor(vmax, 2));
  vmax = fmaxf(vmax, __shfl_xor(vmax, 4));
  float ssum = 0.f;
#pragma unroll
  for (int jj = 0; jj < 4; ++jj) { wv[jj] = __expf(wv[jj] - vmax); ssum += wv[jj]; }
#pragma unroll
  for (int jj = 0; jj < 4; ++jj) wsh[i][j0 + jj] = wv[jj];
  ssum += __shfl_xor(ssum, 1);
  ssum += __shfl_xor(ssum, 2);
  ssum += __shfl_xor(ssum, 4);
  if ((t & 7) == 0) pden[i] = 1.0f / (ssum + 1e-8f);
  __syncthreads();

  // ctx_i[d] = sum_j p_ij v_j[d]
  const int d0 = (t & 7) * 16;
  float acc[16];
#pragma unroll
  for (int d = 0; d < 16; ++d) acc[d] = 0.f;
  for (int j = 0; j < NH_; ++j) {
    const float p = wsh[i][j];
    float vf[16];
    unpack8(*(const uint4*)&v_s[j * 128 + d0], vf);
    unpack8(*(const uint4*)&v_s[j * 128 + d0 + 8], vf + 8);
#pragma unroll
    for (int d = 0; d < 16; ++d) acc[d] += p * vf[d];
  }
  const float inv = pden[i];
  union { uint4 u[2]; unsigned short us[16]; } ov;
#pragma unroll
  for (int d = 0; d < 16; ++d) ov.us[d] = f2bf(acc[d] * inv);
  unsigned short* cp = ctx + ((long)b * S_ + s) * H_ + i * HD_ + d0;
  *(uint4*)&cp[0] = ov.u[0];
  *(uint4*)&cp[8] = ov.u[1];
}

// -----------------------------------------------------------------------------
extern "C" void kernel_launch(void* const* d_in, const int* in_sizes, int n_in,
                              void* d_out, int out_size, void* d_ws, size_t ws_size,
                              hipStream_t stream)
{
  (void)in_sizes; (void)n_in; (void)out_size; (void)ws_size;
  const float* hidden   = (const float*)d_in[0];
  const float* residual = (const float*)d_in[1];
  const float* alibi    = (const float*)d_in[2];
  const float* Wqkv     = (const float*)d_in[4];
  const float* bqkv     = (const float*)d_in[5];
  const float* Wd       = (const float*)d_in[6];
  const float* bd       = (const float*)d_in[7];
  float* out = (float*)d_out;

  char* ws = (char*)d_ws;
  size_t off = 0;
  auto carve = [&](size_t bytes) -> void* {
    void* p = ws + off;
    off += (bytes + 255) & ~(size_t)255;
    return p;
  };
  const long nHid = (long)B_ * S_ * H_;
  const long nWq  = (long)H3_ * H_;
  unsigned short* hid_bf   = (unsigned short*)carve((size_t)nHid * 2);
  unsigned short* wqkv_bf  = (unsigned short*)carve((size_t)nWq * 2);
  unsigned short* wd_bf    = (unsigned short*)carve((size_t)H_ * H_ * 2);
  unsigned short* fused_bf = (unsigned short*)carve((size_t)B_ * S_ * H3_ * 2);
  unsigned short* z_bf     = (unsigned short*)carve((size_t)nHid * 2);
  unsigned short* ctx_bf   = (unsigned short*)carve((size_t)nHid * 2);
  float*          Gpart    = (float*)carve((size_t)64 * GP_ * 16384 * 4);
  unsigned short* ginv_bf  = (unsigned short*)carve((size_t)64 * 16384 * 2);

  // 1) bf16 casts (single launch, 3 segments)
  cvt3<<<2048, 256, 0, stream>>>(hidden, hid_bf, nHid,
                                 Wqkv, wqkv_bf, nWq,
                                 Wd, wd_bf, (long)H_ * H_);

  // 2) fused = hidden @ Wqkv^T + b_qkv  (bf16 out)
  gemm256<0><<<dim3(H3_ / 256, (B_ * S_) / 256, 1), 512, 0, stream>>>(
      hid_bf, wqkv_bf, fused_bf, bqkv, nullptr, H_, H_, H3_, H_);

  // 3) G partials via MFMA -> Ginv via register Gauss-Jordan (sums partials)
  compute_g<<<dim3(64, GP_), 256, 0, stream>>>(fused_bf, Gpart);
  invert_g<<<64, 1024, 0, stream>>>(Gpart, ginv_bf);

  // 4) Z[b,s,n,:] = Ginv_{b,n} q_{b,n}(s)   (small batched GEMM, 128² kernel)
  gemm_bt<2><<<dim3(1, S_ / 128, 64), 256, 0, stream>>>(
      fused_bf, ginv_bf, z_bf, nullptr, nullptr, H3_, HD_, H_, HD_,
      (long)S_ * H3_, 384, (long)32 * 16384, 16384, (long)S_ * H_, HD_);

  // 5) per-position 32x32 head attention -> ctx (bf16)
  attn_pos<<<dim3(S_, B_), 256, 0, stream>>>(fused_bf, z_bf, alibi, ctx_bf);

  // 6) out = ctx @ Wd^T + b_dense + residual  (f32 out)
  gemm256<1><<<dim3(H_ / 256, (B_ * S_) / 256, 1), 512, 0, stream>>>(
      ctx_bf, wd_bf, out, bd, residual, H_, H_, H_, H_);
}

// Round 13
// 759.594 us; speedup vs baseline: 1.7170x; 1.0204x over previous
//
#include <hip/hip_runtime.h>

#define B_  2
#define S_  2048
#define NH_ 32
#define HD_ 128
#define H_  4096
#define H3_ 12288
#define GP_ 8   // compute_g partial chunks

typedef __bf16 bf16x8 __attribute__((ext_vector_type(8)));
typedef float  f32x4  __attribute__((ext_vector_type(4)));
typedef float  f32x16 __attribute__((ext_vector_type(16)));

__device__ __forceinline__ unsigned short f2bf(float f) {
  unsigned int u = __float_as_uint(f);
  u += 0x7fffu + ((u >> 16) & 1u);
  return (unsigned short)(u >> 16);
}
__device__ __forceinline__ __bf16 u2bf(unsigned short u) {
  return *reinterpret_cast<__bf16*>(&u);
}
__device__ __forceinline__ void unpack8(uint4 r, float f[8]) {
  f[0] = __uint_as_float(r.x << 16); f[1] = __uint_as_float(r.x & 0xffff0000u);
  f[2] = __uint_as_float(r.y << 16); f[3] = __uint_as_float(r.y & 0xffff0000u);
  f[4] = __uint_as_float(r.z << 16); f[5] = __uint_as_float(r.z & 0xffff0000u);
  f[6] = __uint_as_float(r.w << 16); f[7] = __uint_as_float(r.w & 0xffff0000u);
}
__device__ __forceinline__ void gload_lds16(const void* g, void* l) {
  __builtin_amdgcn_global_load_lds(
      (const __attribute__((address_space(1))) unsigned int*)g,
      (__attribute__((address_space(3))) unsigned int*)l, 16, 0, 0);
}

// ---------------- fused f32 -> bf16 converts (one launch, 3 segments) --------
__device__ __forceinline__ void cvt_seg(const float* __restrict__ in,
                                        unsigned short* __restrict__ out,
                                        long n, long base, long stride) {
  for (long i = base; i < n; i += stride) {
    float4 v = *(const float4*)(in + i);
    ushort4 o;
    o.x = f2bf(v.x); o.y = f2bf(v.y); o.z = f2bf(v.z); o.w = f2bf(v.w);
    *(ushort4*)(out + i) = o;
  }
}
__global__ __launch_bounds__(256) void cvt3(
    const float* __restrict__ a, unsigned short* __restrict__ oa, long na,
    const float* __restrict__ b, unsigned short* __restrict__ ob, long nb,
    const float* __restrict__ c, unsigned short* __restrict__ oc, long nc) {
  const long base = ((long)blockIdx.x * 256 + threadIdx.x) * 4;
  const long stride = (long)gridDim.x * 256 * 4;
  cvt_seg(a, oa, na, base, stride);
  cvt_seg(b, ob, nb, base, stride);
  cvt_seg(c, oc, nc, base, stride);
}

// =============================================================================
// 256x256-tile bf16 GEMM (measured-best structure: 8 waves (2x4), BK=32,
// 3-stage LDS pipeline (96 KB), counted vmcnt(4), chunk-XOR swizzle
// (row bits 1..2), setprio around the MFMA cluster).
// EPI 0: bf16 out + bias ; EPI 1: f32 out + bias + residual
// =============================================================================
template <int EPI>
__global__ __launch_bounds__(512, 2) void gemm256(
    const unsigned short* __restrict__ A, const unsigned short* __restrict__ Bt,
    void* __restrict__ C, const float* __restrict__ bias, const float* __restrict__ Res,
    int lda, int ldb, int ldc, int K)
{
  __shared__ __align__(16) unsigned short lds[3 * 16384];

  const int tid = threadIdx.x;
  const int w = tid >> 6, l = tid & 63;

  const int gx = gridDim.x;
  const int nwg = gx * gridDim.y;
  const int flat = blockIdx.y * gx + blockIdx.x;
  const int swz = (flat & 7) * (nwg >> 3) + (flat >> 3);
  const int m0 = (swz / gx) * 256;
  const int n0 = (swz % gx) * 256;

  const int wr = w >> 2, wc = w & 3;
  const int lr16 = l & 15, kq = l >> 4;

  const int srow = w * 16 + (l >> 2);
  const int scs  = (((l & 3) ^ ((l >> 3) & 3)) << 3);
  const unsigned short* ga = A  + (long)(m0 + srow) * lda + scs;
  const unsigned short* gb = Bt + (long)(n0 + srow) * ldb + scs;
  unsigned short* sb_w = lds + w * 512;

  const int rchunk = ((kq ^ ((l >> 1) & 3)) << 3);

  const int NT = K >> 5;

  const f32x4 zero = {0.f, 0.f, 0.f, 0.f};
  f32x4 acc[8][4];
#pragma unroll
  for (int m = 0; m < 8; ++m)
#pragma unroll
    for (int n = 0; n < 4; ++n) acc[m][n] = zero;

  auto stage = [&](int kt, int s) {
    const unsigned short* a = ga + (long)kt * 32;
    const unsigned short* b = gb + (long)kt * 32;
    unsigned short* d = sb_w + s * 16384;
    gload_lds16(a,                  d);
    gload_lds16(a + 128L * lda,     d + 4096);
    gload_lds16(b,                  d + 8192);
    gload_lds16(b + 128L * ldb,     d + 12288);
  };

  stage(0, 0);
  stage(1, 1);
  asm volatile("s_waitcnt vmcnt(4)" ::: "memory");
  __builtin_amdgcn_s_barrier();

  for (int t = 0; t < NT; ++t) {
    const int cur = t % 3;
    if (t + 2 < NT) stage(t + 2, (t + 2) % 3);

    const unsigned short* sa = lds + cur * 16384;
    const unsigned short* sbB = sa + 8192;
    bf16x8 av[8], bv[4];
#pragma unroll
    for (int n = 0; n < 4; ++n)
      bv[n] = *(const bf16x8*)&sbB[(wc * 64 + n * 16 + lr16) * 32 + rchunk];
#pragma unroll
    for (int m = 0; m < 8; ++m)
      av[m] = *(const bf16x8*)&sa[(wr * 128 + m * 16 + lr16) * 32 + rchunk];

    __builtin_amdgcn_s_setprio(1);
#pragma unroll
    for (int m = 0; m < 8; ++m)
#pragma unroll
      for (int n = 0; n < 4; ++n)
        acc[m][n] = __builtin_amdgcn_mfma_f32_16x16x32_bf16(av[m], bv[n], acc[m][n], 0, 0, 0);
    __builtin_amdgcn_s_setprio(0);

    if (t + 1 < NT) {
      if (t + 2 < NT) asm volatile("s_waitcnt vmcnt(4)" ::: "memory");
      else            asm volatile("s_waitcnt vmcnt(0)" ::: "memory");
      __builtin_amdgcn_s_barrier();
    }
  }

#pragma unroll
  for (int m = 0; m < 8; ++m) {
    const int grow0 = m0 + wr * 128 + m * 16 + kq * 4;
#pragma unroll
    for (int n = 0; n < 4; ++n) {
      const int gcol = n0 + wc * 64 + n * 16 + lr16;
#pragma unroll
      for (int i = 0; i < 4; ++i) {
        const long gi = (long)(grow0 + i) * ldc + gcol;
        float v = acc[m][n][i];
        if (EPI == 0) {
          ((unsigned short*)C)[gi] = f2bf(v + bias[gcol]);
        } else {
          ((float*)C)[gi] = v + bias[gcol] + Res[gi];
        }
      }
    }
  }
}

// ---------------- 128-tile bf16 GEMM (batched Z-GEMM), swizzled ----------
template <int EPI>
__global__ __launch_bounds__(256) void gemm_bt(
    const unsigned short* __restrict__ Abase, const unsigned short* __restrict__ Bbase,
    void* __restrict__ Cbase, const float* __restrict__ bias, const float* __restrict__ Res,
    int lda, int ldb, int ldc, int K,
    long sAb, long sAn, long sBb, long sBn, long sCb, long sCn)
{
  __shared__ __align__(16) unsigned short As[128][32];
  __shared__ __align__(16) unsigned short Bs[128][32];

  const int zz = blockIdx.z;
  const int zb = zz >> 5, zn = zz & 31;
  const unsigned short* A  = Abase + (long)zb * sAb + (long)zn * sAn;
  const unsigned short* Bm = Bbase + (long)zb * sBb + (long)zn * sBn;
  const long coff = (long)zb * sCb + (long)zn * sCn;

  const int m0 = blockIdx.y * 128;
  const int n0 = blockIdx.x * 128;
  const int tid = threadIdx.x;
  const int wave = tid >> 6;
  const int lane = tid & 63;
  const int wr = wave >> 1, wc = wave & 1;
  const int lr = lane & 15, kq = lane >> 4;
  const int srow = wave * 16 + (lane >> 2);
  const int scol = (((lane & 3) ^ ((lane >> 3) & 3)) << 3);
  const int rch  = ((kq ^ ((lane >> 1) & 3)) << 3);

  const f32x4 zero = {0.0f, 0.0f, 0.0f, 0.0f};
  f32x4 acc[4][4];
#pragma unroll
  for (int m = 0; m < 4; ++m)
#pragma unroll
    for (int n = 0; n < 4; ++n) acc[m][n] = zero;

  for (int k0 = 0; k0 < K; k0 += 32) {
    const unsigned short* ga = A  + (long)(m0 + srow) * lda + k0 + scol;
    const unsigned short* gb = Bm + (long)(n0 + srow) * ldb + k0 + scol;
    gload_lds16(ga,                   &As[wave * 16][0]);
    gload_lds16(ga + (long)64 * lda,  &As[64 + wave * 16][0]);
    gload_lds16(gb,                   &Bs[wave * 16][0]);
    gload_lds16(gb + (long)64 * ldb,  &Bs[64 + wave * 16][0]);
    __syncthreads();

    bf16x8 av[4], bv[4];
#pragma unroll
    for (int m = 0; m < 4; ++m) av[m] = *(const bf16x8*)&As[wr * 64 + m * 16 + lr][rch];
#pragma unroll
    for (int n = 0; n < 4; ++n) bv[n] = *(const bf16x8*)&Bs[wc * 64 + n * 16 + lr][rch];
#pragma unroll
    for (int m = 0; m < 4; ++m)
#pragma unroll
      for (int n = 0; n < 4; ++n)
        acc[m][n] = __builtin_amdgcn_mfma_f32_16x16x32_bf16(av[m], bv[n], acc[m][n], 0, 0, 0);
    __syncthreads();
  }

#pragma unroll
  for (int m = 0; m < 4; ++m) {
    const int grow0 = m0 + wr * 64 + m * 16 + kq * 4;
#pragma unroll
    for (int n = 0; n < 4; ++n) {
      const int gcol = n0 + wc * 64 + n * 16 + lr;
#pragma unroll
      for (int r = 0; r < 4; ++r) {
        const long gi = coff + (long)(grow0 + r) * ldc + gcol;
        float v = acc[m][n][r];
        if (EPI == 0) {
          ((unsigned short*)Cbase)[gi] = f2bf(v + bias[gcol]);
        } else if (EPI == 1) {
          ((float*)Cbase)[gi] = v + bias[gcol] + Res[gi];
        } else {
          ((unsigned short*)Cbase)[gi] = f2bf(v);
        }
      }
    }
  }
}

// ---------------- G partials via MFMA: Gpart[z][p] = Q_chunk^T Q_chunk -------
__global__ __launch_bounds__(256) void compute_g(const unsigned short* __restrict__ fused,
                                                 float* __restrict__ Gpart)
{
  __shared__ __align__(16) unsigned short Qs[64 * 136];
  const int z = blockIdx.x;            // b*32+n
  const int b = z >> 5, n = z & 31;
  const unsigned short* Q = fused + (long)b * S_ * H3_ + n * 384;
  const int t = threadIdx.x;
  const int w = t >> 6, l = t & 63;
  const int l31 = l & 31, hi = l >> 5;
  const int ar0 = (w & 1) * 2, ac0 = (w >> 1) * 2;

  f32x16 acc[2][2];
#pragma unroll
  for (int i = 0; i < 2; ++i)
#pragma unroll
    for (int j = 0; j < 2; ++j)
#pragma unroll
      for (int r = 0; r < 16; ++r) acc[i][j][r] = 0.f;

  const int sbeg = blockIdx.y * (S_ / GP_);

  for (int ss0 = 0; ss0 < S_ / GP_; ss0 += 64) {
    __syncthreads();
#pragma unroll
    for (int pass = 0; pass < 4; ++pass) {
      const int sL = pass * 16 + (t >> 4);
      const int c = t & 15;
      uint4 v = *(const uint4*)(Q + (long)(sbeg + ss0 + sL) * H3_ + c * 8);
      *(uint4*)&Qs[sL * 136 + c * 8] = v;
    }
    __syncthreads();

#pragma unroll
    for (int ks = 0; ks < 4; ++ks) {
      const int sb = ks * 16 + hi * 8;
      bf16x8 fa[2], fb[2];
#pragma unroll
      for (int i = 0; i < 2; ++i) {
        const int colA = (ar0 + i) * 32 + l31;
        const int colB = (ac0 + i) * 32 + l31;
        bf16x8 ra, rbv;
#pragma unroll
        for (int j = 0; j < 8; ++j) {
          ra[j]  = u2bf(Qs[(sb + j) * 136 + colA]);
          rbv[j] = u2bf(Qs[(sb + j) * 136 + colB]);
        }
        fa[i] = ra; fb[i] = rbv;
      }
#pragma unroll
      for (int i = 0; i < 2; ++i)
#pragma unroll
        for (int j = 0; j < 2; ++j)
          acc[i][j] = __builtin_amdgcn_mfma_f32_32x32x16_bf16(fa[i], fb[j], acc[i][j], 0, 0, 0);
    }
  }

  float* Gp = Gpart + ((long)z * GP_ + blockIdx.y) * 16384;
#pragma unroll
  for (int i = 0; i < 2; ++i) {
    const int rowb = (ar0 + i) * 32 + 4 * hi;
#pragma unroll
    for (int j = 0; j < 2; ++j) {
      const int col = (ac0 + j) * 32 + l31;
#pragma unroll
      for (int r = 0; r < 16; ++r) {
        const int row = rowb + (r & 3) + 8 * (r >> 2);
        Gp[row * 128 + col] = acc[i][j][r];
      }
    }
  }
}

// ---------------- register-resident Gauss-Jordan inverse of SPD 128x128 ------
__global__ __launch_bounds__(1024) void invert_g(const float* __restrict__ Gpart,
                                                 unsigned short* __restrict__ Ginv)
{
  __shared__ __align__(16) float prow[2][128];
  __shared__ __align__(16) float pcol[2][128];
  const int z = blockIdx.x;
  const int t = threadIdx.x;
  const int c  = t & 127;
  const int rg = t >> 7;
  const float* Gz = Gpart + (long)z * GP_ * 16384;

  float a[16];
#pragma unroll
  for (int i = 0; i < 16; ++i) {
    const int idx = (rg * 16 + i) * 128 + c;
    float s = 0.f;
#pragma unroll
    for (int p = 0; p < GP_; ++p) s += Gz[p * 16384 + idx];
    a[i] = s;
  }

  for (int p = 0; p < 128; ++p) {
    const int buf = p & 1;
    const int prg = p >> 4, pi = p & 15;
    if (rg == prg) {
      float v = a[0];
#pragma unroll
      for (int i = 1; i < 16; ++i) v = (pi == i) ? a[i] : v;
      prow[buf][c] = v;
    }
    if (c == p) {
#pragma unroll
      for (int q = 0; q < 4; ++q) {
        float4 w4 = make_float4(a[q * 4], a[q * 4 + 1], a[q * 4 + 2], a[q * 4 + 3]);
        *(float4*)&pcol[buf][rg * 16 + q * 4] = w4;
      }
    }
    __syncthreads();
    const float invp = 1.0f / prow[buf][p];
    const float rowv = (c == p) ? invp : prow[buf][c] * invp;
#pragma unroll
    for (int q = 0; q < 4; ++q) {
      const float4 pc4 = *(const float4*)&pcol[buf][rg * 16 + q * 4];
      const float pcv[4] = {pc4.x, pc4.y, pc4.z, pc4.w};
#pragma unroll
      for (int j = 0; j < 4; ++j) {
        const int i = q * 4 + j;
        const int r = rg * 16 + i;
        const float cur = (c == p) ? 0.f : a[i];
        a[i] = (r == p) ? rowv : cur - pcv[j] * rowv;
      }
    }
  }
  unsigned short* Oz = Ginv + (long)z * 16384;
#pragma unroll
  for (int i = 0; i < 16; ++i) Oz[(rg * 16 + i) * 128 + c] = f2bf(a[i]);
}

// ---------------- per-position 32x32 head attention (MFMA grams + MFMA PV) ---
// w = g1/128 + alib_j*g2 via per-wave d-slice MFMA grams (r12, verified);
// softmax writes P as bf16 into padded [32][34] LDS; PV = P(32x32) @ V(32x128)
// via 2 mfma_32x32x16 per wave (wave w -> d-slice w*32), epilogue scales by
// pden[row] (broadcast) and writes coalesced u16 segments.
__global__ __launch_bounds__(256) void attn_pos(
    const unsigned short* __restrict__ fused, const unsigned short* __restrict__ Zb,
    const float* __restrict__ alibi, unsigned short* __restrict__ ctx)
{
  __shared__ __align__(16) unsigned short q_s[32 * 136];   // 8.5 KB
  __shared__ __align__(16) unsigned short k_s[32 * 136];
  __shared__ __align__(16) unsigned short z_s[32 * 136];
  __shared__ __align__(16) unsigned short v_s[32 * 128];   // 8 KB (gload linear)
  __shared__ float part[4][32][33];                        // 16.5 KB
  __shared__ float wsh[NH_][NH_ + 1];
  __shared__ unsigned short pbf[32 * 34];                  // P bf16, stride 34
  __shared__ float pden[NH_];
  __shared__ float alib[NH_];

  const int s = blockIdx.x, b = blockIdx.y;
  const int t = threadIdx.x;
  const int w = t >> 6, l = t & 63;
  const int l31 = l & 31, hi = l >> 5;
  const unsigned short* src = fused + ((long)b * S_ + s) * H3_;
  const unsigned short* zg = Zb + ((long)b * S_ + s) * H_;

  if (t < NH_) alib[t] = 0.08838834764831845f * alibi[((long)(b * NH_ + t)) * S_ + s];

  // v via gload_lds, linear [head][d]
  {
    const int i0 = t >> 4, c = t & 15;
    gload_lds16(src + i0 * 384 + 256 + c * 8,        (char*)v_s + w * 1024);
    gload_lds16(src + (i0 + 16) * 384 + 256 + c * 8, (char*)v_s + 4096 + w * 1024);
  }
  // q,k,z reg-staged into padded [32][136]
  {
    const int row = t >> 3, c = (t & 7) * 16;
    uint4 a0 = *(const uint4*)(src + row * 384 + c);
    uint4 a1 = *(const uint4*)(src + row * 384 + c + 8);
    uint4 b0 = *(const uint4*)(src + row * 384 + 128 + c);
    uint4 b1 = *(const uint4*)(src + row * 384 + 128 + c + 8);
    uint4 c0 = *(const uint4*)(zg + row * 128 + c);
    uint4 c1 = *(const uint4*)(zg + row * 128 + c + 8);
    *(uint4*)&q_s[row * 136 + c] = a0; *(uint4*)&q_s[row * 136 + c + 8] = a1;
    *(uint4*)&k_s[row * 136 + c] = b0; *(uint4*)&k_s[row * 136 + c + 8] = b1;
    *(uint4*)&z_s[row * 136 + c] = c0; *(uint4*)&z_s[row * 136 + c + 8] = c1;
  }
  __syncthreads();

  // per-wave d-slice grams
  {
    f32x16 g1, g2;
#pragma unroll
    for (int r = 0; r < 16; ++r) { g1[r] = 0.f; g2[r] = 0.f; }
#pragma unroll
    for (int ks = 0; ks < 2; ++ks) {
      const int off = w * 32 + ks * 16 + hi * 8;
      bf16x8 aq = *(const bf16x8*)&q_s[l31 * 136 + off];
      bf16x8 bk = *(const bf16x8*)&k_s[l31 * 136 + off];
      bf16x8 bz = *(const bf16x8*)&z_s[l31 * 136 + off];
      g1 = __builtin_amdgcn_mfma_f32_32x32x16_bf16(aq, bk, g1, 0, 0, 0);
      g2 = __builtin_amdgcn_mfma_f32_32x32x16_bf16(aq, bz, g2, 0, 0, 0);
    }
    const float aj = alib[l31];
#pragma unroll
    for (int r = 0; r < 16; ++r) {
      const int row = (r & 3) + 8 * (r >> 2) + 4 * hi;
      part[w][row][l31] = 0.0078125f * g1[r] + aj * g2[r];
    }
  }
  __syncthreads();

  // reduce 4 wave-partials into wsh
#pragma unroll
  for (int e = 0; e < 4; ++e) {
    const int idx = t * 4 + e;
    const int ii = idx >> 5, jj = idx & 31;
    wsh[ii][jj] = part[0][ii][jj] + part[1][ii][jj] + part[2][ii][jj] + part[3][ii][jj];
  }
  __syncthreads();

  // wave-parallel softmax: 8-lane group owns row i; write P as bf16
  const int i = t >> 3;
  const int j0 = (t & 7) * 4;
  float wv[4];
#pragma unroll
  for (int jj = 0; jj < 4; ++jj) wv[jj] = wsh[i][j0 + jj];
  float vmax = fmaxf(fmaxf(wv[0], wv[1]), fmaxf(wv[2], wv[3]));
  vmax = fmaxf(vmax, __shfl_xor(vmax, 1));
  vmax = fmaxf(vmax, __shfl_xor(vmax, 2));
  vmax = fmaxf(vmax, __shfl_xor(vmax, 4));
  float ssum = 0.f;
#pragma unroll
  for (int jj = 0; jj < 4; ++jj) { wv[jj] = __expf(wv[jj] - vmax); ssum += wv[jj]; }
#pragma unroll
  for (int jj = 0; jj < 4; ++jj) pbf[i * 34 + j0 + jj] = f2bf(wv[jj]);
  ssum += __shfl_xor(ssum, 1);
  ssum += __shfl_xor(ssum, 2);
  ssum += __shfl_xor(ssum, 4);
  if ((t & 7) == 0) pden[i] = 1.0f / (ssum + 1e-8f);
  __syncthreads();

  // PV via MFMA: wave w -> d-slice w*32..w*32+31
  {
    f32x16 cacc;
#pragma unroll
    for (int r = 0; r < 16; ++r) cacc[r] = 0.f;
    bf16x8 pa[2], vb[2];
#pragma unroll
    for (int ks = 0; ks < 2; ++ks) {
      bf16x8 p8, v8;
#pragma unroll
      for (int jj = 0; jj < 8; ++jj) {
        const int k = ks * 16 + hi * 8 + jj;
        p8[jj] = u2bf(pbf[l31 * 34 + k]);            // A: row=l31(i), k
        v8[jj] = u2bf(v_s[k * 128 + w * 32 + l31]);  // B: col=l31(d), k=j
      }
      pa[ks] = p8; vb[ks] = v8;
    }
    cacc = __builtin_amdgcn_mfma_f32_32x32x16_bf16(pa[0], vb[0], cacc, 0, 0, 0);
    cacc = __builtin_amdgcn_mfma_f32_32x32x16_bf16(pa[1], vb[1], cacc, 0, 0, 0);

    unsigned short* cb = ctx + ((long)b * S_ + s) * H_ + w * 32 + l31;
#pragma unroll
    for (int r = 0; r < 16; ++r) {
      const int row = (r & 3) + 8 * (r >> 2) + 4 * hi;   // head index i
      cb[row * HD_] = f2bf(cacc[r] * pden[row]);
    }
  }
}

// -----------------------------------------------------------------------------
extern "C" void kernel_launch(void* const* d_in, const int* in_sizes, int n_in,
                              void* d_out, int out_size, void* d_ws, size_t ws_size,
                              hipStream_t stream)
{
  (void)in_sizes; (void)n_in; (void)out_size; (void)ws_size;
  const float* hidden   = (const float*)d_in[0];
  const float* residual = (const float*)d_in[1];
  const float* alibi    = (const float*)d_in[2];
  const float* Wqkv     = (const float*)d_in[4];
  const float* bqkv     = (const float*)d_in[5];
  const float* Wd       = (const float*)d_in[6];
  const float* bd       = (const float*)d_in[7];
  float* out = (float*)d_out;

  char* ws = (char*)d_ws;
  size_t off = 0;
  auto carve = [&](size_t bytes) -> void* {
    void* p = ws + off;
    off += (bytes + 255) & ~(size_t)255;
    return p;
  };
  const long nHid = (long)B_ * S_ * H_;
  const long nWq  = (long)H3_ * H_;
  unsigned short* hid_bf   = (unsigned short*)carve((size_t)nHid * 2);
  unsigned short* wqkv_bf  = (unsigned short*)carve((size_t)nWq * 2);
  unsigned short* wd_bf    = (unsigned short*)carve((size_t)H_ * H_ * 2);
  unsigned short* fused_bf = (unsigned short*)carve((size_t)B_ * S_ * H3_ * 2);
  unsigned short* z_bf     = (unsigned short*)carve((size_t)nHid * 2);
  unsigned short* ctx_bf   = (unsigned short*)carve((size_t)nHid * 2);
  float*          Gpart    = (float*)carve((size_t)64 * GP_ * 16384 * 4);
  unsigned short* ginv_bf  = (unsigned short*)carve((size_t)64 * 16384 * 2);

  // 1) bf16 casts (single launch, 3 segments)
  cvt3<<<2048, 256, 0, stream>>>(hidden, hid_bf, nHid,
                                 Wqkv, wqkv_bf, nWq,
                                 Wd, wd_bf, (long)H_ * H_);

  // 2) fused = hidden @ Wqkv^T + b_qkv  (bf16 out)
  gemm256<0><<<dim3(H3_ / 256, (B_ * S_) / 256, 1), 512, 0, stream>>>(
      hid_bf, wqkv_bf, fused_bf, bqkv, nullptr, H_, H_, H3_, H_);

  // 3) G partials via MFMA -> Ginv via register Gauss-Jordan (sums partials)
  compute_g<<<dim3(64, GP_), 256, 0, stream>>>(fused_bf, Gpart);
  invert_g<<<64, 1024, 0, stream>>>(Gpart, ginv_bf);

  // 4) Z[b,s,n,:] = Ginv_{b,n} q_{b,n}(s)   (small batched GEMM, 128² kernel)
  gemm_bt<2><<<dim3(1, S_ / 128, 64), 256, 0, stream>>>(
      fused_bf, ginv_bf, z_bf, nullptr, nullptr, H3_, HD_, H_, HD_,
      (long)S_ * H3_, 384, (long)32 * 16384, 16384, (long)S_ * H_, HD_);

  // 5) per-position 32x32 head attention -> ctx (bf16)
  attn_pos<<<dim3(S_, B_), 256, 0, stream>>>(fused_bf, z_bf, alibi, ctx_bf);

  // 6) out = ctx @ Wd^T + b_dense + residual  (f32 out)
  gemm256<1><<<dim3(H_ / 256, (B_ * S_) / 256, 1), 512, 0, stream>>>(
      ctx_bf, wd_bf, out, bd, residual, H_, H_, H_, H_);
}

// Round 14
// 754.713 us; speedup vs baseline: 1.7281x; 1.0065x over previous
//
#include <hip/hip_runtime.h>

#define B_  2
#define S_  2048
#define NH_ 32
#define HD_ 128
#define H_  4096
#define H3_ 12288
#define GP_ 8   // compute_g partial chunks

typedef __bf16 bf16x8 __attribute__((ext_vector_type(8)));
typedef float  f32x4  __attribute__((ext_vector_type(4)));
typedef float  f32x16 __attribute__((ext_vector_type(16)));

__device__ __forceinline__ unsigned short f2bf(float f) {
  unsigned int u = __float_as_uint(f);
  u += 0x7fffu + ((u >> 16) & 1u);
  return (unsigned short)(u >> 16);
}
__device__ __forceinline__ __bf16 u2bf(unsigned short u) {
  return *reinterpret_cast<__bf16*>(&u);
}
__device__ __forceinline__ void unpack8(uint4 r, float f[8]) {
  f[0] = __uint_as_float(r.x << 16); f[1] = __uint_as_float(r.x & 0xffff0000u);
  f[2] = __uint_as_float(r.y << 16); f[3] = __uint_as_float(r.y & 0xffff0000u);
  f[4] = __uint_as_float(r.z << 16); f[5] = __uint_as_float(r.z & 0xffff0000u);
  f[6] = __uint_as_float(r.w << 16); f[7] = __uint_as_float(r.w & 0xffff0000u);
}
__device__ __forceinline__ void gload_lds16(const void* g, void* l) {
  __builtin_amdgcn_global_load_lds(
      (const __attribute__((address_space(1))) unsigned int*)g,
      (__attribute__((address_space(3))) unsigned int*)l, 16, 0, 0);
}

// ---------------- fused f32 -> bf16 converts (one launch, 3 segments) --------
__device__ __forceinline__ void cvt_seg(const float* __restrict__ in,
                                        unsigned short* __restrict__ out,
                                        long n, long base, long stride) {
  for (long i = base; i < n; i += stride) {
    float4 v = *(const float4*)(in + i);
    ushort4 o;
    o.x = f2bf(v.x); o.y = f2bf(v.y); o.z = f2bf(v.z); o.w = f2bf(v.w);
    *(ushort4*)(out + i) = o;
  }
}
__global__ __launch_bounds__(256) void cvt3(
    const float* __restrict__ a, unsigned short* __restrict__ oa, long na,
    const float* __restrict__ b, unsigned short* __restrict__ ob, long nb,
    const float* __restrict__ c, unsigned short* __restrict__ oc, long nc) {
  const long base = ((long)blockIdx.x * 256 + threadIdx.x) * 4;
  const long stride = (long)gridDim.x * 256 * 4;
  cvt_seg(a, oa, na, base, stride);
  cvt_seg(b, ob, nb, base, stride);
  cvt_seg(c, oc, nc, base, stride);
}

// =============================================================================
// 256x256-tile bf16 GEMM (measured-best structure: 8 waves (2x4), BK=32,
// 3-stage LDS pipeline (96 KB), counted vmcnt(4), chunk-XOR swizzle
// (row bits 1..2), setprio around the MFMA cluster).
// EPI 0: bf16 out + bias ; EPI 1: f32 out + bias + residual
// =============================================================================
template <int EPI>
__global__ __launch_bounds__(512, 2) void gemm256(
    const unsigned short* __restrict__ A, const unsigned short* __restrict__ Bt,
    void* __restrict__ C, const float* __restrict__ bias, const float* __restrict__ Res,
    int lda, int ldb, int ldc, int K)
{
  __shared__ __align__(16) unsigned short lds[3 * 16384];

  const int tid = threadIdx.x;
  const int w = tid >> 6, l = tid & 63;

  const int gx = gridDim.x;
  const int nwg = gx * gridDim.y;
  const int flat = blockIdx.y * gx + blockIdx.x;
  const int swz = (flat & 7) * (nwg >> 3) + (flat >> 3);
  const int m0 = (swz / gx) * 256;
  const int n0 = (swz % gx) * 256;

  const int wr = w >> 2, wc = w & 3;
  const int lr16 = l & 15, kq = l >> 4;

  const int srow = w * 16 + (l >> 2);
  const int scs  = (((l & 3) ^ ((l >> 3) & 3)) << 3);
  const unsigned short* ga = A  + (long)(m0 + srow) * lda + scs;
  const unsigned short* gb = Bt + (long)(n0 + srow) * ldb + scs;
  unsigned short* sb_w = lds + w * 512;

  const int rchunk = ((kq ^ ((l >> 1) & 3)) << 3);

  const int NT = K >> 5;

  const f32x4 zero = {0.f, 0.f, 0.f, 0.f};
  f32x4 acc[8][4];
#pragma unroll
  for (int m = 0; m < 8; ++m)
#pragma unroll
    for (int n = 0; n < 4; ++n) acc[m][n] = zero;

  auto stage = [&](int kt, int s) {
    const unsigned short* a = ga + (long)kt * 32;
    const unsigned short* b = gb + (long)kt * 32;
    unsigned short* d = sb_w + s * 16384;
    gload_lds16(a,                  d);
    gload_lds16(a + 128L * lda,     d + 4096);
    gload_lds16(b,                  d + 8192);
    gload_lds16(b + 128L * ldb,     d + 12288);
  };

  stage(0, 0);
  stage(1, 1);
  asm volatile("s_waitcnt vmcnt(4)" ::: "memory");
  __builtin_amdgcn_s_barrier();

  for (int t = 0; t < NT; ++t) {
    const int cur = t % 3;
    if (t + 2 < NT) stage(t + 2, (t + 2) % 3);

    const unsigned short* sa = lds + cur * 16384;
    const unsigned short* sbB = sa + 8192;
    bf16x8 av[8], bv[4];
#pragma unroll
    for (int n = 0; n < 4; ++n)
      bv[n] = *(const bf16x8*)&sbB[(wc * 64 + n * 16 + lr16) * 32 + rchunk];
#pragma unroll
    for (int m = 0; m < 8; ++m)
      av[m] = *(const bf16x8*)&sa[(wr * 128 + m * 16 + lr16) * 32 + rchunk];

    __builtin_amdgcn_s_setprio(1);
#pragma unroll
    for (int m = 0; m < 8; ++m)
#pragma unroll
      for (int n = 0; n < 4; ++n)
        acc[m][n] = __builtin_amdgcn_mfma_f32_16x16x32_bf16(av[m], bv[n], acc[m][n], 0, 0, 0);
    __builtin_amdgcn_s_setprio(0);

    if (t + 1 < NT) {
      if (t + 2 < NT) asm volatile("s_waitcnt vmcnt(4)" ::: "memory");
      else            asm volatile("s_waitcnt vmcnt(0)" ::: "memory");
      __builtin_amdgcn_s_barrier();
    }
  }

#pragma unroll
  for (int m = 0; m < 8; ++m) {
    const int grow0 = m0 + wr * 128 + m * 16 + kq * 4;
#pragma unroll
    for (int n = 0; n < 4; ++n) {
      const int gcol = n0 + wc * 64 + n * 16 + lr16;
#pragma unroll
      for (int i = 0; i < 4; ++i) {
        const long gi = (long)(grow0 + i) * ldc + gcol;
        float v = acc[m][n][i];
        if (EPI == 0) {
          ((unsigned short*)C)[gi] = f2bf(v + bias[gcol]);
        } else {
          ((float*)C)[gi] = v + bias[gcol] + Res[gi];
        }
      }
    }
  }
}

// ---------------- single-stage Z-GEMM: Z[b,s,n,:] = Ginv_{b,n} q_{b,n}(s) ----
// Whole A-panel (128 rows of q, K=128) + whole Ginv (128x128) staged once into
// 64 KB LDS (XOR-swizzled chunks pc ^= row&7, both sides), ONE barrier,
// 64 MFMA per wave (4 waves, wave tile 64x64), bf16 out.
__global__ __launch_bounds__(256) void zgemm(
    const unsigned short* __restrict__ fused, const unsigned short* __restrict__ Ginv,
    unsigned short* __restrict__ Zb)
{
  __shared__ __align__(16) unsigned short As[128 * 128];
  __shared__ __align__(16) unsigned short Bs[128 * 128];
  const int z = blockIdx.z;           // b*32+n
  const int zb = z >> 5, zn = z & 31;
  const int m0 = blockIdx.y * 128;
  const unsigned short* A  = fused + (long)zb * S_ * H3_ + zn * 384 + (long)m0 * H3_;
  const unsigned short* Bg = Ginv + (long)z * 16384;
  const int t = threadIdx.x;
  const int wave = t >> 6, l = t & 63;
  const int wr = wave >> 1, wc = wave & 1;
  const int lr = l & 15, kq = l >> 4;

  // stage: 8 rounds; slot s = r*256+t -> row = s>>4, phys chunk = t&15,
  // source chunk = (t&15) ^ (row&7). LDS dest linear (wave-uniform base).
  {
    const int pc = t & 15;
#pragma unroll
    for (int r = 0; r < 8; ++r) {
      const int row = (r * 256 + t) >> 4;
      const int sc = ((pc ^ (row & 7)) << 3);
      gload_lds16(A + (long)row * H3_ + sc, (char*)As + r * 4096 + wave * 1024);
      gload_lds16(Bg + row * 128 + sc,      (char*)Bs + r * 4096 + wave * 1024);
    }
  }
  asm volatile("s_waitcnt vmcnt(0)" ::: "memory");
  __syncthreads();

  const f32x4 zero = {0.f, 0.f, 0.f, 0.f};
  f32x4 acc[4][4];
#pragma unroll
  for (int m = 0; m < 4; ++m)
#pragma unroll
    for (int n = 0; n < 4; ++n) acc[m][n] = zero;

#pragma unroll
  for (int kk = 0; kk < 4; ++kk) {      // K-steps of 32
    bf16x8 av[4], bv[4];
#pragma unroll
    for (int m = 0; m < 4; ++m) {
      const int row = wr * 64 + m * 16 + lr;
      av[m] = *(const bf16x8*)&As[row * 128 + (((kk * 4 + kq) ^ (row & 7)) << 3)];
    }
#pragma unroll
    for (int n = 0; n < 4; ++n) {
      const int row = wc * 64 + n * 16 + lr;
      bv[n] = *(const bf16x8*)&Bs[row * 128 + (((kk * 4 + kq) ^ (row & 7)) << 3)];
    }
#pragma unroll
    for (int m = 0; m < 4; ++m)
#pragma unroll
      for (int n = 0; n < 4; ++n)
        acc[m][n] = __builtin_amdgcn_mfma_f32_16x16x32_bf16(av[m], bv[n], acc[m][n], 0, 0, 0);
  }

  // epilogue: C/D col=lane&15, row=(lane>>4)*4+r ; Z layout [b][s][n*128+d]
#pragma unroll
  for (int m = 0; m < 4; ++m) {
    const int grow0 = wr * 64 + m * 16 + kq * 4;
#pragma unroll
    for (int n = 0; n < 4; ++n) {
      const int gcol = wc * 64 + n * 16 + lr;
#pragma unroll
      for (int r = 0; r < 4; ++r) {
        const long gi = ((long)zb * S_ + m0 + grow0 + r) * H_ + zn * HD_ + gcol;
        Zb[gi] = f2bf(acc[m][n][r]);
      }
    }
  }
}

// ---------------- G partials via MFMA: Gpart[z][p] = Q_chunk^T Q_chunk -------
__global__ __launch_bounds__(256) void compute_g(const unsigned short* __restrict__ fused,
                                                 float* __restrict__ Gpart)
{
  __shared__ __align__(16) unsigned short Qs[64 * 136];
  const int z = blockIdx.x;            // b*32+n
  const int b = z >> 5, n = z & 31;
  const unsigned short* Q = fused + (long)b * S_ * H3_ + n * 384;
  const int t = threadIdx.x;
  const int w = t >> 6, l = t & 63;
  const int l31 = l & 31, hi = l >> 5;
  const int ar0 = (w & 1) * 2, ac0 = (w >> 1) * 2;

  f32x16 acc[2][2];
#pragma unroll
  for (int i = 0; i < 2; ++i)
#pragma unroll
    for (int j = 0; j < 2; ++j)
#pragma unroll
      for (int r = 0; r < 16; ++r) acc[i][j][r] = 0.f;

  const int sbeg = blockIdx.y * (S_ / GP_);

  for (int ss0 = 0; ss0 < S_ / GP_; ss0 += 64) {
    __syncthreads();
#pragma unroll
    for (int pass = 0; pass < 4; ++pass) {
      const int sL = pass * 16 + (t >> 4);
      const int c = t & 15;
      uint4 v = *(const uint4*)(Q + (long)(sbeg + ss0 + sL) * H3_ + c * 8);
      *(uint4*)&Qs[sL * 136 + c * 8] = v;
    }
    __syncthreads();

#pragma unroll
    for (int ks = 0; ks < 4; ++ks) {
      const int sb = ks * 16 + hi * 8;
      bf16x8 fa[2], fb[2];
#pragma unroll
      for (int i = 0; i < 2; ++i) {
        const int colA = (ar0 + i) * 32 + l31;
        const int colB = (ac0 + i) * 32 + l31;
        bf16x8 ra, rbv;
#pragma unroll
        for (int j = 0; j < 8; ++j) {
          ra[j]  = u2bf(Qs[(sb + j) * 136 + colA]);
          rbv[j] = u2bf(Qs[(sb + j) * 136 + colB]);
        }
        fa[i] = ra; fb[i] = rbv;
      }
#pragma unroll
      for (int i = 0; i < 2; ++i)
#pragma unroll
        for (int j = 0; j < 2; ++j)
          acc[i][j] = __builtin_amdgcn_mfma_f32_32x32x16_bf16(fa[i], fb[j], acc[i][j], 0, 0, 0);
    }
  }

  float* Gp = Gpart + ((long)z * GP_ + blockIdx.y) * 16384;
#pragma unroll
  for (int i = 0; i < 2; ++i) {
    const int rowb = (ar0 + i) * 32 + 4 * hi;
#pragma unroll
    for (int j = 0; j < 2; ++j) {
      const int col = (ac0 + j) * 32 + l31;
#pragma unroll
      for (int r = 0; r < 16; ++r) {
        const int row = rowb + (r & 3) + 8 * (r >> 2);
        Gp[row * 128 + col] = acc[i][j][r];
      }
    }
  }
}

// ---------------- register-resident Gauss-Jordan inverse of SPD 128x128 ------
__global__ __launch_bounds__(1024) void invert_g(const float* __restrict__ Gpart,
                                                 unsigned short* __restrict__ Ginv)
{
  __shared__ __align__(16) float prow[2][128];
  __shared__ __align__(16) float pcol[2][128];
  const int z = blockIdx.x;
  const int t = threadIdx.x;
  const int c  = t & 127;
  const int rg = t >> 7;
  const float* Gz = Gpart + (long)z * GP_ * 16384;

  float a[16];
#pragma unroll
  for (int i = 0; i < 16; ++i) {
    const int idx = (rg * 16 + i) * 128 + c;
    float s = 0.f;
#pragma unroll
    for (int p = 0; p < GP_; ++p) s += Gz[p * 16384 + idx];
    a[i] = s;
  }

  for (int p = 0; p < 128; ++p) {
    const int buf = p & 1;
    const int prg = p >> 4, pi = p & 15;
    if (rg == prg) {
      float v = a[0];
#pragma unroll
      for (int i = 1; i < 16; ++i) v = (pi == i) ? a[i] : v;
      prow[buf][c] = v;
    }
    if (c == p) {
#pragma unroll
      for (int q = 0; q < 4; ++q) {
        float4 w4 = make_float4(a[q * 4], a[q * 4 + 1], a[q * 4 + 2], a[q * 4 + 3]);
        *(float4*)&pcol[buf][rg * 16 + q * 4] = w4;
      }
    }
    __syncthreads();
    const float invp = 1.0f / prow[buf][p];
    const float rowv = (c == p) ? invp : prow[buf][c] * invp;
#pragma unroll
    for (int q = 0; q < 4; ++q) {
      const float4 pc4 = *(const float4*)&pcol[buf][rg * 16 + q * 4];
      const float pcv[4] = {pc4.x, pc4.y, pc4.z, pc4.w};
#pragma unroll
      for (int j = 0; j < 4; ++j) {
        const int i = q * 4 + j;
        const int r = rg * 16 + i;
        const float cur = (c == p) ? 0.f : a[i];
        a[i] = (r == p) ? rowv : cur - pcv[j] * rowv;
      }
    }
  }
  unsigned short* Oz = Ginv + (long)z * 16384;
#pragma unroll
  for (int i = 0; i < 16; ++i) Oz[(rg * 16 + i) * 128 + c] = f2bf(a[i]);
}

// ---------------- per-position 32x32 head attention (MFMA grams + MFMA PV) ---
__global__ __launch_bounds__(256) void attn_pos(
    const unsigned short* __restrict__ fused, const unsigned short* __restrict__ Zb,
    const float* __restrict__ alibi, unsigned short* __restrict__ ctx)
{
  __shared__ __align__(16) unsigned short q_s[32 * 136];
  __shared__ __align__(16) unsigned short k_s[32 * 136];
  __shared__ __align__(16) unsigned short z_s[32 * 136];
  __shared__ __align__(16) unsigned short v_s[32 * 128];
  __shared__ float part[4][32][33];
  __shared__ unsigned short pbf[32 * 34];
  __shared__ float pden[NH_];
  __shared__ float alib[NH_];

  const int s = blockIdx.x, b = blockIdx.y;
  const int t = threadIdx.x;
  const int w = t >> 6, l = t & 63;
  const int l31 = l & 31, hi = l >> 5;
  const unsigned short* src = fused + ((long)b * S_ + s) * H3_;
  const unsigned short* zg = Zb + ((long)b * S_ + s) * H_;

  if (t < NH_) alib[t] = 0.08838834764831845f * alibi[((long)(b * NH_ + t)) * S_ + s];

  {
    const int i0 = t >> 4, c = t & 15;
    gload_lds16(src + i0 * 384 + 256 + c * 8,        (char*)v_s + w * 1024);
    gload_lds16(src + (i0 + 16) * 384 + 256 + c * 8, (char*)v_s + 4096 + w * 1024);
  }
  {
    const int row = t >> 3, c = (t & 7) * 16;
    uint4 a0 = *(const uint4*)(src + row * 384 + c);
    uint4 a1 = *(const uint4*)(src + row * 384 + c + 8);
    uint4 b0 = *(const uint4*)(src + row * 384 + 128 + c);
    uint4 b1 = *(const uint4*)(src + row * 384 + 128 + c + 8);
    uint4 c0 = *(const uint4*)(zg + row * 128 + c);
    uint4 c1 = *(const uint4*)(zg + row * 128 + c + 8);
    *(uint4*)&q_s[row * 136 + c] = a0; *(uint4*)&q_s[row * 136 + c + 8] = a1;
    *(uint4*)&k_s[row * 136 + c] = b0; *(uint4*)&k_s[row * 136 + c + 8] = b1;
    *(uint4*)&z_s[row * 136 + c] = c0; *(uint4*)&z_s[row * 136 + c + 8] = c1;
  }
  __syncthreads();

  // per-wave d-slice grams
  {
    f32x16 g1, g2;
#pragma unroll
    for (int r = 0; r < 16; ++r) { g1[r] = 0.f; g2[r] = 0.f; }
#pragma unroll
    for (int ks = 0; ks < 2; ++ks) {
      const int off = w * 32 + ks * 16 + hi * 8;
      bf16x8 aq = *(const bf16x8*)&q_s[l31 * 136 + off];
      bf16x8 bk = *(const bf16x8*)&k_s[l31 * 136 + off];
      bf16x8 bz = *(const bf16x8*)&z_s[l31 * 136 + off];
      g1 = __builtin_amdgcn_mfma_f32_32x32x16_bf16(aq, bk, g1, 0, 0, 0);
      g2 = __builtin_amdgcn_mfma_f32_32x32x16_bf16(aq, bz, g2, 0, 0, 0);
    }
    const float aj = alib[l31];
#pragma unroll
    for (int r = 0; r < 16; ++r) {
      const int row = (r & 3) + 8 * (r >> 2) + 4 * hi;
      part[w][row][l31] = 0.0078125f * g1[r] + aj * g2[r];
    }
  }
  __syncthreads();

  // wave-parallel softmax, reading the 4 wave-partials directly (no wsh pass)
  const int i = t >> 3;
  const int j0 = (t & 7) * 4;
  float wv[4];
#pragma unroll
  for (int jj = 0; jj < 4; ++jj)
    wv[jj] = part[0][i][j0 + jj] + part[1][i][j0 + jj]
           + part[2][i][j0 + jj] + part[3][i][j0 + jj];
  float vmax = fmaxf(fmaxf(wv[0], wv[1]), fmaxf(wv[2], wv[3]));
  vmax = fmaxf(vmax, __shfl_xor(vmax, 1));
  vmax = fmaxf(vmax, __shfl_xor(vmax, 2));
  vmax = fmaxf(vmax, __shfl_xor(vmax, 4));
  float ssum = 0.f;
#pragma unroll
  for (int jj = 0; jj < 4; ++jj) { wv[jj] = __expf(wv[jj] - vmax); ssum += wv[jj]; }
#pragma unroll
  for (int jj = 0; jj < 4; ++jj) pbf[i * 34 + j0 + jj] = f2bf(wv[jj]);
  ssum += __shfl_xor(ssum, 1);
  ssum += __shfl_xor(ssum, 2);
  ssum += __shfl_xor(ssum, 4);
  if ((t & 7) == 0) pden[i] = 1.0f / (ssum + 1e-8f);
  __syncthreads();

  // PV via MFMA: wave w -> d-slice w*32..w*32+31
  {
    f32x16 cacc;
#pragma unroll
    for (int r = 0; r < 16; ++r) cacc[r] = 0.f;
    bf16x8 pa[2], vb[2];
#pragma unroll
    for (int ks = 0; ks < 2; ++ks) {
      bf16x8 p8, v8;
#pragma unroll
      for (int jj = 0; jj < 8; ++jj) {
        const int k = ks * 16 + hi * 8 + jj;
        p8[jj] = u2bf(pbf[l31 * 34 + k]);
        v8[jj] = u2bf(v_s[k * 128 + w * 32 + l31]);
      }
      pa[ks] = p8; vb[ks] = v8;
    }
    cacc = __builtin_amdgcn_mfma_f32_32x32x16_bf16(pa[0], vb[0], cacc, 0, 0, 0);
    cacc = __builtin_amdgcn_mfma_f32_32x32x16_bf16(pa[1], vb[1], cacc, 0, 0, 0);

    unsigned short* cb = ctx + ((long)b * S_ + s) * H_ + w * 32 + l31;
#pragma unroll
    for (int r = 0; r < 16; ++r) {
      const int row = (r & 3) + 8 * (r >> 2) + 4 * hi;
      cb[row * HD_] = f2bf(cacc[r] * pden[row]);
    }
  }
}

// -----------------------------------------------------------------------------
extern "C" void kernel_launch(void* const* d_in, const int* in_sizes, int n_in,
                              void* d_out, int out_size, void* d_ws, size_t ws_size,
                              hipStream_t stream)
{
  (void)in_sizes; (void)n_in; (void)out_size; (void)ws_size;
  const float* hidden   = (const float*)d_in[0];
  const float* residual = (const float*)d_in[1];
  const float* alibi    = (const float*)d_in[2];
  const float* Wqkv     = (const float*)d_in[4];
  const float* bqkv     = (const float*)d_in[5];
  const float* Wd       = (const float*)d_in[6];
  const float* bd       = (const float*)d_in[7];
  float* out = (float*)d_out;

  char* ws = (char*)d_ws;
  size_t off = 0;
  auto carve = [&](size_t bytes) -> void* {
    void* p = ws + off;
    off += (bytes + 255) & ~(size_t)255;
    return p;
  };
  const long nHid = (long)B_ * S_ * H_;
  const long nWq  = (long)H3_ * H_;
  unsigned short* hid_bf   = (unsigned short*)carve((size_t)nHid * 2);
  unsigned short* wqkv_bf  = (unsigned short*)carve((size_t)nWq * 2);
  unsigned short* wd_bf    = (unsigned short*)carve((size_t)H_ * H_ * 2);
  unsigned short* fused_bf = (unsigned short*)carve((size_t)B_ * S_ * H3_ * 2);
  unsigned short* z_bf     = (unsigned short*)carve((size_t)nHid * 2);
  unsigned short* ctx_bf   = (unsigned short*)carve((size_t)nHid * 2);
  float*          Gpart    = (float*)carve((size_t)64 * GP_ * 16384 * 4);
  unsigned short* ginv_bf  = (unsigned short*)carve((size_t)64 * 16384 * 2);

  // 1) bf16 casts (single launch, 3 segments)
  cvt3<<<2048, 256, 0, stream>>>(hidden, hid_bf, nHid,
                                 Wqkv, wqkv_bf, nWq,
                                 Wd, wd_bf, (long)H_ * H_);

  // 2) fused = hidden @ Wqkv^T + b_qkv  (bf16 out)
  gemm256<0><<<dim3(H3_ / 256, (B_ * S_) / 256, 1), 512, 0, stream>>>(
      hid_bf, wqkv_bf, fused_bf, bqkv, nullptr, H_, H_, H3_, H_);

  // 3) G partials via MFMA -> Ginv via register Gauss-Jordan (sums partials)
  compute_g<<<dim3(64, GP_), 256, 0, stream>>>(fused_bf, Gpart);
  invert_g<<<64, 1024, 0, stream>>>(Gpart, ginv_bf);

  // 4) Z[b,s,n,:] = Ginv_{b,n} q_{b,n}(s)  (single-stage batched GEMM)
  zgemm<<<dim3(1, S_ / 128, 64), 256, 0, stream>>>(fused_bf, ginv_bf, z_bf);

  // 5) per-position 32x32 head attention -> ctx (bf16)
  attn_pos<<<dim3(S_, B_), 256, 0, stream>>>(fused_bf, z_bf, alibi, ctx_bf);

  // 6) out = ctx @ Wd^T + b_dense + residual  (f32 out)
  gemm256<1><<<dim3(H_ / 256, (B_ * S_) / 256, 1), 512, 0, stream>>>(
      ctx_bf, wd_bf, out, bd, residual, H_, H_, H_, H_);
}

// Round 15
// 742.632 us; speedup vs baseline: 1.7562x; 1.0163x over previous
//
#include <hip/hip_runtime.h>

#define B_  2
#define S_  2048
#define NH_ 32
#define HD_ 128
#define H_  4096
#define H3_ 12288
#define GP_ 8   // compute_g partial chunks

typedef __bf16 bf16x8 __attribute__((ext_vector_type(8)));
typedef float  f32x4  __attribute__((ext_vector_type(4)));
typedef float  f32x16 __attribute__((ext_vector_type(16)));

__device__ __forceinline__ unsigned short f2bf(float f) {
  unsigned int u = __float_as_uint(f);
  u += 0x7fffu + ((u >> 16) & 1u);
  return (unsigned short)(u >> 16);
}
__device__ __forceinline__ __bf16 u2bf(unsigned short u) {
  return *reinterpret_cast<__bf16*>(&u);
}
__device__ __forceinline__ void unpack8(uint4 r, float f[8]) {
  f[0] = __uint_as_float(r.x << 16); f[1] = __uint_as_float(r.x & 0xffff0000u);
  f[2] = __uint_as_float(r.y << 16); f[3] = __uint_as_float(r.y & 0xffff0000u);
  f[4] = __uint_as_float(r.z << 16); f[5] = __uint_as_float(r.z & 0xffff0000u);
  f[6] = __uint_as_float(r.w << 16); f[7] = __uint_as_float(r.w & 0xffff0000u);
}
__device__ __forceinline__ void gload_lds16(const void* g, void* l) {
  __builtin_amdgcn_global_load_lds(
      (const __attribute__((address_space(1))) unsigned int*)g,
      (__attribute__((address_space(3))) unsigned int*)l, 16, 0, 0);
}

// ---------------- fused f32 -> bf16 converts (one launch, 3 segments) --------
__device__ __forceinline__ void cvt_seg(const float* __restrict__ in,
                                        unsigned short* __restrict__ out,
                                        long n, long base, long stride) {
  for (long i = base; i < n; i += stride) {
    float4 v = *(const float4*)(in + i);
    ushort4 o;
    o.x = f2bf(v.x); o.y = f2bf(v.y); o.z = f2bf(v.z); o.w = f2bf(v.w);
    *(ushort4*)(out + i) = o;
  }
}
__global__ __launch_bounds__(256) void cvt3(
    const float* __restrict__ a, unsigned short* __restrict__ oa, long na,
    const float* __restrict__ b, unsigned short* __restrict__ ob, long nb,
    const float* __restrict__ c, unsigned short* __restrict__ oc, long nc) {
  const long base = ((long)blockIdx.x * 256 + threadIdx.x) * 4;
  const long stride = (long)gridDim.x * 256 * 4;
  cvt_seg(a, oa, na, base, stride);
  cvt_seg(b, ob, nb, base, stride);
  cvt_seg(c, oc, nc, base, stride);
}

// =============================================================================
// 256x256-tile bf16 GEMM — 16-wave variant: same 3-stage/96KB pipeline,
// counted vmcnt(2), same chunk-XOR swizzle, but 16 waves with 64x64 wave
// tiles (acc = 64 regs) + __launch_bounds__(1024,4) -> 4 waves/SIMD so the
// LDS-read bursts of some waves overlap the MFMA bursts of others.
// EPI 0: bf16 out + bias ; EPI 1: f32 out + bias + residual
// =============================================================================
template <int EPI>
__global__ __launch_bounds__(1024, 4) void gemm256(
    const unsigned short* __restrict__ A, const unsigned short* __restrict__ Bt,
    void* __restrict__ C, const float* __restrict__ bias, const float* __restrict__ Res,
    int lda, int ldb, int ldc, int K)
{
  __shared__ __align__(16) unsigned short lds[3 * 16384];   // 3 x (A 16KB + B 16KB)

  const int tid = threadIdx.x;
  const int w = tid >> 6, l = tid & 63;

  const int gx = gridDim.x;
  const int nwg = gx * gridDim.y;
  const int flat = blockIdx.y * gx + blockIdx.x;
  const int swz = (flat & 7) * (nwg >> 3) + (flat >> 3);
  const int m0 = (swz / gx) * 256;
  const int n0 = (swz % gx) * 256;

  const int wr = w >> 2, wc = w & 3;      // 4x4 wave grid; wave tile 64x64
  const int lr16 = l & 15, kq = l >> 4;

  // staging: thread covers row tid>>2 (0-255), physical chunk tid&3;
  // pre-swizzled source chunk = (tid&3) ^ (row bits 1..2) = ^ ((tid>>3)&3)
  const int srow = tid >> 2;
  const int scs  = (((tid & 3) ^ ((tid >> 3) & 3)) << 3);
  const unsigned short* ga = A  + (long)(m0 + srow) * lda + scs;
  const unsigned short* gb = Bt + (long)(n0 + srow) * ldb + scs;
  unsigned short* sb_w = lds + w * 512;   // wave-uniform dest (tid*8 elems)

  // ds_read: logical chunk kq of frag-row rr at physical chunk kq^((rr>>1)&3)
  const int rchunk = ((kq ^ ((l >> 1) & 3)) << 3);

  const int NT = K >> 5;

  const f32x4 zero = {0.f, 0.f, 0.f, 0.f};
  f32x4 acc[4][4];
#pragma unroll
  for (int m = 0; m < 4; ++m)
#pragma unroll
    for (int n = 0; n < 4; ++n) acc[m][n] = zero;

  auto stage = [&](int kt, int s) {
    gload_lds16(ga + (long)kt * 32, sb_w + s * 16384);          // A half
    gload_lds16(gb + (long)kt * 32, sb_w + s * 16384 + 8192);   // B half
  };

  stage(0, 0);
  stage(1, 1);
  asm volatile("s_waitcnt vmcnt(2)" ::: "memory");
  __builtin_amdgcn_s_barrier();

  for (int t = 0; t < NT; ++t) {
    const int cur = t % 3;
    if (t + 2 < NT) stage(t + 2, (t + 2) % 3);

    const unsigned short* sa = lds + cur * 16384;
    const unsigned short* sbB = sa + 8192;
    bf16x8 av[4], bv[4];
#pragma unroll
    for (int n = 0; n < 4; ++n)
      bv[n] = *(const bf16x8*)&sbB[(wc * 64 + n * 16 + lr16) * 32 + rchunk];
#pragma unroll
    for (int m = 0; m < 4; ++m)
      av[m] = *(const bf16x8*)&sa[(wr * 64 + m * 16 + lr16) * 32 + rchunk];

    __builtin_amdgcn_s_setprio(1);
#pragma unroll
    for (int m = 0; m < 4; ++m)
#pragma unroll
      for (int n = 0; n < 4; ++n)
        acc[m][n] = __builtin_amdgcn_mfma_f32_16x16x32_bf16(av[m], bv[n], acc[m][n], 0, 0, 0);
    __builtin_amdgcn_s_setprio(0);

    if (t + 1 < NT) {
      if (t + 2 < NT) asm volatile("s_waitcnt vmcnt(2)" ::: "memory");
      else            asm volatile("s_waitcnt vmcnt(0)" ::: "memory");
      __builtin_amdgcn_s_barrier();
    }
  }

  // epilogue: C/D layout col=lane&15, row=(lane>>4)*4+i
#pragma unroll
  for (int m = 0; m < 4; ++m) {
    const int grow0 = m0 + wr * 64 + m * 16 + kq * 4;
#pragma unroll
    for (int n = 0; n < 4; ++n) {
      const int gcol = n0 + wc * 64 + n * 16 + lr16;
#pragma unroll
      for (int i = 0; i < 4; ++i) {
        const long gi = (long)(grow0 + i) * ldc + gcol;
        float v = acc[m][n][i];
        if (EPI == 0) {
          ((unsigned short*)C)[gi] = f2bf(v + bias[gcol]);
        } else {
          ((float*)C)[gi] = v + bias[gcol] + Res[gi];
        }
      }
    }
  }
}

// ---------------- single-stage Z-GEMM: Z[b,s,n,:] = Ginv_{b,n} q_{b,n}(s) ----
__global__ __launch_bounds__(256) void zgemm(
    const unsigned short* __restrict__ fused, const unsigned short* __restrict__ Ginv,
    unsigned short* __restrict__ Zb)
{
  __shared__ __align__(16) unsigned short As[128 * 128];
  __shared__ __align__(16) unsigned short Bs[128 * 128];
  const int z = blockIdx.z;           // b*32+n
  const int zb = z >> 5, zn = z & 31;
  const int m0 = blockIdx.y * 128;
  const unsigned short* A  = fused + (long)zb * S_ * H3_ + zn * 384 + (long)m0 * H3_;
  const unsigned short* Bg = Ginv + (long)z * 16384;
  const int t = threadIdx.x;
  const int wave = t >> 6, l = t & 63;
  const int wr = wave >> 1, wc = wave & 1;
  const int lr = l & 15, kq = l >> 4;

  {
    const int pc = t & 15;
#pragma unroll
    for (int r = 0; r < 8; ++r) {
      const int row = (r * 256 + t) >> 4;
      const int sc = ((pc ^ (row & 7)) << 3);
      gload_lds16(A + (long)row * H3_ + sc, (char*)As + r * 4096 + wave * 1024);
      gload_lds16(Bg + row * 128 + sc,      (char*)Bs + r * 4096 + wave * 1024);
    }
  }
  asm volatile("s_waitcnt vmcnt(0)" ::: "memory");
  __syncthreads();

  const f32x4 zero = {0.f, 0.f, 0.f, 0.f};
  f32x4 acc[4][4];
#pragma unroll
  for (int m = 0; m < 4; ++m)
#pragma unroll
    for (int n = 0; n < 4; ++n) acc[m][n] = zero;

#pragma unroll
  for (int kk = 0; kk < 4; ++kk) {
    bf16x8 av[4], bv[4];
#pragma unroll
    for (int m = 0; m < 4; ++m) {
      const int row = wr * 64 + m * 16 + lr;
      av[m] = *(const bf16x8*)&As[row * 128 + (((kk * 4 + kq) ^ (row & 7)) << 3)];
    }
#pragma unroll
    for (int n = 0; n < 4; ++n) {
      const int row = wc * 64 + n * 16 + lr;
      bv[n] = *(const bf16x8*)&Bs[row * 128 + (((kk * 4 + kq) ^ (row & 7)) << 3)];
    }
#pragma unroll
    for (int m = 0; m < 4; ++m)
#pragma unroll
      for (int n = 0; n < 4; ++n)
        acc[m][n] = __builtin_amdgcn_mfma_f32_16x16x32_bf16(av[m], bv[n], acc[m][n], 0, 0, 0);
  }

#pragma unroll
  for (int m = 0; m < 4; ++m) {
    const int grow0 = wr * 64 + m * 16 + kq * 4;
#pragma unroll
    for (int n = 0; n < 4; ++n) {
      const int gcol = wc * 64 + n * 16 + lr;
#pragma unroll
      for (int r = 0; r < 4; ++r) {
        const long gi = ((long)zb * S_ + m0 + grow0 + r) * H_ + zn * HD_ + gcol;
        Zb[gi] = f2bf(acc[m][n][r]);
      }
    }
  }
}

// ---------------- G partials via MFMA: Gpart[z][p] = Q_chunk^T Q_chunk -------
__global__ __launch_bounds__(256) void compute_g(const unsigned short* __restrict__ fused,
                                                 float* __restrict__ Gpart)
{
  __shared__ __align__(16) unsigned short Qs[64 * 136];
  const int z = blockIdx.x;            // b*32+n
  const int b = z >> 5, n = z & 31;
  const unsigned short* Q = fused + (long)b * S_ * H3_ + n * 384;
  const int t = threadIdx.x;
  const int w = t >> 6, l = t & 63;
  const int l31 = l & 31, hi = l >> 5;
  const int ar0 = (w & 1) * 2, ac0 = (w >> 1) * 2;

  f32x16 acc[2][2];
#pragma unroll
  for (int i = 0; i < 2; ++i)
#pragma unroll
    for (int j = 0; j < 2; ++j)
#pragma unroll
      for (int r = 0; r < 16; ++r) acc[i][j][r] = 0.f;

  const int sbeg = blockIdx.y * (S_ / GP_);

  for (int ss0 = 0; ss0 < S_ / GP_; ss0 += 64) {
    __syncthreads();
#pragma unroll
    for (int pass = 0; pass < 4; ++pass) {
      const int sL = pass * 16 + (t >> 4);
      const int c = t & 15;
      uint4 v = *(const uint4*)(Q + (long)(sbeg + ss0 + sL) * H3_ + c * 8);
      *(uint4*)&Qs[sL * 136 + c * 8] = v;
    }
    __syncthreads();

#pragma unroll
    for (int ks = 0; ks < 4; ++ks) {
      const int sb = ks * 16 + hi * 8;
      bf16x8 fa[2], fb[2];
#pragma unroll
      for (int i = 0; i < 2; ++i) {
        const int colA = (ar0 + i) * 32 + l31;
        const int colB = (ac0 + i) * 32 + l31;
        bf16x8 ra, rbv;
#pragma unroll
        for (int j = 0; j < 8; ++j) {
          ra[j]  = u2bf(Qs[(sb + j) * 136 + colA]);
          rbv[j] = u2bf(Qs[(sb + j) * 136 + colB]);
        }
        fa[i] = ra; fb[i] = rbv;
      }
#pragma unroll
      for (int i = 0; i < 2; ++i)
#pragma unroll
        for (int j = 0; j < 2; ++j)
          acc[i][j] = __builtin_amdgcn_mfma_f32_32x32x16_bf16(fa[i], fb[j], acc[i][j], 0, 0, 0);
    }
  }

  float* Gp = Gpart + ((long)z * GP_ + blockIdx.y) * 16384;
#pragma unroll
  for (int i = 0; i < 2; ++i) {
    const int rowb = (ar0 + i) * 32 + 4 * hi;
#pragma unroll
    for (int j = 0; j < 2; ++j) {
      const int col = (ac0 + j) * 32 + l31;
#pragma unroll
      for (int r = 0; r < 16; ++r) {
        const int row = rowb + (r & 3) + 8 * (r >> 2);
        Gp[row * 128 + col] = acc[i][j][r];
      }
    }
  }
}

// ---------------- register-resident Gauss-Jordan inverse of SPD 128x128 ------
__global__ __launch_bounds__(1024) void invert_g(const float* __restrict__ Gpart,
                                                 unsigned short* __restrict__ Ginv)
{
  __shared__ __align__(16) float prow[2][128];
  __shared__ __align__(16) float pcol[2][128];
  const int z = blockIdx.x;
  const int t = threadIdx.x;
  const int c  = t & 127;
  const int rg = t >> 7;
  const float* Gz = Gpart + (long)z * GP_ * 16384;

  float a[16];
#pragma unroll
  for (int i = 0; i < 16; ++i) {
    const int idx = (rg * 16 + i) * 128 + c;
    float s = 0.f;
#pragma unroll
    for (int p = 0; p < GP_; ++p) s += Gz[p * 16384 + idx];
    a[i] = s;
  }

  for (int p = 0; p < 128; ++p) {
    const int buf = p & 1;
    const int prg = p >> 4, pi = p & 15;
    if (rg == prg) {
      float v = a[0];
#pragma unroll
      for (int i = 1; i < 16; ++i) v = (pi == i) ? a[i] : v;
      prow[buf][c] = v;
    }
    if (c == p) {
#pragma unroll
      for (int q = 0; q < 4; ++q) {
        float4 w4 = make_float4(a[q * 4], a[q * 4 + 1], a[q * 4 + 2], a[q * 4 + 3]);
        *(float4*)&pcol[buf][rg * 16 + q * 4] = w4;
      }
    }
    __syncthreads();
    const float invp = 1.0f / prow[buf][p];
    const float rowv = (c == p) ? invp : prow[buf][c] * invp;
#pragma unroll
    for (int q = 0; q < 4; ++q) {
      const float4 pc4 = *(const float4*)&pcol[buf][rg * 16 + q * 4];
      const float pcv[4] = {pc4.x, pc4.y, pc4.z, pc4.w};
#pragma unroll
      for (int j = 0; j < 4; ++j) {
        const int i = q * 4 + j;
        const int r = rg * 16 + i;
        const float cur = (c == p) ? 0.f : a[i];
        a[i] = (r == p) ? rowv : cur - pcv[j] * rowv;
      }
    }
  }
  unsigned short* Oz = Ginv + (long)z * 16384;
#pragma unroll
  for (int i = 0; i < 16; ++i) Oz[(rg * 16 + i) * 128 + c] = f2bf(a[i]);
}

// ---------------- per-position 32x32 head attention (MFMA grams + MFMA PV) ---
__global__ __launch_bounds__(256) void attn_pos(
    const unsigned short* __restrict__ fused, const unsigned short* __restrict__ Zb,
    const float* __restrict__ alibi, unsigned short* __restrict__ ctx)
{
  __shared__ __align__(16) unsigned short q_s[32 * 136];
  __shared__ __align__(16) unsigned short k_s[32 * 136];
  __shared__ __align__(16) unsigned short z_s[32 * 136];
  __shared__ __align__(16) unsigned short v_s[32 * 128];
  __shared__ float part[4][32][33];
  __shared__ unsigned short pbf[32 * 34];
  __shared__ float pden[NH_];
  __shared__ float alib[NH_];

  const int s = blockIdx.x, b = blockIdx.y;
  const int t = threadIdx.x;
  const int w = t >> 6, l = t & 63;
  const int l31 = l & 31, hi = l >> 5;
  const unsigned short* src = fused + ((long)b * S_ + s) * H3_;
  const unsigned short* zg = Zb + ((long)b * S_ + s) * H_;

  if (t < NH_) alib[t] = 0.08838834764831845f * alibi[((long)(b * NH_ + t)) * S_ + s];

  {
    const int i0 = t >> 4, c = t & 15;
    gload_lds16(src + i0 * 384 + 256 + c * 8,        (char*)v_s + w * 1024);
    gload_lds16(src + (i0 + 16) * 384 + 256 + c * 8, (char*)v_s + 4096 + w * 1024);
  }
  {
    const int row = t >> 3, c = (t & 7) * 16;
    uint4 a0 = *(const uint4*)(src + row * 384 + c);
    uint4 a1 = *(const uint4*)(src + row * 384 + c + 8);
    uint4 b0 = *(const uint4*)(src + row * 384 + 128 + c);
    uint4 b1 = *(const uint4*)(src + row * 384 + 128 + c + 8);
    uint4 c0 = *(const uint4*)(zg + row * 128 + c);
    uint4 c1 = *(const uint4*)(zg + row * 128 + c + 8);
    *(uint4*)&q_s[row * 136 + c] = a0; *(uint4*)&q_s[row * 136 + c + 8] = a1;
    *(uint4*)&k_s[row * 136 + c] = b0; *(uint4*)&k_s[row * 136 + c + 8] = b1;
    *(uint4*)&z_s[row * 136 + c] = c0; *(uint4*)&z_s[row * 136 + c + 8] = c1;
  }
  __syncthreads();

  // per-wave d-slice grams
  {
    f32x16 g1, g2;
#pragma unroll
    for (int r = 0; r < 16; ++r) { g1[r] = 0.f; g2[r] = 0.f; }
#pragma unroll
    for (int ks = 0; ks < 2; ++ks) {
      const int off = w * 32 + ks * 16 + hi * 8;
      bf16x8 aq = *(const bf16x8*)&q_s[l31 * 136 + off];
      bf16x8 bk = *(const bf16x8*)&k_s[l31 * 136 + off];
      bf16x8 bz = *(const bf16x8*)&z_s[l31 * 136 + off];
      g1 = __builtin_amdgcn_mfma_f32_32x32x16_bf16(aq, bk, g1, 0, 0, 0);
      g2 = __builtin_amdgcn_mfma_f32_32x32x16_bf16(aq, bz, g2, 0, 0, 0);
    }
    const float aj = alib[l31];
#pragma unroll
    for (int r = 0; r < 16; ++r) {
      const int row = (r & 3) + 8 * (r >> 2) + 4 * hi;
      part[w][row][l31] = 0.0078125f * g1[r] + aj * g2[r];
    }
  }
  __syncthreads();

  // wave-parallel softmax, reading the 4 wave-partials directly
  const int i = t >> 3;
  const int j0 = (t & 7) * 4;
  float wv[4];
#pragma unroll
  for (int jj = 0; jj < 4; ++jj)
    wv[jj] = part[0][i][j0 + jj] + part[1][i][j0 + jj]
           + part[2][i][j0 + jj] + part[3][i][j0 + jj];
  float vmax = fmaxf(fmaxf(wv[0], wv[1]), fmaxf(wv[2], wv[3]));
  vmax = fmaxf(vmax, __shfl_xor(vmax, 1));
  vmax = fmaxf(vmax, __shfl_xor(vmax, 2));
  vmax = fmaxf(vmax, __shfl_xor(vmax, 4));
  float ssum = 0.f;
#pragma unroll
  for (int jj = 0; jj < 4; ++jj) { wv[jj] = __expf(wv[jj] - vmax); ssum += wv[jj]; }
#pragma unroll
  for (int jj = 0; jj < 4; ++jj) pbf[i * 34 + j0 + jj] = f2bf(wv[jj]);
  ssum += __shfl_xor(ssum, 1);
  ssum += __shfl_xor(ssum, 2);
  ssum += __shfl_xor(ssum, 4);
  if ((t & 7) == 0) pden[i] = 1.0f / (ssum + 1e-8f);
  __syncthreads();

  // PV via MFMA: wave w -> d-slice w*32..w*32+31
  {
    f32x16 cacc;
#pragma unroll
    for (int r = 0; r < 16; ++r) cacc[r] = 0.f;
    bf16x8 pa[2], vb[2];
#pragma unroll
    for (int ks = 0; ks < 2; ++ks) {
      bf16x8 p8, v8;
#pragma unroll
      for (int jj = 0; jj < 8; ++jj) {
        const int k = ks * 16 + hi * 8 + jj;
        p8[jj] = u2bf(pbf[l31 * 34 + k]);
        v8[jj] = u2bf(v_s[k * 128 + w * 32 + l31]);
      }
      pa[ks] = p8; vb[ks] = v8;
    }
    cacc = __builtin_amdgcn_mfma_f32_32x32x16_bf16(pa[0], vb[0], cacc, 0, 0, 0);
    cacc = __builtin_amdgcn_mfma_f32_32x32x16_bf16(pa[1], vb[1], cacc, 0, 0, 0);

    unsigned short* cb = ctx + ((long)b * S_ + s) * H_ + w * 32 + l31;
#pragma unroll
    for (int r = 0; r < 16; ++r) {
      const int row = (r & 3) + 8 * (r >> 2) + 4 * hi;
      cb[row * HD_] = f2bf(cacc[r] * pden[row]);
    }
  }
}

// -----------------------------------------------------------------------------
extern "C" void kernel_launch(void* const* d_in, const int* in_sizes, int n_in,
                              void* d_out, int out_size, void* d_ws, size_t ws_size,
                              hipStream_t stream)
{
  (void)in_sizes; (void)n_in; (void)out_size; (void)ws_size;
  const float* hidden   = (const float*)d_in[0];
  const float* residual = (const float*)d_in[1];
  const float* alibi    = (const float*)d_in[2];
  const float* Wqkv     = (const float*)d_in[4];
  const float* bqkv     = (const float*)d_in[5];
  const float* Wd       = (const float*)d_in[6];
  const float* bd       = (const float*)d_in[7];
  float* out = (float*)d_out;

  char* ws = (char*)d_ws;
  size_t off = 0;
  auto carve = [&](size_t bytes) -> void* {
    void* p = ws + off;
    off += (bytes + 255) & ~(size_t)255;
    return p;
  };
  const long nHid = (long)B_ * S_ * H_;
  const long nWq  = (long)H3_ * H_;
  unsigned short* hid_bf   = (unsigned short*)carve((size_t)nHid * 2);
  unsigned short* wqkv_bf  = (unsigned short*)carve((size_t)nWq * 2);
  unsigned short* wd_bf    = (unsigned short*)carve((size_t)H_ * H_ * 2);
  unsigned short* fused_bf = (unsigned short*)carve((size_t)B_ * S_ * H3_ * 2);
  unsigned short* z_bf     = (unsigned short*)carve((size_t)nHid * 2);
  unsigned short* ctx_bf   = (unsigned short*)carve((size_t)nHid * 2);
  float*          Gpart    = (float*)carve((size_t)64 * GP_ * 16384 * 4);
  unsigned short* ginv_bf  = (unsigned short*)carve((size_t)64 * 16384 * 2);

  // 1) bf16 casts (single launch, 3 segments)
  cvt3<<<2048, 256, 0, stream>>>(hidden, hid_bf, nHid,
                                 Wqkv, wqkv_bf, nWq,
                                 Wd, wd_bf, (long)H_ * H_);

  // 2) fused = hidden @ Wqkv^T + b_qkv  (bf16 out)
  gemm256<0><<<dim3(H3_ / 256, (B_ * S_) / 256, 1), 1024, 0, stream>>>(
      hid_bf, wqkv_bf, fused_bf, bqkv, nullptr, H_, H_, H3_, H_);

  // 3) G partials via MFMA -> Ginv via register Gauss-Jordan (sums partials)
  compute_g<<<dim3(64, GP_), 256, 0, stream>>>(fused_bf, Gpart);
  invert_g<<<64, 1024, 0, stream>>>(Gpart, ginv_bf);

  // 4) Z[b,s,n,:] = Ginv_{b,n} q_{b,n}(s)  (single-stage batched GEMM)
  zgemm<<<dim3(1, S_ / 128, 64), 256, 0, stream>>>(fused_bf, ginv_bf, z_bf);

  // 5) per-position 32x32 head attention -> ctx (bf16)
  attn_pos<<<dim3(S_, B_), 256, 0, stream>>>(fused_bf, z_bf, alibi, ctx_bf);

  // 6) out = ctx @ Wd^T + b_dense + residual  (f32 out)
  gemm256<1><<<dim3(H_ / 256, (B_ * S_) / 256, 1), 1024, 0, stream>>>(
      ctx_bf, wd_bf, out, bd, residual, H_, H_, H_, H_);
}